// Round 3
// baseline (341.270 us; speedup 1.0000x reference)
//
#include <hip/hip_runtime.h>
#include <hip/hip_bf16.h>

typedef unsigned short u16;
typedef __attribute__((ext_vector_type(4))) float f32x4;
typedef __attribute__((ext_vector_type(8))) short short8;

#define NB   8
#define CIN  256
#define EDIM 256
#define M3   768
#define HWN  4096
#define LND  64
#define NS2  72    // NS LDS row stride (bf16 elems): 144B, 16B aligned

__device__ __forceinline__ float bf2f(u16 u){ return __uint_as_float(((unsigned)u)<<16); }
__device__ __forceinline__ u16 f2bf(float f){ __hip_bfloat16 h = __float2bfloat16(f); return *reinterpret_cast<u16*>(&h); }
__device__ __forceinline__ void bf2x2(unsigned u, float &lo, float &hi){
  lo = __uint_as_float(u<<16);
  hi = __uint_as_float(u & 0xffff0000u);
}

typedef __attribute__((address_space(1))) unsigned as1_uint;
typedef __attribute__((address_space(3))) unsigned as3_uint;
// async global->LDS, 16B per lane; dest must be wave-uniform base + lane*16
__device__ __forceinline__ void gl16(const void* g, void* l){
  __builtin_amdgcn_global_load_lds((const as1_uint*)g, (as3_uint*)l, 16, 0, 0);
}

// ---------------- prep: Xt[n][p][c] (bf16) = transpose of X[n][c][p] (fp32) ----------------
// blocks >= 2048: convert w_qkv / w_out to bf16 (once, instead of per GEMM block)
__global__ __launch_bounds__(256) void k_prep(const float* __restrict__ x, u16* __restrict__ Xt,
                                              const float* __restrict__ wq, const float* __restrict__ wo,
                                              u16* __restrict__ Wqb, u16* __restrict__ Wob){
  const int bi = blockIdx.x;
  const int tid = threadIdx.x;
  if(bi >= 2048){
    int ti = (bi-2048)*256 + tid;          // 0..2047
    const float* src; u16* dst;
    if(ti < 1536){ src = wq + (size_t)ti*128;        dst = Wqb + (size_t)ti*128; }
    else         { src = wo + (size_t)(ti-1536)*128; dst = Wob + (size_t)(ti-1536)*128; }
    #pragma unroll
    for(int t=0;t<128;t+=8){
      float4 v0 = *(const float4*)(src+t);
      float4 v1 = *(const float4*)(src+t+4);
      ushort4 o0, o1;
      o0.x=f2bf(v0.x); o0.y=f2bf(v0.y); o0.z=f2bf(v0.z); o0.w=f2bf(v0.w);
      o1.x=f2bf(v1.x); o1.y=f2bf(v1.y); o1.z=f2bf(v1.z); o1.w=f2bf(v1.w);
      *(ushort4*)(dst+t)   = o0;
      *(ushort4*)(dst+t+4) = o1;
    }
    return;
  }
  __shared__ float Ts[64*65];
  const int n = bi>>8, rem = bi&255, ct = rem>>6, pt = rem&63;
  const int c0 = ct*64, p0 = pt*64;
  {
    int cc = tid>>2, pj = (tid&3)*16;
    const float* xp = x + (size_t)n*CIN*HWN + (size_t)(c0+cc)*HWN + p0 + pj;
    #pragma unroll
    for(int j=0;j<16;j++) Ts[cc*65 + pj + j] = xp[j];
  }
  __syncthreads();
  {
    int pp = tid>>2, ej = (tid&3)*16;
    u16* op = Xt + ((size_t)n*HWN + p0 + pp)*CIN + c0 + ej;
    ushort4 o[4];
    #pragma unroll
    for(int j=0;j<16;j++) ((u16*)o)[j] = f2bf(Ts[(ej+j)*65 + pp]);
    *(ushort4*)(op+0)  = o[0];
    *(ushort4*)(op+4)  = o[1];
    *(ushort4*)(op+8)  = o[2];
    *(ushort4*)(op+12) = o[3];
  }
}

// ---------------- QKV GEMM 128x128xK256 bf16 MFMA, global_load_lds + XOR swizzle ------------
__global__ __launch_bounds__(256) void k_qkv(const u16* __restrict__ Wb, const u16* __restrict__ Xt,
                                             const float* __restrict__ bias, u16* __restrict__ Y){
  __shared__ __align__(16) u16 As[128*64];
  __shared__ __align__(16) u16 Bs[128*64];
  const int bi = blockIdx.x;
  const int n = bi&7, rem = bi>>3;
  const int ch0 = (rem%6)*128, p0 = (rem/6)*128;
  const int tid = threadIdx.x, lane = tid&63;
  const int c = tid&15, qq = (tid>>4)&3, w4 = tid>>6;
  const int wr0 = (w4&1)*64, wc0 = (w4>>1)*64;
  const u16* xb = Xt + ((size_t)n*HWN + p0)*CIN;
  const u16* wb = Wb + (size_t)ch0*CIN;
  f32x4 acc[4][4];
  #pragma unroll
  for(int mt=0;mt<4;mt++)
    #pragma unroll
    for(int nt=0;nt<4;nt++){ acc[mt][nt][0]=0.f; acc[mt][nt][1]=0.f; acc[mt][nt][2]=0.f; acc[mt][nt][3]=0.f; }
  const int srow  = w4*8 + (lane>>3);
  const int dslot = lane&7;
  const int sgo   = (dslot ^ (lane>>3))*8;       // swizzled source u16 offset within row-chunk
  const int rdswz = (c&7);                        // read-side row&7
  for(int ph=0; ph<4; ph++){
    #pragma unroll
    for(int j=0;j<4;j++){
      int r = j*32 + srow;
      gl16(wb + (size_t)r*CIN + ph*64 + sgo, &As[r*64 + dslot*8]);
    }
    #pragma unroll
    for(int j=0;j<4;j++){
      int r = j*32 + srow;
      gl16(xb + (size_t)r*CIN + ph*64 + sgo, &Bs[r*64 + dslot*8]);
    }
    __syncthreads();
    #pragma unroll
    for(int kt=0;kt<2;kt++){
      short8 af[4], bff[4];
      const int rslot = ((kt*4+qq)^rdswz)*8;
      #pragma unroll
      for(int mt=0;mt<4;mt++) af[mt]  = *(const short8*)&As[(wr0+mt*16+c)*64 + rslot];
      #pragma unroll
      for(int nt=0;nt<4;nt++) bff[nt] = *(const short8*)&Bs[(wc0+nt*16+c)*64 + rslot];
      #pragma unroll
      for(int mt=0;mt<4;mt++)
        #pragma unroll
        for(int nt=0;nt<4;nt++)
          acc[mt][nt] = __builtin_amdgcn_mfma_f32_16x16x32_bf16(af[mt], bff[nt], acc[mt][nt], 0, 0, 0);
    }
    __syncthreads();
  }
  u16* Yb = Y + (size_t)n*M3*HWN;
  #pragma unroll
  for(int mt=0;mt<4;mt++){
    int chb = ch0 + wr0 + mt*16 + 4*qq;
    float b0 = bias[chb], b1 = bias[chb+1], b2 = bias[chb+2], b3 = bias[chb+3];
    #pragma unroll
    for(int nt=0;nt<4;nt++){
      int p = p0 + wc0 + nt*16 + c;
      u16* yp = Yb + (size_t)chb*HWN + p;
      yp[0]             = f2bf(acc[mt][nt][0]+b0);
      yp[HWN]           = f2bf(acc[mt][nt][1]+b1);
      yp[2*(size_t)HWN] = f2bf(acc[mt][nt][2]+b2);
      yp[3*(size_t)HWN] = f2bf(acc[mt][nt][3]+b3);
    }
  }
}

// ---------------- landmarks (+ zero B3 for the atomic accumulation in k_mega) ----------------
__global__ void k_land(const u16* __restrict__ Y, float* __restrict__ qland, float* __restrict__ kland,
                       float* __restrict__ B3){
  const int l = blockIdx.x, n = blockIdx.y, e = threadIdx.x;
  B3[((size_t)n*LND + l)*EDIM + e] = 0.f;
  const u16* base = Y + (size_t)n*M3*HWN;
  float qs=0.f, ks=0.f;
  #pragma unroll 8
  for(int m=0;m<64;m++){
    size_t off = (size_t)(l*64+m)*M3;
    qs += bf2f(base[off+e]);
    ks += bf2f(base[off+256+e]);
  }
  qland[((size_t)n*LND+l)*EDIM+e] = qs*(1.f/4096.f);
  kland[((size_t)n*LND+l)*EDIM+e] = ks*(1.f/4096.f);
}

// ---------------- Z1[n][j][i] = kland_j · q_i ; Z3[n][i][j] = qland_i · k_j (raw logits) --------
#define LGS 264   // A LDS row stride (u16): 528B, 16B aligned, bank-conflict-free
__global__ __launch_bounds__(256) void k_landgemm(const u16* __restrict__ Y, const float* __restrict__ qland,
                                                  const float* __restrict__ kland, float* __restrict__ Z1,
                                                  float* __restrict__ Z3){
  __shared__ __align__(16) u16 As[64*LGS];
  __shared__ __align__(16) u16 Bs[2][64*64];
  const int z = blockIdx.y, n = z>>1, which = z&1;
  const int b0 = blockIdx.x*64;
  const float* land = (which ? qland : kland) + (size_t)n*LND*EDIM;
  const int boff = which ? 256 : 0;
  float* out = (which ? Z3 : Z1) + (size_t)n*LND*HWN;
  const u16* Yb = Y + (size_t)n*M3*HWN + boff;
  const int tid = threadIdx.x, lane = tid&63;
  const int c = tid&15, qq = (tid>>4)&3, wv = tid>>6;
  {
    int r = tid>>2, c0 = (tid&3)*64;
    const float* lp = land + (size_t)r*EDIM + c0;
    u16* dp = &As[r*LGS + c0];
    #pragma unroll
    for(int j=0;j<64;j+=4){
      float4 v = *(const float4*)(lp+j);
      ushort4 o; o.x=f2bf(v.x); o.y=f2bf(v.y); o.z=f2bf(v.z); o.w=f2bf(v.w);
      *(ushort4*)(dp+j) = o;
    }
  }
  const int srow  = wv*8 + (lane>>3);            // 0..31
  const int dslot = lane&7;
  const int sgo   = (dslot ^ (lane>>3))*8;       // row&7 == lane>>3 here
  const int rdswz = (c&7);
  f32x4 acc[4];
  #pragma unroll
  for(int nt=0;nt<4;nt++){ acc[nt][0]=0.f; acc[nt][1]=0.f; acc[nt][2]=0.f; acc[nt][3]=0.f; }
  #pragma unroll
  for(int j=0;j<2;j++){
    int r = j*32 + srow;
    gl16(Yb + (size_t)(b0+r)*M3 + sgo, &Bs[0][r*64 + dslot*8]);
  }
  __syncthreads();
  for(int ph=0; ph<4; ph++){
    const int cur = ph&1;
    if(ph<3){
      #pragma unroll
      for(int j=0;j<2;j++){
        int r = j*32 + srow;
        gl16(Yb + (size_t)(b0+r)*M3 + (ph+1)*64 + sgo, &Bs[cur^1][r*64 + dslot*8]);
      }
    }
    #pragma unroll
    for(int kt=0;kt<2;kt++){
      short8 af = *(const short8*)&As[(16*wv + c)*LGS + ph*64 + kt*32 + qq*8];
      const int rslot = ((kt*4+qq)^rdswz)*8;
      #pragma unroll
      for(int nt=0;nt<4;nt++){
        short8 bff = *(const short8*)&Bs[cur][(nt*16+c)*64 + rslot];
        acc[nt] = __builtin_amdgcn_mfma_f32_16x16x32_bf16(af, bff, acc[nt], 0, 0, 0);
      }
    }
    __syncthreads();
  }
  const int m0 = 16*wv + 4*qq;
  #pragma unroll
  for(int nt=0;nt<4;nt++){
    int col = b0 + nt*16 + c;
    out[(size_t)(m0+0)*HWN + col] = acc[nt][0];
    out[(size_t)(m0+1)*HWN + col] = acc[nt][1];
    out[(size_t)(m0+2)*HWN + col] = acc[nt][2];
    out[(size_t)(m0+3)*HWN + col] = acc[nt][3];
  }
}

// ---------------- NS 64x64 matmul via bf16 MFMA ----------------
__device__ __forceinline__ void ns_mm(const u16* L, const u16* Rt, int wv, int q, int c, f32x4 r4[4]){
  short8 a0 = *(const short8*)(L + (size_t)(16*wv + c)*NS2 + 8*q);
  short8 a1 = *(const short8*)(L + (size_t)(16*wv + c)*NS2 + 32 + 8*q);
  #pragma unroll
  for(int tc=0;tc<4;tc++){
    f32x4 acc = {0.f,0.f,0.f,0.f};
    short8 b0 = *(const short8*)(Rt + (size_t)(16*tc + c)*NS2 + 8*q);
    short8 b1 = *(const short8*)(Rt + (size_t)(16*tc + c)*NS2 + 32 + 8*q);
    acc = __builtin_amdgcn_mfma_f32_16x16x32_bf16(a0, b0, acc, 0, 0, 0);
    acc = __builtin_amdgcn_mfma_f32_16x16x32_bf16(a1, b1, acc, 0, 0, 0);
    r4[tc] = acc;
  }
}

// ---------------- NS body (k2 + Newton-Schulz pseudo-inverse), runs inside k_mega ----------------
__device__ void ns_body(int n, char* smem, const float* __restrict__ qland,
                        const float* __restrict__ kland, float* __restrict__ KinvT){
  u16* Kb  = (u16*)(smem + 0);
  u16* Vb  = (u16*)(smem + 9216);
  u16* Vt  = (u16*)(smem + 18432);
  u16* KVb = (u16*)(smem + 27648);
  u16* KVt = (u16*)(smem + 36864);
  u16* Tt  = (u16*)(smem + 46080);
  float* sS   = (float*)(smem + 55296);
  float* sred = (float*)(smem + 72704);
  const int tid = threadIdx.x;
  const int wv = tid>>6, q = (tid>>4)&3, c = tid&15;
  const float* qb = qland + (size_t)n*LND*EDIM;
  const float* kb = kland + (size_t)n*LND*EDIM;
  f32x4 acc[4];
  #pragma unroll
  for(int t=0;t<4;t++){ acc[t][0]=0.f; acc[t][1]=0.f; acc[t][2]=0.f; acc[t][3]=0.f; }
  for(int e0=0;e0<EDIM;e0+=64){
    __syncthreads();
    {
      int row = tid>>2, c0 = (tid&3)*16;
      const float* qp = qb + (size_t)row*EDIM + e0 + c0;
      const float* kp = kb + (size_t)row*EDIM + e0 + c0;
      u16* qd = &KVb[row*NS2 + c0];
      u16* kd = &KVt[row*NS2 + c0];
      #pragma unroll
      for(int j=0;j<16;j+=4){
        float4 qv = *(const float4*)(qp+j);
        float4 kv = *(const float4*)(kp+j);
        ushort4 qo, ko;
        qo.x=f2bf(qv.x); qo.y=f2bf(qv.y); qo.z=f2bf(qv.z); qo.w=f2bf(qv.w);
        ko.x=f2bf(kv.x); ko.y=f2bf(kv.y); ko.z=f2bf(kv.z); ko.w=f2bf(kv.w);
        *(ushort4*)(qd+j) = qo;
        *(ushort4*)(kd+j) = ko;
      }
    }
    __syncthreads();
    {
      short8 a0 = *(const short8*)&KVb[(16*wv+c)*NS2 + 8*q];
      short8 a1 = *(const short8*)&KVb[(16*wv+c)*NS2 + 32 + 8*q];
      #pragma unroll
      for(int tc=0;tc<4;tc++){
        short8 b0 = *(const short8*)&KVt[(16*tc+c)*NS2 + 8*q];
        short8 b1 = *(const short8*)&KVt[(16*tc+c)*NS2 + 32 + 8*q];
        acc[tc] = __builtin_amdgcn_mfma_f32_16x16x32_bf16(a0, b0, acc[tc], 0, 0, 0);
        acc[tc] = __builtin_amdgcn_mfma_f32_16x16x32_bf16(a1, b1, acc[tc], 0, 0, 0);
      }
    }
  }
  #pragma unroll
  for(int tc=0;tc<4;tc++){
    int col = 16*tc + c, row0 = 16*wv + 4*q;
    sS[(row0+0)*68+col] = acc[tc][0];
    sS[(row0+1)*68+col] = acc[tc][1];
    sS[(row0+2)*68+col] = acc[tc][2];
    sS[(row0+3)*68+col] = acc[tc][3];
  }
  __syncthreads();
  if(tid < 64){
    int j = tid;
    float m = -1e30f;
    for(int i=0;i<64;i++) m = fmaxf(m, sS[i*68+j]);
    float ssum = 0.f;
    for(int i=0;i<64;i++) ssum += __expf(sS[i*68+j]-m);
    float inv = 1.f/ssum, cs = 0.f;
    for(int i=0;i<64;i++){
      float kv = __expf(sS[i*68+j]-m)*inv;
      cs += fabsf(kv);
      Kb[i*NS2+j] = f2bf(kv);
    }
    sred[j] = cs;
  }
  __syncthreads();
  if(tid < 64){
    int i = tid; float rs = 0.f;
    for(int j=0;j<64;j++) rs += fabsf(bf2f(Kb[i*NS2+j]));
    sred[64+i] = rs;
  }
  __syncthreads();
  if(tid == 0){
    float v0=-1e30f, vi=-1e30f;
    for(int t=0;t<64;t++){ v0 = fmaxf(v0, sred[t]); vi = fmaxf(vi, sred[64+t]); }
    sred[128] = 1.f/(v0*vi);
  }
  __syncthreads();
  {
    float sc = sred[128];
    int i = tid>>2, j16 = (tid&3)*16;
    #pragma unroll
    for(int jj=0;jj<16;jj++){
      int j = j16+jj;
      u16 bvv = f2bf(bf2f(Kb[j*NS2+i])*sc);
      Vb[i*NS2+j] = bvv;
      Vt[j*NS2+i] = bvv;
    }
  }
  __syncthreads();
  f32x4 r4[4];
  for(int it=0; it<6; it++){
    ns_mm(Kb, Vt, wv, q, c, r4);
    #pragma unroll
    for(int tc=0;tc<4;tc++){
      int col = 16*tc + c, row0 = 16*wv + 4*q;
      ushort4 pk;
      pk.x = f2bf(r4[tc][0]); pk.y = f2bf(r4[tc][1]); pk.z = f2bf(r4[tc][2]); pk.w = f2bf(r4[tc][3]);
      KVb[(row0+0)*NS2+col] = pk.x; KVb[(row0+1)*NS2+col] = pk.y;
      KVb[(row0+2)*NS2+col] = pk.z; KVb[(row0+3)*NS2+col] = pk.w;
      *(ushort4*)&KVt[(size_t)col*NS2 + row0] = pk;
    }
    __syncthreads();
    ns_mm(KVb, KVt, wv, q, c, r4);
    #pragma unroll
    for(int tc=0;tc<4;tc++){
      int col = 16*tc+c, row0 = 16*wv+4*q;
      ushort4 pk;
      #pragma unroll
      for(int r=0;r<4;r++){
        float kvv = bf2f(KVb[(row0+r)*NS2+col]);
        ((u16*)&pk)[r] = f2bf(7.f*kvv - r4[tc][r]);
      }
      *(ushort4*)&Tt[(size_t)col*NS2 + row0] = pk;
    }
    __syncthreads();
    ns_mm(KVb, Tt, wv, q, c, r4);
    __syncthreads();
    #pragma unroll
    for(int tc=0;tc<4;tc++){
      int col = 16*tc+c, row0 = 16*wv+4*q;
      ushort4 pk;
      #pragma unroll
      for(int r=0;r<4;r++){
        float kvv = bf2f(KVb[(row0+r)*NS2+col]);
        ((u16*)&pk)[r] = f2bf(15.f*kvv - r4[tc][r]);
      }
      *(ushort4*)&Tt[(size_t)col*NS2 + row0] = pk;
    }
    __syncthreads();
    ns_mm(Vb, Tt, wv, q, c, r4);
    __syncthreads();
    #pragma unroll
    for(int tc=0;tc<4;tc++){
      int col = 16*tc+c, row0 = 16*wv+4*q;
      float nv[4]; ushort4 pk;
      #pragma unroll
      for(int r=0;r<4;r++){
        float vv = bf2f(Vb[(row0+r)*NS2+col]);
        nv[r] = 0.25f*(13.f*vv - r4[tc][r]);
        u16 bb = f2bf(nv[r]);
        Vb[(row0+r)*NS2+col] = bb;
        ((u16*)&pk)[r] = bb;
      }
      *(ushort4*)&Vt[(size_t)col*NS2 + row0] = pk;
      if(it==5){
        *(float4*)&KinvT[(size_t)n*4096 + (size_t)col*64 + row0] = make_float4(nv[0],nv[1],nv[2],nv[3]);
      }
    }
    __syncthreads();
  }
}

// ---------------- f body: soft3 + k3@v partial, atomicAdd into B3 ----------------
#define NSTR 76
__device__ void f_body(int idx, char* smem, const float* __restrict__ Z3, const u16* __restrict__ Y,
                       float* __restrict__ B3){
  const int kc = idx&31, n = (idx>>5)&7, eh = idx>>8;
  const int tid = threadIdx.x;
  const int jb = kc*128, eb = eh*128;
  float* Sf = (float*)smem;              // [64][132] raw logits
  u16* k3T  = (u16*)(smem + 33792);      // [128][NSTR] post-softmax bf16
  const float* z3b = Z3 + (size_t)n*LND*HWN;
  {
    int ibase = (tid>>5)*8, j4 = (tid&31)*4;
    #pragma unroll
    for(int r=0;r<8;r++){
      int i = ibase + r;
      *(float4*)&Sf[i*132 + j4] = *(const float4*)&z3b[(size_t)i*HWN + jb + j4];
    }
  }
  __syncthreads();
  if(tid < 128){
    int j = tid;
    float m = -1e30f;
    for(int i=0;i<64;i++) m = fmaxf(m, Sf[i*132 + j]);
    float s = 0.f;
    for(int i=0;i<64;i++){ float e = __expf(Sf[i*132 + j] - m); Sf[i*132 + j] = e; s += e; }
    float inv = 1.f/s;
    u16* kr = &k3T[j*NSTR];
    for(int i=0;i<64;i+=4){
      ushort4 o;
      o.x = f2bf(Sf[(i+0)*132 + j]*inv);
      o.y = f2bf(Sf[(i+1)*132 + j]*inv);
      o.z = f2bf(Sf[(i+2)*132 + j]*inv);
      o.w = f2bf(Sf[(i+3)*132 + j]*inv);
      *(ushort4*)(kr + i) = o;
    }
  }
  __syncthreads();
  const int i0 = (tid>>4)*4, e0 = eb + (tid&15)*8;
  const u16* Yb = Y + (size_t)n*M3*HWN;
  float acc[4][8] = {};
  for(int j=0;j<128;j++){
    ushort4 av = *(const ushort4*)&k3T[(size_t)j*NSTR + i0];
    float a0 = bf2f(av.x), a1 = bf2f(av.y), a2 = bf2f(av.z), a3 = bf2f(av.w);
    const u16* vp = Yb + (size_t)(jb+j)*M3 + 512 + e0;
    uint4 U0 = *(const uint4*)vp;
    float bv[8];
    bf2x2(U0.x, bv[0], bv[1]);  bf2x2(U0.y, bv[2], bv[3]);
    bf2x2(U0.z, bv[4], bv[5]);  bf2x2(U0.w, bv[6], bv[7]);
    #pragma unroll
    for(int u=0;u<8;u++){
      acc[0][u] += a0*bv[u];
      acc[1][u] += a1*bv[u];
      acc[2][u] += a2*bv[u];
      acc[3][u] += a3*bv[u];
    }
  }
  float* pb = B3 + (size_t)n*LND*EDIM;
  #pragma unroll
  for(int s=0;s<4;s++)
    #pragma unroll
    for(int u=0;u<8;u++)
      atomicAdd(&pb[(size_t)(i0+s)*EDIM + e0 + u], acc[s][u]);
}

// ---------------- soft1 body: softmax of Z1 over contiguous 4096 ----------------
__device__ void soft1_body(int b, char* smem, float* __restrict__ Z1){
  const int n = b>>6, j = b&63, tid = threadIdx.x;
  float* redm = (float*)smem;
  float* reds = redm + 4;
  float* base = Z1 + ((size_t)n*LND + j)*HWN;
  float v[16];
  float m = -1e30f;
  #pragma unroll
  for(int r=0;r<16;r++){ v[r] = base[r*256 + tid]; m = fmaxf(m, v[r]); }
  #pragma unroll
  for(int o=32;o;o>>=1) m = fmaxf(m, __shfl_xor(m, o));
  const int wid = tid>>6;
  if((tid&63)==0) redm[wid] = m;
  __syncthreads();
  m = fmaxf(fmaxf(redm[0],redm[1]), fmaxf(redm[2],redm[3]));
  float s = 0.f;
  #pragma unroll
  for(int r=0;r<16;r++){ v[r] = __expf(v[r]-m); s += v[r]; }
  #pragma unroll
  for(int o=32;o;o>>=1) s += __shfl_xor(s, o);
  if((tid&63)==0) reds[wid] = s;
  __syncthreads();
  s = reds[0]+reds[1]+reds[2]+reds[3];
  float inv = 1.f/s;
  #pragma unroll
  for(int r=0;r<16;r++) base[r*256 + tid] = v[r]*inv;
}

// ---------------- mega kernel: blocks 0-7 NS, 8-519 f, 520-1031 soft1 (all independent) ------
__global__ __launch_bounds__(256) void k_mega(const float* __restrict__ Z3, const u16* __restrict__ Y,
                                              float* __restrict__ B3, float* __restrict__ Z1,
                                              const float* __restrict__ qland, const float* __restrict__ kland,
                                              float* __restrict__ KinvT){
  __shared__ __align__(16) char smem[73728];
  const int bi = blockIdx.x;
  if(bi < 8)        ns_body(bi, smem, qland, kland, KinvT);
  else if(bi < 520) f_body(bi-8, smem, Z3, Y, B3);
  else              soft1_body(bi-520, smem, Z1);
}

// ---------------- C2[j][e] = sum_l Kinv[j][l]*B3[l][e] ----------------
__global__ __launch_bounds__(256) void k_c2(const float* __restrict__ KinvT, const float* __restrict__ B3,
                                            float* __restrict__ C2){
  const int eb = blockIdx.x*64, n = blockIdx.y, tid = threadIdx.x;
  __shared__ float KT[64][68];
  __shared__ float Bs2[64][68];
  {
    int l = tid>>2, o16 = (tid&3)*16;
    const float* kp = KinvT + (size_t)n*4096 + l*64 + o16;
    const float* bp = B3 + ((size_t)n*LND + l)*EDIM + eb + o16;
    #pragma unroll
    for(int t=0;t<16;t+=4){
      *(float4*)&KT[l][o16+t]  = *(const float4*)(kp+t);
      *(float4*)&Bs2[l][o16+t] = *(const float4*)(bp+t);
    }
  }
  __syncthreads();
  const int j0 = (tid>>4)*4, u0 = (tid&15)*4;
  float acc[4][4] = {};
  #pragma unroll 8
  for(int l=0;l<64;l++){
    f32x4 a = *(f32x4*)&KT[l][j0];
    f32x4 b = *(f32x4*)&Bs2[l][u0];
    #pragma unroll
    for(int s=0;s<4;s++)
      #pragma unroll
      for(int u=0;u<4;u++) acc[s][u] += a[s]*b[u];
  }
  #pragma unroll
  for(int s=0;s<4;s++){
    float4 fv = make_float4(acc[s][0],acc[s][1],acc[s][2],acc[s][3]);
    *(float4*)&C2[((size_t)n*LND + j0+s)*EDIM + eb + u0] = fv;
  }
}

// ---------------- out[i][e] = sum_j k1t[j][i]*C2[j][e] + v[i][e]; OM bf16 ----------------
__global__ __launch_bounds__(256) void k_out(const float* __restrict__ Z1, const float* __restrict__ C2,
                                             const u16* __restrict__ Y, u16* __restrict__ OM){
  const int ib = blockIdx.x*64, n = blockIdx.y, tid = threadIdx.x;
  __shared__ float K1s[64][68];
  __shared__ u16 C2s[64*264];
  {
    int j = tid>>2, i16 = (tid&3)*16;
    const float* zp = Z1 + ((size_t)n*LND + j)*HWN + ib + i16;
    #pragma unroll
    for(int t=0;t<16;t+=4) *(float4*)&K1s[j][i16+t] = *(const float4*)(zp+t);
    int e64 = (tid&3)*64;
    const float* cp = C2 + ((size_t)n*LND + j)*EDIM + e64;
    #pragma unroll
    for(int t=0;t<64;t+=4){
      float4 v = *(const float4*)(cp+t);
      C2s[j*264 + e64+t+0] = f2bf(v.x);
      C2s[j*264 + e64+t+1] = f2bf(v.y);
      C2s[j*264 + e64+t+2] = f2bf(v.z);
      C2s[j*264 + e64+t+3] = f2bf(v.w);
    }
  }
  __syncthreads();
  const int i0 = (tid>>4)*4, e0 = (tid&15)*16;
  float acc[4][16] = {};
  for(int j=0;j<64;j++){
    f32x4 a = *(f32x4*)&K1s[j][i0];
    const u16* cb = &C2s[j*264 + e0];
    uint4 U0 = *(const uint4*)cb;
    uint4 U1 = *(const uint4*)(cb+8);
    float bv[16];
    bf2x2(U0.x, bv[0], bv[1]);  bf2x2(U0.y, bv[2], bv[3]);
    bf2x2(U0.z, bv[4], bv[5]);  bf2x2(U0.w, bv[6], bv[7]);
    bf2x2(U1.x, bv[8], bv[9]);  bf2x2(U1.y, bv[10], bv[11]);
    bf2x2(U1.z, bv[12], bv[13]); bf2x2(U1.w, bv[14], bv[15]);
    #pragma unroll
    for(int u=0;u<16;u++){
      acc[0][u] += a[0]*bv[u];
      acc[1][u] += a[1]*bv[u];
      acc[2][u] += a[2]*bv[u];
      acc[3][u] += a[3]*bv[u];
    }
  }
  const u16* Yb = Y + (size_t)n*M3*HWN;
  u16* ob = OM + (size_t)n*HWN*EDIM;
  #pragma unroll
  for(int s=0;s<4;s++){
    int i = ib + i0 + s;
    const u16* vp = Yb + (size_t)i*M3 + 512 + e0;
    uint4 U0 = *(const uint4*)vp, U1 = *(const uint4*)(vp+8);
    float vv[16];
    bf2x2(U0.x, vv[0], vv[1]);  bf2x2(U0.y, vv[2], vv[3]);
    bf2x2(U0.z, vv[4], vv[5]);  bf2x2(U0.w, vv[6], vv[7]);
    bf2x2(U1.x, vv[8], vv[9]);  bf2x2(U1.y, vv[10], vv[11]);
    bf2x2(U1.z, vv[12], vv[13]); bf2x2(U1.w, vv[14], vv[15]);
    #pragma unroll
    for(int t=0;t<16;t+=4){
      ushort4 o;
      o.x = f2bf(acc[s][t+0]+vv[t+0]);
      o.y = f2bf(acc[s][t+1]+vv[t+1]);
      o.z = f2bf(acc[s][t+2]+vv[t+2]);
      o.w = f2bf(acc[s][t+3]+vv[t+3]);
      *(ushort4*)&ob[(size_t)i*EDIM + e0 + t] = o;
    }
  }
}

// ---------------- transpose of raw-reshaped OM ----------------
__global__ __launch_bounds__(256) void k_trans2(const u16* __restrict__ OM, u16* __restrict__ OMT){
  __shared__ u16 Ts[64*65];
  const int bi = blockIdx.x;
  const int n = bi>>8, rem = bi&255, et = rem>>6, pt = rem&63;
  const int e0 = et*64, p0 = pt*64, tid = threadIdx.x;
  const u16* omb = OM + (size_t)n*HWN*EDIM;
  {
    int ee = tid>>2, pj = (tid&3)*16;
    const u16* ip = omb + (size_t)(e0+ee)*HWN + p0 + pj;
    ushort4 v0 = *(const ushort4*)(ip);
    ushort4 v1 = *(const ushort4*)(ip+4);
    ushort4 v2 = *(const ushort4*)(ip+8);
    ushort4 v3 = *(const ushort4*)(ip+12);
    u16* tp = &Ts[ee*65 + pj];
    tp[0]=v0.x; tp[1]=v0.y; tp[2]=v0.z; tp[3]=v0.w;
    tp[4]=v1.x; tp[5]=v1.y; tp[6]=v1.z; tp[7]=v1.w;
    tp[8]=v2.x; tp[9]=v2.y; tp[10]=v2.z; tp[11]=v2.w;
    tp[12]=v3.x; tp[13]=v3.y; tp[14]=v3.z; tp[15]=v3.w;
  }
  __syncthreads();
  {
    int pp = tid>>2, ej = (tid&3)*16;
    u16* op = OMT + ((size_t)n*HWN + p0 + pp)*EDIM + e0 + ej;
    ushort4 o[4];
    #pragma unroll
    for(int j=0;j<16;j++) ((u16*)o)[j] = Ts[(ej+j)*65 + pp];
    *(ushort4*)(op+0)  = o[0];
    *(ushort4*)(op+4)  = o[1];
    *(ushort4*)(op+8)  = o[2];
    *(ushort4*)(op+12) = o[3];
  }
}

// ---------------- proj GEMM 128x128xK256, global_load_lds + XOR swizzle ----------------
__global__ __launch_bounds__(256) void k_proj(const u16* __restrict__ Wb, const u16* __restrict__ OMT,
                                              const float* __restrict__ bias, float* __restrict__ out){
  __shared__ __align__(16) u16 As[128*64];
  __shared__ __align__(16) u16 Bs[128*64];
  const int bi = blockIdx.x;
  const int n = bi&7, rem = bi>>3;
  const int ch0 = (rem&1)*128, p0 = (rem>>1)*128;
  const int tid = threadIdx.x, lane = tid&63;
  const int c = tid&15, qq = (tid>>4)&3, w4 = tid>>6;
  const int wr0 = (w4&1)*64, wc0 = (w4>>1)*64;
  const u16* xb = OMT + ((size_t)n*HWN + p0)*EDIM;
  const u16* wb = Wb + (size_t)ch0*EDIM;
  f32x4 acc[4][4];
  #pragma unroll
  for(int mt=0;mt<4;mt++)
    #pragma unroll
    for(int nt=0;nt<4;nt++){ acc[mt][nt][0]=0.f; acc[mt][nt][1]=0.f; acc[mt][nt][2]=0.f; acc[mt][nt][3]=0.f; }
  const int srow  = w4*8 + (lane>>3);
  const int dslot = lane&7;
  const int sgo   = (dslot ^ (lane>>3))*8;
  const int rdswz = (c&7);
  for(int ph=0; ph<4; ph++){
    #pragma unroll
    for(int j=0;j<4;j++){
      int r = j*32 + srow;
      gl16(wb + (size_t)r*EDIM + ph*64 + sgo, &As[r*64 + dslot*8]);
    }
    #pragma unroll
    for(int j=0;j<4;j++){
      int r = j*32 + srow;
      gl16(xb + (size_t)r*EDIM + ph*64 + sgo, &Bs[r*64 + dslot*8]);
    }
    __syncthreads();
    #pragma unroll
    for(int kt=0;kt<2;kt++){
      short8 af[4], bff[4];
      const int rslot = ((kt*4+qq)^rdswz)*8;
      #pragma unroll
      for(int mt=0;mt<4;mt++) af[mt]  = *(const short8*)&As[(wr0+mt*16+c)*64 + rslot];
      #pragma unroll
      for(int nt=0;nt<4;nt++) bff[nt] = *(const short8*)&Bs[(wc0+nt*16+c)*64 + rslot];
      #pragma unroll
      for(int mt=0;mt<4;mt++)
        #pragma unroll
        for(int nt=0;nt<4;nt++)
          acc[mt][nt] = __builtin_amdgcn_mfma_f32_16x16x32_bf16(af[mt], bff[nt], acc[mt][nt], 0, 0, 0);
    }
    __syncthreads();
  }
  float* ob = out + (size_t)n*EDIM*HWN;
  #pragma unroll
  for(int mt=0;mt<4;mt++){
    int chb = ch0 + wr0 + mt*16 + 4*qq;
    float b0 = bias[chb], b1 = bias[chb+1], b2 = bias[chb+2], b3 = bias[chb+3];
    #pragma unroll
    for(int nt=0;nt<4;nt++){
      int p = p0 + wc0 + nt*16 + c;
      float* yp = ob + (size_t)chb*HWN + p;
      yp[0]             = acc[mt][nt][0]+b0;
      yp[HWN]           = acc[mt][nt][1]+b1;
      yp[2*(size_t)HWN] = acc[mt][nt][2]+b2;
      yp[3*(size_t)HWN] = acc[mt][nt][3]+b3;
    }
  }
}

extern "C" void kernel_launch(void* const* d_in, const int* in_sizes, int n_in,
                              void* d_out, int out_size, void* d_ws, size_t ws_size,
                              hipStream_t stream){
  (void)out_size; (void)ws_size;
  const float* x     = (const float*)d_in[0];
  const float* w_qkv = (const float*)d_in[1];
  const float* b_qkv = (const float*)d_in[2];
  const float* w_out = (const float*)d_in[3];
  const float* b_out = (const float*)d_in[4];
  for(int i=0;i<n_in;i++){
    switch(in_sizes[i]){
      case 8388608: x     = (const float*)d_in[i]; break;
      case 196608:  w_qkv = (const float*)d_in[i]; break;
      case 768:     b_qkv = (const float*)d_in[i]; break;
      case 65536:   w_out = (const float*)d_in[i]; break;
      case 256:     b_out = (const float*)d_in[i]; break;
      default: break;
    }
  }
  float* out = (float*)d_out;
  char* ws = (char*)d_ws;

  u16*   Y     = (u16*)(ws + 0);              // 50,331,648 B  bf16 [8][768*4096]
  float* qland = (float*)(ws + 50331648);
  float* kland = (float*)(ws + 50855936);
  float* Z1    = (float*)(ws + 51380224);
  float* Z3    = (float*)(ws + 59768832);
  float* KinvT = (float*)(ws + 68157440);
  u16*   Xt    = (u16*)(ws + 68288512);       // 16 MB region: Xt -> OMT
  u16*   OMT   = (u16*)(ws + 68288512);
  float* B3    = (float*)(ws + 85065728);
  float* C2    = (float*)(ws + 85590016);
  u16*   OM    = (u16*)(ws + 86114304);       // 16 MB bf16
  // Wqb overlaps Z3 (Z3 written by k_landgemm AFTER k_qkv consumes Wqb — stream-ordered safe)
  u16*   Wqb   = (u16*)(ws + 59768832);       // 393,216 B bf16 [768][256]
  u16*   Wob   = (u16*)(ws + 102891520);      // 131,072 B bf16 [256][256] (persists to k_proj)

  k_prep    <<<dim3(2056),   256, 0, stream>>>(x, Xt, w_qkv, w_out, Wqb, Wob);
  k_qkv     <<<dim3(1536),   256, 0, stream>>>(Wqb, Xt, b_qkv, Y);
  k_land    <<<dim3(64,8),   256, 0, stream>>>(Y, qland, kland, B3);
  k_landgemm<<<dim3(64,16),  256, 0, stream>>>(Y, qland, kland, Z1, Z3);
  k_mega    <<<dim3(1032),   256, 0, stream>>>(Z3, Y, B3, Z1, qland, kland, KinvT);
  k_c2      <<<dim3(4,8),    256, 0, stream>>>(KinvT, B3, C2);
  k_out     <<<dim3(64,8),   256, 0, stream>>>(Z1, C2, Y, OM);
  k_trans2  <<<dim3(2048),   256, 0, stream>>>(OM, OMT);
  k_proj    <<<dim3(512),    256, 0, stream>>>(w_out ? Wob : Wob, OMT, b_out, out);
}

// Round 4
// 243.976 us; speedup vs baseline: 1.3988x; 1.3988x over previous
//
#include <hip/hip_runtime.h>
#include <hip/hip_bf16.h>

typedef unsigned short u16;
typedef __attribute__((ext_vector_type(4))) float f32x4;
typedef __attribute__((ext_vector_type(8))) short short8;

#define NB   8
#define CIN  256
#define EDIM 256
#define M3   768
#define HWN  4096
#define LND  64
#define NS2  72    // NS LDS row stride (bf16 elems): 144B, 16B aligned

__device__ __forceinline__ float bf2f(u16 u){ return __uint_as_float(((unsigned)u)<<16); }
__device__ __forceinline__ u16 f2bf(float f){ __hip_bfloat16 h = __float2bfloat16(f); return *reinterpret_cast<u16*>(&h); }
__device__ __forceinline__ void bf2x2(unsigned u, float &lo, float &hi){
  lo = __uint_as_float(u<<16);
  hi = __uint_as_float(u & 0xffff0000u);
}

typedef __attribute__((address_space(1))) unsigned as1_uint;
typedef __attribute__((address_space(3))) unsigned as3_uint;
// async global->LDS, 16B per lane; dest must be wave-uniform base + lane*16
__device__ __forceinline__ void gl16(const void* g, void* l){
  __builtin_amdgcn_global_load_lds((const as1_uint*)g, (as3_uint*)l, 16, 0, 0);
}

// ---------------- prep: Xt[n][p][c] (bf16) = transpose of X[n][c][p] (fp32) ----------------
// blocks >= 2048: convert w_qkv / w_out to bf16 (once, instead of per GEMM block)
__global__ __launch_bounds__(256) void k_prep(const float* __restrict__ x, u16* __restrict__ Xt,
                                              const float* __restrict__ wq, const float* __restrict__ wo,
                                              u16* __restrict__ Wqb, u16* __restrict__ Wob){
  const int bi = blockIdx.x;
  const int tid = threadIdx.x;
  if(bi >= 2048){
    int ti = (bi-2048)*256 + tid;          // 0..2047
    const float* src; u16* dst;
    if(ti < 1536){ src = wq + (size_t)ti*128;        dst = Wqb + (size_t)ti*128; }
    else         { src = wo + (size_t)(ti-1536)*128; dst = Wob + (size_t)(ti-1536)*128; }
    #pragma unroll
    for(int t=0;t<128;t+=8){
      float4 v0 = *(const float4*)(src+t);
      float4 v1 = *(const float4*)(src+t+4);
      ushort4 o0, o1;
      o0.x=f2bf(v0.x); o0.y=f2bf(v0.y); o0.z=f2bf(v0.z); o0.w=f2bf(v0.w);
      o1.x=f2bf(v1.x); o1.y=f2bf(v1.y); o1.z=f2bf(v1.z); o1.w=f2bf(v1.w);
      *(ushort4*)(dst+t)   = o0;
      *(ushort4*)(dst+t+4) = o1;
    }
    return;
  }
  __shared__ float Ts[64*65];
  const int n = bi>>8, rem = bi&255, ct = rem>>6, pt = rem&63;
  const int c0 = ct*64, p0 = pt*64;
  {
    int cc = tid>>2, pj = (tid&3)*16;
    const float* xp = x + (size_t)n*CIN*HWN + (size_t)(c0+cc)*HWN + p0 + pj;
    #pragma unroll
    for(int j=0;j<16;j++) Ts[cc*65 + pj + j] = xp[j];
  }
  __syncthreads();
  {
    int pp = tid>>2, ej = (tid&3)*16;
    u16* op = Xt + ((size_t)n*HWN + p0 + pp)*CIN + c0 + ej;
    ushort4 o[4];
    #pragma unroll
    for(int j=0;j<16;j++) ((u16*)o)[j] = f2bf(Ts[(ej+j)*65 + pp]);
    *(ushort4*)(op+0)  = o[0];
    *(ushort4*)(op+4)  = o[1];
    *(ushort4*)(op+8)  = o[2];
    *(ushort4*)(op+12) = o[3];
  }
}

// ---------------- QKV GEMM 128x128xK256 bf16 MFMA, global_load_lds + XOR swizzle ------------
__global__ __launch_bounds__(256) void k_qkv(const u16* __restrict__ Wb, const u16* __restrict__ Xt,
                                             const float* __restrict__ bias, u16* __restrict__ Y){
  __shared__ __align__(16) u16 As[128*64];
  __shared__ __align__(16) u16 Bs[128*64];
  const int bi = blockIdx.x;
  const int n = bi&7, rem = bi>>3;
  const int ch0 = (rem%6)*128, p0 = (rem/6)*128;
  const int tid = threadIdx.x, lane = tid&63;
  const int c = tid&15, qq = (tid>>4)&3, w4 = tid>>6;
  const int wr0 = (w4&1)*64, wc0 = (w4>>1)*64;
  const u16* xb = Xt + ((size_t)n*HWN + p0)*CIN;
  const u16* wb = Wb + (size_t)ch0*CIN;
  f32x4 acc[4][4];
  #pragma unroll
  for(int mt=0;mt<4;mt++)
    #pragma unroll
    for(int nt=0;nt<4;nt++){ acc[mt][nt][0]=0.f; acc[mt][nt][1]=0.f; acc[mt][nt][2]=0.f; acc[mt][nt][3]=0.f; }
  const int srow  = w4*8 + (lane>>3);
  const int dslot = lane&7;
  const int sgo   = (dslot ^ (lane>>3))*8;       // swizzled source u16 offset within row-chunk
  const int rdswz = (c&7);                        // read-side row&7
  for(int ph=0; ph<4; ph++){
    #pragma unroll
    for(int j=0;j<4;j++){
      int r = j*32 + srow;
      gl16(wb + (size_t)r*CIN + ph*64 + sgo, &As[r*64 + dslot*8]);
    }
    #pragma unroll
    for(int j=0;j<4;j++){
      int r = j*32 + srow;
      gl16(xb + (size_t)r*CIN + ph*64 + sgo, &Bs[r*64 + dslot*8]);
    }
    __syncthreads();
    #pragma unroll
    for(int kt=0;kt<2;kt++){
      short8 af[4], bff[4];
      const int rslot = ((kt*4+qq)^rdswz)*8;
      #pragma unroll
      for(int mt=0;mt<4;mt++) af[mt]  = *(const short8*)&As[(wr0+mt*16+c)*64 + rslot];
      #pragma unroll
      for(int nt=0;nt<4;nt++) bff[nt] = *(const short8*)&Bs[(wc0+nt*16+c)*64 + rslot];
      #pragma unroll
      for(int mt=0;mt<4;mt++)
        #pragma unroll
        for(int nt=0;nt<4;nt++)
          acc[mt][nt] = __builtin_amdgcn_mfma_f32_16x16x32_bf16(af[mt], bff[nt], acc[mt][nt], 0, 0, 0);
    }
    __syncthreads();
  }
  u16* Yb = Y + (size_t)n*M3*HWN;
  #pragma unroll
  for(int mt=0;mt<4;mt++){
    int chb = ch0 + wr0 + mt*16 + 4*qq;
    float b0 = bias[chb], b1 = bias[chb+1], b2 = bias[chb+2], b3 = bias[chb+3];
    #pragma unroll
    for(int nt=0;nt<4;nt++){
      int p = p0 + wc0 + nt*16 + c;
      u16* yp = Yb + (size_t)chb*HWN + p;
      yp[0]             = f2bf(acc[mt][nt][0]+b0);
      yp[HWN]           = f2bf(acc[mt][nt][1]+b1);
      yp[2*(size_t)HWN] = f2bf(acc[mt][nt][2]+b2);
      yp[3*(size_t)HWN] = f2bf(acc[mt][nt][3]+b3);
    }
  }
}

// ---------------- landmarks ----------------
__global__ void k_land(const u16* __restrict__ Y, float* __restrict__ qland, float* __restrict__ kland){
  const int l = blockIdx.x, n = blockIdx.y, e = threadIdx.x;
  const u16* base = Y + (size_t)n*M3*HWN;
  float qs=0.f, ks=0.f;
  #pragma unroll 8
  for(int m=0;m<64;m++){
    size_t off = (size_t)(l*64+m)*M3;
    qs += bf2f(base[off+e]);
    ks += bf2f(base[off+256+e]);
  }
  qland[((size_t)n*LND+l)*EDIM+e] = qs*(1.f/4096.f);
  kland[((size_t)n*LND+l)*EDIM+e] = ks*(1.f/4096.f);
}

// ---------------- Z1[n][j][i] = kland_j · q_i ; Z3[n][i][j] = qland_i · k_j (raw logits) --------
#define LGS 264   // A LDS row stride (u16): 528B, 16B aligned, bank-conflict-free
__global__ __launch_bounds__(256) void k_landgemm(const u16* __restrict__ Y, const float* __restrict__ qland,
                                                  const float* __restrict__ kland, float* __restrict__ Z1,
                                                  float* __restrict__ Z3){
  __shared__ __align__(16) u16 As[64*LGS];
  __shared__ __align__(16) u16 Bs[2][64*64];
  const int z = blockIdx.y, n = z>>1, which = z&1;
  const int b0 = blockIdx.x*64;
  const float* land = (which ? qland : kland) + (size_t)n*LND*EDIM;
  const int boff = which ? 256 : 0;
  float* out = (which ? Z3 : Z1) + (size_t)n*LND*HWN;
  const u16* Yb = Y + (size_t)n*M3*HWN + boff;
  const int tid = threadIdx.x, lane = tid&63;
  const int c = tid&15, qq = (tid>>4)&3, wv = tid>>6;
  {
    int r = tid>>2, c0 = (tid&3)*64;
    const float* lp = land + (size_t)r*EDIM + c0;
    u16* dp = &As[r*LGS + c0];
    #pragma unroll
    for(int j=0;j<64;j+=4){
      float4 v = *(const float4*)(lp+j);
      ushort4 o; o.x=f2bf(v.x); o.y=f2bf(v.y); o.z=f2bf(v.z); o.w=f2bf(v.w);
      *(ushort4*)(dp+j) = o;
    }
  }
  const int srow  = wv*8 + (lane>>3);            // 0..31
  const int dslot = lane&7;
  const int sgo   = (dslot ^ (lane>>3))*8;       // row&7 == lane>>3 here
  const int rdswz = (c&7);
  f32x4 acc[4];
  #pragma unroll
  for(int nt=0;nt<4;nt++){ acc[nt][0]=0.f; acc[nt][1]=0.f; acc[nt][2]=0.f; acc[nt][3]=0.f; }
  #pragma unroll
  for(int j=0;j<2;j++){
    int r = j*32 + srow;
    gl16(Yb + (size_t)(b0+r)*M3 + sgo, &Bs[0][r*64 + dslot*8]);
  }
  __syncthreads();
  for(int ph=0; ph<4; ph++){
    const int cur = ph&1;
    if(ph<3){
      #pragma unroll
      for(int j=0;j<2;j++){
        int r = j*32 + srow;
        gl16(Yb + (size_t)(b0+r)*M3 + (ph+1)*64 + sgo, &Bs[cur^1][r*64 + dslot*8]);
      }
    }
    #pragma unroll
    for(int kt=0;kt<2;kt++){
      short8 af = *(const short8*)&As[(16*wv + c)*LGS + ph*64 + kt*32 + qq*8];
      const int rslot = ((kt*4+qq)^rdswz)*8;
      #pragma unroll
      for(int nt=0;nt<4;nt++){
        short8 bff = *(const short8*)&Bs[cur][(nt*16+c)*64 + rslot];
        acc[nt] = __builtin_amdgcn_mfma_f32_16x16x32_bf16(af, bff, acc[nt], 0, 0, 0);
      }
    }
    __syncthreads();
  }
  const int m0 = 16*wv + 4*qq;
  #pragma unroll
  for(int nt=0;nt<4;nt++){
    int col = b0 + nt*16 + c;
    out[(size_t)(m0+0)*HWN + col] = acc[nt][0];
    out[(size_t)(m0+1)*HWN + col] = acc[nt][1];
    out[(size_t)(m0+2)*HWN + col] = acc[nt][2];
    out[(size_t)(m0+3)*HWN + col] = acc[nt][3];
  }
}

// ---------------- NS 64x64 matmul via bf16 MFMA ----------------
__device__ __forceinline__ void ns_mm(const u16* L, const u16* Rt, int wv, int q, int c, f32x4 r4[4]){
  short8 a0 = *(const short8*)(L + (size_t)(16*wv + c)*NS2 + 8*q);
  short8 a1 = *(const short8*)(L + (size_t)(16*wv + c)*NS2 + 32 + 8*q);
  #pragma unroll
  for(int tc=0;tc<4;tc++){
    f32x4 acc = {0.f,0.f,0.f,0.f};
    short8 b0 = *(const short8*)(Rt + (size_t)(16*tc + c)*NS2 + 8*q);
    short8 b1 = *(const short8*)(Rt + (size_t)(16*tc + c)*NS2 + 32 + 8*q);
    acc = __builtin_amdgcn_mfma_f32_16x16x32_bf16(a0, b0, acc, 0, 0, 0);
    acc = __builtin_amdgcn_mfma_f32_16x16x32_bf16(a1, b1, acc, 0, 0, 0);
    r4[tc] = acc;
  }
}

// ---------------- NS body (k2 + Newton-Schulz pseudo-inverse), runs inside k_mega ----------------
__device__ void ns_body(int n, char* smem, const float* __restrict__ qland,
                        const float* __restrict__ kland, float* __restrict__ KinvT){
  u16* Kb  = (u16*)(smem + 0);
  u16* Vb  = (u16*)(smem + 9216);
  u16* Vt  = (u16*)(smem + 18432);
  u16* KVb = (u16*)(smem + 27648);
  u16* KVt = (u16*)(smem + 36864);
  u16* Tt  = (u16*)(smem + 46080);
  float* sS   = (float*)(smem + 55296);
  float* sred = (float*)(smem + 72704);
  const int tid = threadIdx.x;
  const int wv = tid>>6, q = (tid>>4)&3, c = tid&15;
  const float* qb = qland + (size_t)n*LND*EDIM;
  const float* kb = kland + (size_t)n*LND*EDIM;
  f32x4 acc[4];
  #pragma unroll
  for(int t=0;t<4;t++){ acc[t][0]=0.f; acc[t][1]=0.f; acc[t][2]=0.f; acc[t][3]=0.f; }
  for(int e0=0;e0<EDIM;e0+=64){
    __syncthreads();
    {
      int row = tid>>2, c0 = (tid&3)*16;
      const float* qp = qb + (size_t)row*EDIM + e0 + c0;
      const float* kp = kb + (size_t)row*EDIM + e0 + c0;
      u16* qd = &KVb[row*NS2 + c0];
      u16* kd = &KVt[row*NS2 + c0];
      #pragma unroll
      for(int j=0;j<16;j+=4){
        float4 qv = *(const float4*)(qp+j);
        float4 kv = *(const float4*)(kp+j);
        ushort4 qo, ko;
        qo.x=f2bf(qv.x); qo.y=f2bf(qv.y); qo.z=f2bf(qv.z); qo.w=f2bf(qv.w);
        ko.x=f2bf(kv.x); ko.y=f2bf(kv.y); ko.z=f2bf(kv.z); ko.w=f2bf(kv.w);
        *(ushort4*)(qd+j) = qo;
        *(ushort4*)(kd+j) = ko;
      }
    }
    __syncthreads();
    {
      short8 a0 = *(const short8*)&KVb[(16*wv+c)*NS2 + 8*q];
      short8 a1 = *(const short8*)&KVb[(16*wv+c)*NS2 + 32 + 8*q];
      #pragma unroll
      for(int tc=0;tc<4;tc++){
        short8 b0 = *(const short8*)&KVt[(16*tc+c)*NS2 + 8*q];
        short8 b1 = *(const short8*)&KVt[(16*tc+c)*NS2 + 32 + 8*q];
        acc[tc] = __builtin_amdgcn_mfma_f32_16x16x32_bf16(a0, b0, acc[tc], 0, 0, 0);
        acc[tc] = __builtin_amdgcn_mfma_f32_16x16x32_bf16(a1, b1, acc[tc], 0, 0, 0);
      }
    }
  }
  #pragma unroll
  for(int tc=0;tc<4;tc++){
    int col = 16*tc + c, row0 = 16*wv + 4*q;
    sS[(row0+0)*68+col] = acc[tc][0];
    sS[(row0+1)*68+col] = acc[tc][1];
    sS[(row0+2)*68+col] = acc[tc][2];
    sS[(row0+3)*68+col] = acc[tc][3];
  }
  __syncthreads();
  if(tid < 64){
    int j = tid;
    float m = -1e30f;
    for(int i=0;i<64;i++) m = fmaxf(m, sS[i*68+j]);
    float ssum = 0.f;
    for(int i=0;i<64;i++) ssum += __expf(sS[i*68+j]-m);
    float inv = 1.f/ssum, cs = 0.f;
    for(int i=0;i<64;i++){
      float kv = __expf(sS[i*68+j]-m)*inv;
      cs += fabsf(kv);
      Kb[i*NS2+j] = f2bf(kv);
    }
    sred[j] = cs;
  }
  __syncthreads();
  if(tid < 64){
    int i = tid; float rs = 0.f;
    for(int j=0;j<64;j++) rs += fabsf(bf2f(Kb[i*NS2+j]));
    sred[64+i] = rs;
  }
  __syncthreads();
  if(tid == 0){
    float v0=-1e30f, vi=-1e30f;
    for(int t=0;t<64;t++){ v0 = fmaxf(v0, sred[t]); vi = fmaxf(vi, sred[64+t]); }
    sred[128] = 1.f/(v0*vi);
  }
  __syncthreads();
  {
    float sc = sred[128];
    int i = tid>>2, j16 = (tid&3)*16;
    #pragma unroll
    for(int jj=0;jj<16;jj++){
      int j = j16+jj;
      u16 bvv = f2bf(bf2f(Kb[j*NS2+i])*sc);
      Vb[i*NS2+j] = bvv;
      Vt[j*NS2+i] = bvv;
    }
  }
  __syncthreads();
  f32x4 r4[4];
  for(int it=0; it<6; it++){
    ns_mm(Kb, Vt, wv, q, c, r4);
    #pragma unroll
    for(int tc=0;tc<4;tc++){
      int col = 16*tc + c, row0 = 16*wv + 4*q;
      ushort4 pk;
      pk.x = f2bf(r4[tc][0]); pk.y = f2bf(r4[tc][1]); pk.z = f2bf(r4[tc][2]); pk.w = f2bf(r4[tc][3]);
      KVb[(row0+0)*NS2+col] = pk.x; KVb[(row0+1)*NS2+col] = pk.y;
      KVb[(row0+2)*NS2+col] = pk.z; KVb[(row0+3)*NS2+col] = pk.w;
      *(ushort4*)&KVt[(size_t)col*NS2 + row0] = pk;
    }
    __syncthreads();
    ns_mm(KVb, KVt, wv, q, c, r4);
    #pragma unroll
    for(int tc=0;tc<4;tc++){
      int col = 16*tc+c, row0 = 16*wv+4*q;
      ushort4 pk;
      #pragma unroll
      for(int r=0;r<4;r++){
        float kvv = bf2f(KVb[(row0+r)*NS2+col]);
        ((u16*)&pk)[r] = f2bf(7.f*kvv - r4[tc][r]);
      }
      *(ushort4*)&Tt[(size_t)col*NS2 + row0] = pk;
    }
    __syncthreads();
    ns_mm(KVb, Tt, wv, q, c, r4);
    __syncthreads();
    #pragma unroll
    for(int tc=0;tc<4;tc++){
      int col = 16*tc+c, row0 = 16*wv+4*q;
      ushort4 pk;
      #pragma unroll
      for(int r=0;r<4;r++){
        float kvv = bf2f(KVb[(row0+r)*NS2+col]);
        ((u16*)&pk)[r] = f2bf(15.f*kvv - r4[tc][r]);
      }
      *(ushort4*)&Tt[(size_t)col*NS2 + row0] = pk;
    }
    __syncthreads();
    ns_mm(Vb, Tt, wv, q, c, r4);
    __syncthreads();
    #pragma unroll
    for(int tc=0;tc<4;tc++){
      int col = 16*tc+c, row0 = 16*wv+4*q;
      float nv[4]; ushort4 pk;
      #pragma unroll
      for(int r=0;r<4;r++){
        float vv = bf2f(Vb[(row0+r)*NS2+col]);
        nv[r] = 0.25f*(13.f*vv - r4[tc][r]);
        u16 bb = f2bf(nv[r]);
        Vb[(row0+r)*NS2+col] = bb;
        ((u16*)&pk)[r] = bb;
      }
      *(ushort4*)&Vt[(size_t)col*NS2 + row0] = pk;
      if(it==5){
        *(float4*)&KinvT[(size_t)n*4096 + (size_t)col*64 + row0] = make_float4(nv[0],nv[1],nv[2],nv[3]);
      }
    }
    __syncthreads();
  }
}

// ---------------- f body: soft3 + k3@v partial into part[n][kc][64][eb..eb+128] ----------------
#define NSTR 76
__device__ void f_body(int idx, char* smem, const float* __restrict__ Z3, const u16* __restrict__ Y,
                       float* __restrict__ part){
  const int kc = idx&31, n = (idx>>5)&7, eh = idx>>8;
  const int tid = threadIdx.x;
  const int jb = kc*128, eb = eh*128;
  float* Sf = (float*)smem;              // [64][132] raw logits
  u16* k3T  = (u16*)(smem + 33792);      // [128][NSTR] post-softmax bf16
  const float* z3b = Z3 + (size_t)n*LND*HWN;
  {
    int ibase = (tid>>5)*8, j4 = (tid&31)*4;
    #pragma unroll
    for(int r=0;r<8;r++){
      int i = ibase + r;
      *(float4*)&Sf[i*132 + j4] = *(const float4*)&z3b[(size_t)i*HWN + jb + j4];
    }
  }
  __syncthreads();
  if(tid < 128){
    int j = tid;
    float m = -1e30f;
    for(int i=0;i<64;i++) m = fmaxf(m, Sf[i*132 + j]);
    float s = 0.f;
    for(int i=0;i<64;i++){ float e = __expf(Sf[i*132 + j] - m); Sf[i*132 + j] = e; s += e; }
    float inv = 1.f/s;
    u16* kr = &k3T[j*NSTR];
    for(int i=0;i<64;i+=4){
      ushort4 o;
      o.x = f2bf(Sf[(i+0)*132 + j]*inv);
      o.y = f2bf(Sf[(i+1)*132 + j]*inv);
      o.z = f2bf(Sf[(i+2)*132 + j]*inv);
      o.w = f2bf(Sf[(i+3)*132 + j]*inv);
      *(ushort4*)(kr + i) = o;
    }
  }
  __syncthreads();
  const int i0 = (tid>>4)*4, e0 = eb + (tid&15)*8;
  const u16* Yb = Y + (size_t)n*M3*HWN;
  float acc[4][8] = {};
  for(int j=0;j<128;j++){
    ushort4 av = *(const ushort4*)&k3T[(size_t)j*NSTR + i0];
    float a0 = bf2f(av.x), a1 = bf2f(av.y), a2 = bf2f(av.z), a3 = bf2f(av.w);
    const u16* vp = Yb + (size_t)(jb+j)*M3 + 512 + e0;
    uint4 U0 = *(const uint4*)vp;
    float bv[8];
    bf2x2(U0.x, bv[0], bv[1]);  bf2x2(U0.y, bv[2], bv[3]);
    bf2x2(U0.z, bv[4], bv[5]);  bf2x2(U0.w, bv[6], bv[7]);
    #pragma unroll
    for(int u=0;u<8;u++){
      acc[0][u] += a0*bv[u];
      acc[1][u] += a1*bv[u];
      acc[2][u] += a2*bv[u];
      acc[3][u] += a3*bv[u];
    }
  }
  float* pb = part + ((size_t)n*32 + kc)*LND*EDIM;
  #pragma unroll
  for(int s=0;s<4;s++)
    #pragma unroll
    for(int t=0;t<8;t+=4){
      float4 fv = make_float4(acc[s][t],acc[s][t+1],acc[s][t+2],acc[s][t+3]);
      *(float4*)&pb[(size_t)(i0+s)*EDIM + e0 + t] = fv;
    }
}

// ---------------- soft1 body: softmax of Z1 over contiguous 4096 ----------------
__device__ void soft1_body(int b, char* smem, float* __restrict__ Z1){
  const int n = b>>6, j = b&63, tid = threadIdx.x;
  float* redm = (float*)smem;
  float* reds = redm + 4;
  float* base = Z1 + ((size_t)n*LND + j)*HWN;
  float v[16];
  float m = -1e30f;
  #pragma unroll
  for(int r=0;r<16;r++){ v[r] = base[r*256 + tid]; m = fmaxf(m, v[r]); }
  #pragma unroll
  for(int o=32;o;o>>=1) m = fmaxf(m, __shfl_xor(m, o));
  const int wid = tid>>6;
  if((tid&63)==0) redm[wid] = m;
  __syncthreads();
  m = fmaxf(fmaxf(redm[0],redm[1]), fmaxf(redm[2],redm[3]));
  float s = 0.f;
  #pragma unroll
  for(int r=0;r<16;r++){ v[r] = __expf(v[r]-m); s += v[r]; }
  #pragma unroll
  for(int o=32;o;o>>=1) s += __shfl_xor(s, o);
  if((tid&63)==0) reds[wid] = s;
  __syncthreads();
  s = reds[0]+reds[1]+reds[2]+reds[3];
  float inv = 1.f/s;
  #pragma unroll
  for(int r=0;r<16;r++) base[r*256 + tid] = v[r]*inv;
}

// ---------------- mega kernel: blocks 0-7 NS, 8-519 f, 520-1031 soft1 (all independent) ------
// No atomics: f writes to part[], reduced by k_fred (HIP fp32 atomicAdd = CAS loop, 139MB
// write storm measured in round 3).
__global__ __launch_bounds__(256) void k_mega(const float* __restrict__ Z3, const u16* __restrict__ Y,
                                              float* __restrict__ part, float* __restrict__ Z1,
                                              const float* __restrict__ qland, const float* __restrict__ kland,
                                              float* __restrict__ KinvT){
  __shared__ __align__(16) char smem[73728];
  const int bi = blockIdx.x;
  if(bi < 8)        ns_body(bi, smem, qland, kland, KinvT);
  else if(bi < 520) f_body(bi-8, smem, Z3, Y, part);
  else              soft1_body(bi-520, smem, Z1);
}

__global__ void k_fred(const float* __restrict__ part, float* __restrict__ B3){
  const int idx = blockIdx.x*256 + threadIdx.x;
  const int n = idx >> 14, rem = idx & 16383;
  const float* p = part + (size_t)n*32*16384 + rem;
  float s = 0.f;
  #pragma unroll
  for(int kc=0;kc<32;kc++) s += p[(size_t)kc*16384];
  B3[idx] = s;
}

// ---------------- C2[j][e] = sum_l Kinv[j][l]*B3[l][e] ----------------
__global__ __launch_bounds__(256) void k_c2(const float* __restrict__ KinvT, const float* __restrict__ B3,
                                            float* __restrict__ C2){
  const int eb = blockIdx.x*64, n = blockIdx.y, tid = threadIdx.x;
  __shared__ float KT[64][68];
  __shared__ float Bs2[64][68];
  {
    int l = tid>>2, o16 = (tid&3)*16;
    const float* kp = KinvT + (size_t)n*4096 + l*64 + o16;
    const float* bp = B3 + ((size_t)n*LND + l)*EDIM + eb + o16;
    #pragma unroll
    for(int t=0;t<16;t+=4){
      *(float4*)&KT[l][o16+t]  = *(const float4*)(kp+t);
      *(float4*)&Bs2[l][o16+t] = *(const float4*)(bp+t);
    }
  }
  __syncthreads();
  const int j0 = (tid>>4)*4, u0 = (tid&15)*4;
  float acc[4][4] = {};
  #pragma unroll 8
  for(int l=0;l<64;l++){
    f32x4 a = *(f32x4*)&KT[l][j0];
    f32x4 b = *(f32x4*)&Bs2[l][u0];
    #pragma unroll
    for(int s=0;s<4;s++)
      #pragma unroll
      for(int u=0;u<4;u++) acc[s][u] += a[s]*b[u];
  }
  #pragma unroll
  for(int s=0;s<4;s++){
    float4 fv = make_float4(acc[s][0],acc[s][1],acc[s][2],acc[s][3]);
    *(float4*)&C2[((size_t)n*LND + j0+s)*EDIM + eb + u0] = fv;
  }
}

// ---------------- out[i][e] = sum_j k1t[j][i]*C2[j][e] + v[i][e]; OM bf16 ----------------
__global__ __launch_bounds__(256) void k_out(const float* __restrict__ Z1, const float* __restrict__ C2,
                                             const u16* __restrict__ Y, u16* __restrict__ OM){
  const int ib = blockIdx.x*64, n = blockIdx.y, tid = threadIdx.x;
  __shared__ float K1s[64][68];
  __shared__ u16 C2s[64*264];
  {
    int j = tid>>2, i16 = (tid&3)*16;
    const float* zp = Z1 + ((size_t)n*LND + j)*HWN + ib + i16;
    #pragma unroll
    for(int t=0;t<16;t+=4) *(float4*)&K1s[j][i16+t] = *(const float4*)(zp+t);
    int e64 = (tid&3)*64;
    const float* cp = C2 + ((size_t)n*LND + j)*EDIM + e64;
    #pragma unroll
    for(int t=0;t<64;t+=4){
      float4 v = *(const float4*)(cp+t);
      C2s[j*264 + e64+t+0] = f2bf(v.x);
      C2s[j*264 + e64+t+1] = f2bf(v.y);
      C2s[j*264 + e64+t+2] = f2bf(v.z);
      C2s[j*264 + e64+t+3] = f2bf(v.w);
    }
  }
  __syncthreads();
  const int i0 = (tid>>4)*4, e0 = (tid&15)*16;
  float acc[4][16] = {};
  for(int j=0;j<64;j++){
    f32x4 a = *(f32x4*)&K1s[j][i0];
    const u16* cb = &C2s[j*264 + e0];
    uint4 U0 = *(const uint4*)cb;
    uint4 U1 = *(const uint4*)(cb+8);
    float bv[16];
    bf2x2(U0.x, bv[0], bv[1]);  bf2x2(U0.y, bv[2], bv[3]);
    bf2x2(U0.z, bv[4], bv[5]);  bf2x2(U0.w, bv[6], bv[7]);
    bf2x2(U1.x, bv[8], bv[9]);  bf2x2(U1.y, bv[10], bv[11]);
    bf2x2(U1.z, bv[12], bv[13]); bf2x2(U1.w, bv[14], bv[15]);
    #pragma unroll
    for(int u=0;u<16;u++){
      acc[0][u] += a[0]*bv[u];
      acc[1][u] += a[1]*bv[u];
      acc[2][u] += a[2]*bv[u];
      acc[3][u] += a[3]*bv[u];
    }
  }
  const u16* Yb = Y + (size_t)n*M3*HWN;
  u16* ob = OM + (size_t)n*HWN*EDIM;
  #pragma unroll
  for(int s=0;s<4;s++){
    int i = ib + i0 + s;
    const u16* vp = Yb + (size_t)i*M3 + 512 + e0;
    uint4 U0 = *(const uint4*)vp, U1 = *(const uint4*)(vp+8);
    float vv[16];
    bf2x2(U0.x, vv[0], vv[1]);  bf2x2(U0.y, vv[2], vv[3]);
    bf2x2(U0.z, vv[4], vv[5]);  bf2x2(U0.w, vv[6], vv[7]);
    bf2x2(U1.x, vv[8], vv[9]);  bf2x2(U1.y, vv[10], vv[11]);
    bf2x2(U1.z, vv[12], vv[13]); bf2x2(U1.w, vv[14], vv[15]);
    #pragma unroll
    for(int t=0;t<16;t+=4){
      ushort4 o;
      o.x = f2bf(acc[s][t+0]+vv[t+0]);
      o.y = f2bf(acc[s][t+1]+vv[t+1]);
      o.z = f2bf(acc[s][t+2]+vv[t+2]);
      o.w = f2bf(acc[s][t+3]+vv[t+3]);
      *(ushort4*)&ob[(size_t)i*EDIM + e0 + t] = o;
    }
  }
}

// ---------------- transpose of raw-reshaped OM ----------------
__global__ __launch_bounds__(256) void k_trans2(const u16* __restrict__ OM, u16* __restrict__ OMT){
  __shared__ u16 Ts[64*65];
  const int bi = blockIdx.x;
  const int n = bi>>8, rem = bi&255, et = rem>>6, pt = rem&63;
  const int e0 = et*64, p0 = pt*64, tid = threadIdx.x;
  const u16* omb = OM + (size_t)n*HWN*EDIM;
  {
    int ee = tid>>2, pj = (tid&3)*16;
    const u16* ip = omb + (size_t)(e0+ee)*HWN + p0 + pj;
    ushort4 v0 = *(const ushort4*)(ip);
    ushort4 v1 = *(const ushort4*)(ip+4);
    ushort4 v2 = *(const ushort4*)(ip+8);
    ushort4 v3 = *(const ushort4*)(ip+12);
    u16* tp = &Ts[ee*65 + pj];
    tp[0]=v0.x; tp[1]=v0.y; tp[2]=v0.z; tp[3]=v0.w;
    tp[4]=v1.x; tp[5]=v1.y; tp[6]=v1.z; tp[7]=v1.w;
    tp[8]=v2.x; tp[9]=v2.y; tp[10]=v2.z; tp[11]=v2.w;
    tp[12]=v3.x; tp[13]=v3.y; tp[14]=v3.z; tp[15]=v3.w;
  }
  __syncthreads();
  {
    int pp = tid>>2, ej = (tid&3)*16;
    u16* op = OMT + ((size_t)n*HWN + p0 + pp)*EDIM + e0 + ej;
    ushort4 o[4];
    #pragma unroll
    for(int j=0;j<16;j++) ((u16*)o)[j] = Ts[(ej+j)*65 + pp];
    *(ushort4*)(op+0)  = o[0];
    *(ushort4*)(op+4)  = o[1];
    *(ushort4*)(op+8)  = o[2];
    *(ushort4*)(op+12) = o[3];
  }
}

// ---------------- proj GEMM 128x128xK256, global_load_lds + XOR swizzle ----------------
__global__ __launch_bounds__(256) void k_proj(const u16* __restrict__ Wb, const u16* __restrict__ OMT,
                                              const float* __restrict__ bias, float* __restrict__ out){
  __shared__ __align__(16) u16 As[128*64];
  __shared__ __align__(16) u16 Bs[128*64];
  const int bi = blockIdx.x;
  const int n = bi&7, rem = bi>>3;
  const int ch0 = (rem&1)*128, p0 = (rem>>1)*128;
  const int tid = threadIdx.x, lane = tid&63;
  const int c = tid&15, qq = (tid>>4)&3, w4 = tid>>6;
  const int wr0 = (w4&1)*64, wc0 = (w4>>1)*64;
  const u16* xb = OMT + ((size_t)n*HWN + p0)*EDIM;
  const u16* wb = Wb + (size_t)ch0*EDIM;
  f32x4 acc[4][4];
  #pragma unroll
  for(int mt=0;mt<4;mt++)
    #pragma unroll
    for(int nt=0;nt<4;nt++){ acc[mt][nt][0]=0.f; acc[mt][nt][1]=0.f; acc[mt][nt][2]=0.f; acc[mt][nt][3]=0.f; }
  const int srow  = w4*8 + (lane>>3);
  const int dslot = lane&7;
  const int sgo   = (dslot ^ (lane>>3))*8;
  const int rdswz = (c&7);
  for(int ph=0; ph<4; ph++){
    #pragma unroll
    for(int j=0;j<4;j++){
      int r = j*32 + srow;
      gl16(wb + (size_t)r*EDIM + ph*64 + sgo, &As[r*64 + dslot*8]);
    }
    #pragma unroll
    for(int j=0;j<4;j++){
      int r = j*32 + srow;
      gl16(xb + (size_t)r*EDIM + ph*64 + sgo, &Bs[r*64 + dslot*8]);
    }
    __syncthreads();
    #pragma unroll
    for(int kt=0;kt<2;kt++){
      short8 af[4], bff[4];
      const int rslot = ((kt*4+qq)^rdswz)*8;
      #pragma unroll
      for(int mt=0;mt<4;mt++) af[mt]  = *(const short8*)&As[(wr0+mt*16+c)*64 + rslot];
      #pragma unroll
      for(int nt=0;nt<4;nt++) bff[nt] = *(const short8*)&Bs[(wc0+nt*16+c)*64 + rslot];
      #pragma unroll
      for(int mt=0;mt<4;mt++)
        #pragma unroll
        for(int nt=0;nt<4;nt++)
          acc[mt][nt] = __builtin_amdgcn_mfma_f32_16x16x32_bf16(af[mt], bff[nt], acc[mt][nt], 0, 0, 0);
    }
    __syncthreads();
  }
  float* ob = out + (size_t)n*EDIM*HWN;
  #pragma unroll
  for(int mt=0;mt<4;mt++){
    int chb = ch0 + wr0 + mt*16 + 4*qq;
    float b0 = bias[chb], b1 = bias[chb+1], b2 = bias[chb+2], b3 = bias[chb+3];
    #pragma unroll
    for(int nt=0;nt<4;nt++){
      int p = p0 + wc0 + nt*16 + c;
      float* yp = ob + (size_t)chb*HWN + p;
      yp[0]             = acc[mt][nt][0]+b0;
      yp[HWN]           = acc[mt][nt][1]+b1;
      yp[2*(size_t)HWN] = acc[mt][nt][2]+b2;
      yp[3*(size_t)HWN] = acc[mt][nt][3]+b3;
    }
  }
}

extern "C" void kernel_launch(void* const* d_in, const int* in_sizes, int n_in,
                              void* d_out, int out_size, void* d_ws, size_t ws_size,
                              hipStream_t stream){
  (void)out_size; (void)ws_size;
  const float* x     = (const float*)d_in[0];
  const float* w_qkv = (const float*)d_in[1];
  const float* b_qkv = (const float*)d_in[2];
  const float* w_out = (const float*)d_in[3];
  const float* b_out = (const float*)d_in[4];
  for(int i=0;i<n_in;i++){
    switch(in_sizes[i]){
      case 8388608: x     = (const float*)d_in[i]; break;
      case 196608:  w_qkv = (const float*)d_in[i]; break;
      case 768:     b_qkv = (const float*)d_in[i]; break;
      case 65536:   w_out = (const float*)d_in[i]; break;
      case 256:     b_out = (const float*)d_in[i]; break;
      default: break;
    }
  }
  float* out = (float*)d_out;
  char* ws = (char*)d_ws;

  u16*   Y     = (u16*)(ws + 0);              // 50,331,648 B  bf16 [8][768*4096]
  float* qland = (float*)(ws + 50331648);
  float* kland = (float*)(ws + 50855936);
  float* Z1    = (float*)(ws + 51380224);
  float* Z3    = (float*)(ws + 59768832);
  float* KinvT = (float*)(ws + 68157440);
  u16*   Xt    = (u16*)(ws + 68288512);       // 16 MB region: Xt -> part -> OMT
  float* part  = (float*)(ws + 68288512);
  u16*   OMT   = (u16*)(ws + 68288512);
  float* B3    = (float*)(ws + 85065728);
  float* C2    = (float*)(ws + 85590016);
  u16*   OM    = (u16*)(ws + 86114304);       // 16 MB bf16
  // Wqb overlaps Z3 (Z3 written by k_landgemm AFTER k_qkv consumes Wqb — stream-ordered safe)
  u16*   Wqb   = (u16*)(ws + 59768832);       // 393,216 B bf16 [768][256]
  u16*   Wob   = (u16*)(ws + 102891520);      // 131,072 B bf16 [256][256] (persists to k_proj)

  k_prep    <<<dim3(2056),   256, 0, stream>>>(x, Xt, w_qkv, w_out, Wqb, Wob);
  k_qkv     <<<dim3(1536),   256, 0, stream>>>(Wqb, Xt, b_qkv, Y);
  k_land    <<<dim3(64,8),   256, 0, stream>>>(Y, qland, kland);
  k_landgemm<<<dim3(64,16),  256, 0, stream>>>(Y, qland, kland, Z1, Z3);
  k_mega    <<<dim3(1032),   256, 0, stream>>>(Z3, Y, part, Z1, qland, kland, KinvT);
  k_fred    <<<dim3(512),    256, 0, stream>>>(part, B3);
  k_c2      <<<dim3(4,8),    256, 0, stream>>>(KinvT, B3, C2);
  k_out     <<<dim3(64,8),   256, 0, stream>>>(Z1, C2, Y, OM);
  k_trans2  <<<dim3(2048),   256, 0, stream>>>(OM, OMT);
  k_proj    <<<dim3(512),    256, 0, stream>>>(Wob, OMT, b_out, out);
}

// Round 5
// 237.059 us; speedup vs baseline: 1.4396x; 1.0292x over previous
//
#include <hip/hip_runtime.h>
#include <hip/hip_bf16.h>

typedef unsigned short u16;
typedef __attribute__((ext_vector_type(4))) float f32x4;
typedef __attribute__((ext_vector_type(8))) short short8;

#define NB   8
#define CIN  256
#define EDIM 256
#define M3   768
#define HWN  4096
#define LND  64
#define NS2  72    // NS LDS row stride (bf16 elems): 144B, 16B aligned

__device__ __forceinline__ float bf2f(u16 u){ return __uint_as_float(((unsigned)u)<<16); }
__device__ __forceinline__ u16 f2bf(float f){ __hip_bfloat16 h = __float2bfloat16(f); return *reinterpret_cast<u16*>(&h); }
__device__ __forceinline__ void bf2x2(unsigned u, float &lo, float &hi){
  lo = __uint_as_float(u<<16);
  hi = __uint_as_float(u & 0xffff0000u);
}

typedef __attribute__((address_space(1))) unsigned as1_uint;
typedef __attribute__((address_space(3))) unsigned as3_uint;
// async global->LDS, 16B per lane; dest must be wave-uniform base + lane*16
__device__ __forceinline__ void gl16(const void* g, void* l){
  __builtin_amdgcn_global_load_lds((const as1_uint*)g, (as3_uint*)l, 16, 0, 0);
}

// ---------------- prep: Xt[n][p][c] (bf16) = transpose of X[n][c][p] (fp32) ----------------
// blocks >= 2048: convert w_qkv / w_out to bf16 (once, instead of per GEMM block)
__global__ __launch_bounds__(256) void k_prep(const float* __restrict__ x, u16* __restrict__ Xt,
                                              const float* __restrict__ wq, const float* __restrict__ wo,
                                              u16* __restrict__ Wqb, u16* __restrict__ Wob){
  const int bi = blockIdx.x;
  const int tid = threadIdx.x;
  if(bi >= 2048){
    int ti = (bi-2048)*256 + tid;          // 0..2047
    const float* src; u16* dst;
    if(ti < 1536){ src = wq + (size_t)ti*128;        dst = Wqb + (size_t)ti*128; }
    else         { src = wo + (size_t)(ti-1536)*128; dst = Wob + (size_t)(ti-1536)*128; }
    #pragma unroll
    for(int t=0;t<128;t+=8){
      float4 v0 = *(const float4*)(src+t);
      float4 v1 = *(const float4*)(src+t+4);
      ushort4 o0, o1;
      o0.x=f2bf(v0.x); o0.y=f2bf(v0.y); o0.z=f2bf(v0.z); o0.w=f2bf(v0.w);
      o1.x=f2bf(v1.x); o1.y=f2bf(v1.y); o1.z=f2bf(v1.z); o1.w=f2bf(v1.w);
      *(ushort4*)(dst+t)   = o0;
      *(ushort4*)(dst+t+4) = o1;
    }
    return;
  }
  __shared__ float Ts[64*65];
  const int n = bi>>8, rem = bi&255, ct = rem>>6, pt = rem&63;
  const int c0 = ct*64, p0 = pt*64;
  {
    int cc = tid>>2, pj = (tid&3)*16;
    const float* xp = x + (size_t)n*CIN*HWN + (size_t)(c0+cc)*HWN + p0 + pj;
    #pragma unroll
    for(int j=0;j<16;j++) Ts[cc*65 + pj + j] = xp[j];
  }
  __syncthreads();
  {
    int pp = tid>>2, ej = (tid&3)*16;
    u16* op = Xt + ((size_t)n*HWN + p0 + pp)*CIN + c0 + ej;
    ushort4 o[4];
    #pragma unroll
    for(int j=0;j<16;j++) ((u16*)o)[j] = f2bf(Ts[(ej+j)*65 + pp]);
    *(ushort4*)(op+0)  = o[0];
    *(ushort4*)(op+4)  = o[1];
    *(ushort4*)(op+8)  = o[2];
    *(ushort4*)(op+12) = o[3];
  }
}

// ---------------- QKV GEMM 128x128xK256 bf16 MFMA, global_load_lds + XOR swizzle ------------
__global__ __launch_bounds__(256) void k_qkv(const u16* __restrict__ Wb, const u16* __restrict__ Xt,
                                             const float* __restrict__ bias, u16* __restrict__ Y){
  __shared__ __align__(16) u16 As[128*64];
  __shared__ __align__(16) u16 Bs[128*64];
  const int bi = blockIdx.x;
  const int n = bi&7, rem = bi>>3;
  const int ch0 = (rem%6)*128, p0 = (rem/6)*128;
  const int tid = threadIdx.x, lane = tid&63;
  const int c = tid&15, qq = (tid>>4)&3, w4 = tid>>6;
  const int wr0 = (w4&1)*64, wc0 = (w4>>1)*64;
  const u16* xb = Xt + ((size_t)n*HWN + p0)*CIN;
  const u16* wb = Wb + (size_t)ch0*CIN;
  f32x4 acc[4][4];
  #pragma unroll
  for(int mt=0;mt<4;mt++)
    #pragma unroll
    for(int nt=0;nt<4;nt++){ acc[mt][nt][0]=0.f; acc[mt][nt][1]=0.f; acc[mt][nt][2]=0.f; acc[mt][nt][3]=0.f; }
  const int srow  = w4*8 + (lane>>3);
  const int dslot = lane&7;
  const int sgo   = (dslot ^ (lane>>3))*8;       // swizzled source u16 offset within row-chunk
  const int rdswz = (c&7);                        // read-side row&7
  for(int ph=0; ph<4; ph++){
    #pragma unroll
    for(int j=0;j<4;j++){
      int r = j*32 + srow;
      gl16(wb + (size_t)r*CIN + ph*64 + sgo, &As[r*64 + dslot*8]);
    }
    #pragma unroll
    for(int j=0;j<4;j++){
      int r = j*32 + srow;
      gl16(xb + (size_t)r*CIN + ph*64 + sgo, &Bs[r*64 + dslot*8]);
    }
    __syncthreads();
    #pragma unroll
    for(int kt=0;kt<2;kt++){
      short8 af[4], bff[4];
      const int rslot = ((kt*4+qq)^rdswz)*8;
      #pragma unroll
      for(int mt=0;mt<4;mt++) af[mt]  = *(const short8*)&As[(wr0+mt*16+c)*64 + rslot];
      #pragma unroll
      for(int nt=0;nt<4;nt++) bff[nt] = *(const short8*)&Bs[(wc0+nt*16+c)*64 + rslot];
      #pragma unroll
      for(int mt=0;mt<4;mt++)
        #pragma unroll
        for(int nt=0;nt<4;nt++)
          acc[mt][nt] = __builtin_amdgcn_mfma_f32_16x16x32_bf16(af[mt], bff[nt], acc[mt][nt], 0, 0, 0);
    }
    __syncthreads();
  }
  u16* Yb = Y + (size_t)n*M3*HWN;
  #pragma unroll
  for(int mt=0;mt<4;mt++){
    int chb = ch0 + wr0 + mt*16 + 4*qq;
    float b0 = bias[chb], b1 = bias[chb+1], b2 = bias[chb+2], b3 = bias[chb+3];
    #pragma unroll
    for(int nt=0;nt<4;nt++){
      int p = p0 + wc0 + nt*16 + c;
      u16* yp = Yb + (size_t)chb*HWN + p;
      yp[0]             = f2bf(acc[mt][nt][0]+b0);
      yp[HWN]           = f2bf(acc[mt][nt][1]+b1);
      yp[2*(size_t)HWN] = f2bf(acc[mt][nt][2]+b2);
      yp[3*(size_t)HWN] = f2bf(acc[mt][nt][3]+b3);
    }
  }
}

// ---------------- landmarks ----------------
__global__ void k_land(const u16* __restrict__ Y, float* __restrict__ qland, float* __restrict__ kland){
  const int l = blockIdx.x, n = blockIdx.y, e = threadIdx.x;
  const u16* base = Y + (size_t)n*M3*HWN;
  float qs=0.f, ks=0.f;
  #pragma unroll 8
  for(int m=0;m<64;m++){
    size_t off = (size_t)(l*64+m)*M3;
    qs += bf2f(base[off+e]);
    ks += bf2f(base[off+256+e]);
  }
  qland[((size_t)n*LND+l)*EDIM+e] = qs*(1.f/4096.f);
  kland[((size_t)n*LND+l)*EDIM+e] = ks*(1.f/4096.f);
}

// ---------------- NS 64x64 matmul via bf16 MFMA (per-operand LDS row stride) ----------------
__device__ __forceinline__ void ns_mm2(const u16* L, int sL, const u16* Rt, int sR,
                                       int wv, int q, int c, f32x4 r4[4]){
  short8 a0 = *(const short8*)(L + (size_t)(16*wv + c)*sL + 8*q);
  short8 a1 = *(const short8*)(L + (size_t)(16*wv + c)*sL + 32 + 8*q);
  #pragma unroll
  for(int tc=0;tc<4;tc++){
    f32x4 acc = {0.f,0.f,0.f,0.f};
    short8 b0 = *(const short8*)(Rt + (size_t)(16*tc + c)*sR + 8*q);
    short8 b1 = *(const short8*)(Rt + (size_t)(16*tc + c)*sR + 32 + 8*q);
    acc = __builtin_amdgcn_mfma_f32_16x16x32_bf16(a0, b0, acc, 0, 0, 0);
    acc = __builtin_amdgcn_mfma_f32_16x16x32_bf16(a1, b1, acc, 0, 0, 0);
    r4[tc] = acc;
  }
}

// ---------------- NS body (k2 + Newton-Schulz pseudo-inverse) ----------------
// LDS budget 54272 B: Kb/Vb/Vt/KVb/KVt stride 72 (9216 ea), Tt stride 64 (8192).
// sS (64x66 f32) + sred alias the KVb/KVt region (dead after the k2 phase; barrier added).
#define TTS 64
__device__ void ns_body(int n, char* smem, const float* __restrict__ qland,
                        const float* __restrict__ kland, float* __restrict__ KinvT){
  u16* Kb  = (u16*)(smem + 0);
  u16* Vb  = (u16*)(smem + 9216);
  u16* Vt  = (u16*)(smem + 18432);
  u16* KVb = (u16*)(smem + 27648);
  u16* KVt = (u16*)(smem + 36864);
  u16* Tt  = (u16*)(smem + 46080);         // stride 64, 8192 B -> end 54272
  float* sS   = (float*)(smem + 27648);    // 64x66 f32 = 16896, aliases KVb/KVt
  float* sred = (float*)(smem + 44544);    // 520 B, ends 45064 < 46080
  const int tid = threadIdx.x;
  const int wv = tid>>6, q = (tid>>4)&3, c = tid&15;
  const float* qb = qland + (size_t)n*LND*EDIM;
  const float* kb = kland + (size_t)n*LND*EDIM;
  f32x4 acc[4];
  #pragma unroll
  for(int t=0;t<4;t++){ acc[t][0]=0.f; acc[t][1]=0.f; acc[t][2]=0.f; acc[t][3]=0.f; }
  for(int e0=0;e0<EDIM;e0+=64){
    __syncthreads();
    {
      int row = tid>>2, c0 = (tid&3)*16;
      const float* qp = qb + (size_t)row*EDIM + e0 + c0;
      const float* kp = kb + (size_t)row*EDIM + e0 + c0;
      u16* qd = &KVb[row*NS2 + c0];
      u16* kd = &KVt[row*NS2 + c0];
      #pragma unroll
      for(int j=0;j<16;j+=4){
        float4 qv = *(const float4*)(qp+j);
        float4 kv = *(const float4*)(kp+j);
        ushort4 qo, ko;
        qo.x=f2bf(qv.x); qo.y=f2bf(qv.y); qo.z=f2bf(qv.z); qo.w=f2bf(qv.w);
        ko.x=f2bf(kv.x); ko.y=f2bf(kv.y); ko.z=f2bf(kv.z); ko.w=f2bf(kv.w);
        *(ushort4*)(qd+j) = qo;
        *(ushort4*)(kd+j) = ko;
      }
    }
    __syncthreads();
    {
      short8 a0 = *(const short8*)&KVb[(16*wv+c)*NS2 + 8*q];
      short8 a1 = *(const short8*)&KVb[(16*wv+c)*NS2 + 32 + 8*q];
      #pragma unroll
      for(int tc=0;tc<4;tc++){
        short8 b0 = *(const short8*)&KVt[(16*tc+c)*NS2 + 8*q];
        short8 b1 = *(const short8*)&KVt[(16*tc+c)*NS2 + 32 + 8*q];
        acc[tc] = __builtin_amdgcn_mfma_f32_16x16x32_bf16(a0, b0, acc[tc], 0, 0, 0);
        acc[tc] = __builtin_amdgcn_mfma_f32_16x16x32_bf16(a1, b1, acc[tc], 0, 0, 0);
      }
    }
  }
  __syncthreads();   // KVb/KVt reads done everywhere before sS (alias) is written
  #pragma unroll
  for(int tc=0;tc<4;tc++){
    int col = 16*tc + c, row0 = 16*wv + 4*q;
    sS[(row0+0)*66+col] = acc[tc][0];
    sS[(row0+1)*66+col] = acc[tc][1];
    sS[(row0+2)*66+col] = acc[tc][2];
    sS[(row0+3)*66+col] = acc[tc][3];
  }
  __syncthreads();
  if(tid < 64){
    int j = tid;
    float m = -1e30f;
    for(int i=0;i<64;i++) m = fmaxf(m, sS[i*66+j]);
    float ssum = 0.f;
    for(int i=0;i<64;i++) ssum += __expf(sS[i*66+j]-m);
    float inv = 1.f/ssum, cs = 0.f;
    for(int i=0;i<64;i++){
      float kv = __expf(sS[i*66+j]-m)*inv;
      cs += fabsf(kv);
      Kb[i*NS2+j] = f2bf(kv);
    }
    sred[j] = cs;
  }
  __syncthreads();
  if(tid < 64){
    int i = tid; float rs = 0.f;
    for(int j=0;j<64;j++) rs += fabsf(bf2f(Kb[i*NS2+j]));
    sred[64+i] = rs;
  }
  __syncthreads();
  if(tid == 0){
    float v0=-1e30f, vi=-1e30f;
    for(int t=0;t<64;t++){ v0 = fmaxf(v0, sred[t]); vi = fmaxf(vi, sred[64+t]); }
    sred[128] = 1.f/(v0*vi);
  }
  __syncthreads();
  {
    float sc = sred[128];
    int i = tid>>2, j16 = (tid&3)*16;
    #pragma unroll
    for(int jj=0;jj<16;jj++){
      int j = j16+jj;
      u16 bvv = f2bf(bf2f(Kb[j*NS2+i])*sc);
      Vb[i*NS2+j] = bvv;
      Vt[j*NS2+i] = bvv;
    }
  }
  __syncthreads();
  f32x4 r4[4];
  for(int it=0; it<6; it++){
    ns_mm2(Kb, NS2, Vt, NS2, wv, q, c, r4);
    #pragma unroll
    for(int tc=0;tc<4;tc++){
      int col = 16*tc + c, row0 = 16*wv + 4*q;
      ushort4 pk;
      pk.x = f2bf(r4[tc][0]); pk.y = f2bf(r4[tc][1]); pk.z = f2bf(r4[tc][2]); pk.w = f2bf(r4[tc][3]);
      KVb[(row0+0)*NS2+col] = pk.x; KVb[(row0+1)*NS2+col] = pk.y;
      KVb[(row0+2)*NS2+col] = pk.z; KVb[(row0+3)*NS2+col] = pk.w;
      *(ushort4*)&KVt[(size_t)col*NS2 + row0] = pk;
    }
    __syncthreads();
    ns_mm2(KVb, NS2, KVt, NS2, wv, q, c, r4);
    #pragma unroll
    for(int tc=0;tc<4;tc++){
      int col = 16*tc+c, row0 = 16*wv+4*q;
      ushort4 pk;
      #pragma unroll
      for(int r=0;r<4;r++){
        float kvv = bf2f(KVb[(row0+r)*NS2+col]);
        ((u16*)&pk)[r] = f2bf(7.f*kvv - r4[tc][r]);
      }
      *(ushort4*)&Tt[(size_t)col*TTS + row0] = pk;
    }
    __syncthreads();
    ns_mm2(KVb, NS2, Tt, TTS, wv, q, c, r4);
    __syncthreads();
    #pragma unroll
    for(int tc=0;tc<4;tc++){
      int col = 16*tc+c, row0 = 16*wv+4*q;
      ushort4 pk;
      #pragma unroll
      for(int r=0;r<4;r++){
        float kvv = bf2f(KVb[(row0+r)*NS2+col]);
        ((u16*)&pk)[r] = f2bf(15.f*kvv - r4[tc][r]);
      }
      *(ushort4*)&Tt[(size_t)col*TTS + row0] = pk;
    }
    __syncthreads();
    ns_mm2(Vb, NS2, Tt, TTS, wv, q, c, r4);
    __syncthreads();
    #pragma unroll
    for(int tc=0;tc<4;tc++){
      int col = 16*tc+c, row0 = 16*wv+4*q;
      float nv[4]; ushort4 pk;
      #pragma unroll
      for(int r=0;r<4;r++){
        float vv = bf2f(Vb[(row0+r)*NS2+col]);
        nv[r] = 0.25f*(13.f*vv - r4[tc][r]);
        u16 bb = f2bf(nv[r]);
        Vb[(row0+r)*NS2+col] = bb;
        ((u16*)&pk)[r] = bb;
      }
      *(ushort4*)&Vt[(size_t)col*NS2 + row0] = pk;
      if(it==5){
        *(float4*)&KinvT[(size_t)n*4096 + (size_t)col*64 + row0] = make_float4(nv[0],nv[1],nv[2],nv[3]);
      }
    }
    __syncthreads();
  }
}

// ---------------- Z1/Z3 landmark GEMM + fused NS (blockIdx.x==64) --------------------------
// Union LDS 54272 B: landgemm uses As(33792)+Bs(16384)=50176; ns uses full 54272.
#define LGS 264   // A LDS row stride (u16): 528B, 16B aligned, bank-conflict-free
__global__ __launch_bounds__(256) void k_landgemm(const u16* __restrict__ Y, const float* __restrict__ qland,
                                                  const float* __restrict__ kland, float* __restrict__ Z1,
                                                  float* __restrict__ Z3, float* __restrict__ KinvT){
  __shared__ __align__(16) char usm[54272];
  const int z = blockIdx.y;
  if(blockIdx.x == 64){
    if((z&1)==0) ns_body(z>>1, usm, qland, kland, KinvT);
    return;
  }
  u16* As = (u16*)usm;                 // [64][LGS]
  u16* BsU = (u16*)(usm + 33792);      // [2][64*64]
  const int n = z>>1, which = z&1;
  const int b0 = blockIdx.x*64;
  const float* land = (which ? qland : kland) + (size_t)n*LND*EDIM;
  const int boff = which ? 256 : 0;
  float* out = (which ? Z3 : Z1) + (size_t)n*LND*HWN;
  const u16* Yb = Y + (size_t)n*M3*HWN + boff;
  const int tid = threadIdx.x, lane = tid&63;
  const int c = tid&15, qq = (tid>>4)&3, wv = tid>>6;
  {
    int r = tid>>2, c0 = (tid&3)*64;
    const float* lp = land + (size_t)r*EDIM + c0;
    u16* dp = &As[r*LGS + c0];
    #pragma unroll
    for(int j=0;j<64;j+=4){
      float4 v = *(const float4*)(lp+j);
      ushort4 o; o.x=f2bf(v.x); o.y=f2bf(v.y); o.z=f2bf(v.z); o.w=f2bf(v.w);
      *(ushort4*)(dp+j) = o;
    }
  }
  const int srow  = wv*8 + (lane>>3);            // 0..31
  const int dslot = lane&7;
  const int sgo   = (dslot ^ (lane>>3))*8;       // row&7 == lane>>3 here
  const int rdswz = (c&7);
  f32x4 acc[4];
  #pragma unroll
  for(int nt=0;nt<4;nt++){ acc[nt][0]=0.f; acc[nt][1]=0.f; acc[nt][2]=0.f; acc[nt][3]=0.f; }
  #pragma unroll
  for(int j=0;j<2;j++){
    int r = j*32 + srow;
    gl16(Yb + (size_t)(b0+r)*M3 + sgo, BsU + r*64 + dslot*8);
  }
  __syncthreads();
  for(int ph=0; ph<4; ph++){
    const int cur = ph&1;
    if(ph<3){
      #pragma unroll
      for(int j=0;j<2;j++){
        int r = j*32 + srow;
        gl16(Yb + (size_t)(b0+r)*M3 + (ph+1)*64 + sgo, BsU + (cur^1)*4096 + r*64 + dslot*8);
      }
    }
    #pragma unroll
    for(int kt=0;kt<2;kt++){
      short8 af = *(const short8*)&As[(16*wv + c)*LGS + ph*64 + kt*32 + qq*8];
      const int rslot = ((kt*4+qq)^rdswz)*8;
      #pragma unroll
      for(int nt=0;nt<4;nt++){
        short8 bff = *(const short8*)&BsU[cur*4096 + (nt*16+c)*64 + rslot];
        acc[nt] = __builtin_amdgcn_mfma_f32_16x16x32_bf16(af, bff, acc[nt], 0, 0, 0);
      }
    }
    __syncthreads();
  }
  const int m0 = 16*wv + 4*qq;
  #pragma unroll
  for(int nt=0;nt<4;nt++){
    int col = b0 + nt*16 + c;
    out[(size_t)(m0+0)*HWN + col] = acc[nt][0];
    out[(size_t)(m0+1)*HWN + col] = acc[nt][1];
    out[(size_t)(m0+2)*HWN + col] = acc[nt][2];
    out[(size_t)(m0+3)*HWN + col] = acc[nt][3];
  }
}

// ---------------- f body: soft3 + k3@v partial into part[n][kc][64][eb..eb+128] ----------------
// 4-deep explicit prefetch on the V rows + P fragments (T14 issue-early).
#define NSTR 76
__device__ void f_body(int idx, char* smem, const float* __restrict__ Z3, const u16* __restrict__ Y,
                       float* __restrict__ part){
  const int kc = idx&31, n = (idx>>5)&7, eh = idx>>8;
  const int tid = threadIdx.x;
  const int jb = kc*128, eb = eh*128;
  float* Sf = (float*)smem;              // [64][132] raw logits
  u16* k3T  = (u16*)(smem + 33792);      // [128][NSTR] post-softmax bf16
  const float* z3b = Z3 + (size_t)n*LND*HWN;
  {
    int ibase = (tid>>5)*8, j4 = (tid&31)*4;
    #pragma unroll
    for(int r=0;r<8;r++){
      int i = ibase + r;
      *(float4*)&Sf[i*132 + j4] = *(const float4*)&z3b[(size_t)i*HWN + jb + j4];
    }
  }
  __syncthreads();
  if(tid < 128){
    int j = tid;
    float m = -1e30f;
    for(int i=0;i<64;i++) m = fmaxf(m, Sf[i*132 + j]);
    float s = 0.f;
    for(int i=0;i<64;i++){ float e = __expf(Sf[i*132 + j] - m); Sf[i*132 + j] = e; s += e; }
    float inv = 1.f/s;
    u16* kr = &k3T[j*NSTR];
    for(int i=0;i<64;i+=4){
      ushort4 o;
      o.x = f2bf(Sf[(i+0)*132 + j]*inv);
      o.y = f2bf(Sf[(i+1)*132 + j]*inv);
      o.z = f2bf(Sf[(i+2)*132 + j]*inv);
      o.w = f2bf(Sf[(i+3)*132 + j]*inv);
      *(ushort4*)(kr + i) = o;
    }
  }
  __syncthreads();
  const int i0 = (tid>>4)*4, e0 = eb + (tid&15)*8;
  const u16* Yv = Y + (size_t)n*M3*HWN + 512 + e0;
  float acc[4][8] = {};
  uint4 Ub[4]; ushort4 ab[4];
  #pragma unroll
  for(int t=0;t<4;t++){
    ab[t] = *(const ushort4*)&k3T[(size_t)t*NSTR + i0];
    Ub[t] = *(const uint4*)(Yv + (size_t)(jb+t)*M3);
  }
  for(int j0=0;j0<128;j0+=4){
    uint4 Un[4]; ushort4 an[4];
    if(j0 < 124){
      #pragma unroll
      for(int t=0;t<4;t++){
        an[t] = *(const ushort4*)&k3T[(size_t)(j0+4+t)*NSTR + i0];
        Un[t] = *(const uint4*)(Yv + (size_t)(jb+j0+4+t)*M3);
      }
    }
    #pragma unroll
    for(int t=0;t<4;t++){
      float a0 = bf2f(ab[t].x), a1 = bf2f(ab[t].y), a2 = bf2f(ab[t].z), a3 = bf2f(ab[t].w);
      float bv[8];
      bf2x2(Ub[t].x, bv[0], bv[1]);  bf2x2(Ub[t].y, bv[2], bv[3]);
      bf2x2(Ub[t].z, bv[4], bv[5]);  bf2x2(Ub[t].w, bv[6], bv[7]);
      #pragma unroll
      for(int u=0;u<8;u++){
        acc[0][u] += a0*bv[u];
        acc[1][u] += a1*bv[u];
        acc[2][u] += a2*bv[u];
        acc[3][u] += a3*bv[u];
      }
    }
    if(j0 < 124){
      #pragma unroll
      for(int t=0;t<4;t++){ ab[t] = an[t]; Ub[t] = Un[t]; }
    }
  }
  float* pb = part + ((size_t)n*32 + kc)*LND*EDIM;
  #pragma unroll
  for(int s=0;s<4;s++)
    #pragma unroll
    for(int t=0;t<8;t+=4){
      float4 fv = make_float4(acc[s][t],acc[s][t+1],acc[s][t+2],acc[s][t+3]);
      *(float4*)&pb[(size_t)(i0+s)*EDIM + e0 - eb + (eb) + t] = fv;
    }
}

// ---------------- soft1 body: softmax of Z1 over contiguous 4096 ----------------
__device__ void soft1_body(int b, char* smem, float* __restrict__ Z1){
  const int n = b>>6, j = b&63, tid = threadIdx.x;
  float* redm = (float*)smem;
  float* reds = redm + 4;
  float* base = Z1 + ((size_t)n*LND + j)*HWN;
  float v[16];
  float m = -1e30f;
  #pragma unroll
  for(int r=0;r<16;r++){ v[r] = base[r*256 + tid]; m = fmaxf(m, v[r]); }
  #pragma unroll
  for(int o=32;o;o>>=1) m = fmaxf(m, __shfl_xor(m, o));
  const int wid = tid>>6;
  if((tid&63)==0) redm[wid] = m;
  __syncthreads();
  m = fmaxf(fmaxf(redm[0],redm[1]), fmaxf(redm[2],redm[3]));
  float s = 0.f;
  #pragma unroll
  for(int r=0;r<16;r++){ v[r] = __expf(v[r]-m); s += v[r]; }
  #pragma unroll
  for(int o=32;o;o>>=1) s += __shfl_xor(s, o);
  if((tid&63)==0) reds[wid] = s;
  __syncthreads();
  s = reds[0]+reds[1]+reds[2]+reds[3];
  float inv = 1.f/s;
  #pragma unroll
  for(int r=0;r<16;r++) base[r*256 + tid] = v[r]*inv;
}

// ---------------- mega kernel: blocks 0-511 f, 512-1023 soft1 (53248 B LDS -> 3 blocks/CU) --
__global__ __launch_bounds__(256) void k_mega(const float* __restrict__ Z3, const u16* __restrict__ Y,
                                              float* __restrict__ part, float* __restrict__ Z1){
  __shared__ __align__(16) char smem[53248];
  const int bi = blockIdx.x;
  if(bi < 512) f_body(bi, smem, Z3, Y, part);
  else         soft1_body(bi-512, smem, Z1);
}

__global__ void k_fred(const float* __restrict__ part, float* __restrict__ B3){
  const int idx = blockIdx.x*256 + threadIdx.x;
  const int n = idx >> 14, rem = idx & 16383;
  const float* p = part + (size_t)n*32*16384 + rem;
  float s = 0.f;
  #pragma unroll
  for(int kc=0;kc<32;kc++) s += p[(size_t)kc*16384];
  B3[idx] = s;
}

// ---------------- C2[j][e] = sum_l Kinv[j][l]*B3[l][e] ----------------
__global__ __launch_bounds__(256) void k_c2(const float* __restrict__ KinvT, const float* __restrict__ B3,
                                            float* __restrict__ C2){
  const int eb = blockIdx.x*64, n = blockIdx.y, tid = threadIdx.x;
  __shared__ float KT[64][68];
  __shared__ float Bs2[64][68];
  {
    int l = tid>>2, o16 = (tid&3)*16;
    const float* kp = KinvT + (size_t)n*4096 + l*64 + o16;
    const float* bp = B3 + ((size_t)n*LND + l)*EDIM + eb + o16;
    #pragma unroll
    for(int t=0;t<16;t+=4){
      *(float4*)&KT[l][o16+t]  = *(const float4*)(kp+t);
      *(float4*)&Bs2[l][o16+t] = *(const float4*)(bp+t);
    }
  }
  __syncthreads();
  const int j0 = (tid>>4)*4, u0 = (tid&15)*4;
  float acc[4][4] = {};
  #pragma unroll 8
  for(int l=0;l<64;l++){
    f32x4 a = *(f32x4*)&KT[l][j0];
    f32x4 b = *(f32x4*)&Bs2[l][u0];
    #pragma unroll
    for(int s=0;s<4;s++)
      #pragma unroll
      for(int u=0;u<4;u++) acc[s][u] += a[s]*b[u];
  }
  #pragma unroll
  for(int s=0;s<4;s++){
    float4 fv = make_float4(acc[s][0],acc[s][1],acc[s][2],acc[s][3]);
    *(float4*)&C2[((size_t)n*LND + j0+s)*EDIM + eb + u0] = fv;
  }
}

// ---------------- out[i][e] = sum_j k1t[j][i]*C2[j][e] + v[i][e]; OM bf16 ----------------
__global__ __launch_bounds__(256) void k_out(const float* __restrict__ Z1, const float* __restrict__ C2,
                                             const u16* __restrict__ Y, u16* __restrict__ OM){
  const int ib = blockIdx.x*64, n = blockIdx.y, tid = threadIdx.x;
  __shared__ float K1s[64][68];
  __shared__ u16 C2s[64*264];
  {
    int j = tid>>2, i16 = (tid&3)*16;
    const float* zp = Z1 + ((size_t)n*LND + j)*HWN + ib + i16;
    #pragma unroll
    for(int t=0;t<16;t+=4) *(float4*)&K1s[j][i16+t] = *(const float4*)(zp+t);
    int e64 = (tid&3)*64;
    const float* cp = C2 + ((size_t)n*LND + j)*EDIM + e64;
    #pragma unroll
    for(int t=0;t<64;t+=4){
      float4 v = *(const float4*)(cp+t);
      C2s[j*264 + e64+t+0] = f2bf(v.x);
      C2s[j*264 + e64+t+1] = f2bf(v.y);
      C2s[j*264 + e64+t+2] = f2bf(v.z);
      C2s[j*264 + e64+t+3] = f2bf(v.w);
    }
  }
  __syncthreads();
  const int i0 = (tid>>4)*4, e0 = (tid&15)*16;
  float acc[4][16] = {};
  for(int j=0;j<64;j++){
    f32x4 a = *(f32x4*)&K1s[j][i0];
    const u16* cb = &C2s[j*264 + e0];
    uint4 U0 = *(const uint4*)cb;
    uint4 U1 = *(const uint4*)(cb+8);
    float bv[16];
    bf2x2(U0.x, bv[0], bv[1]);  bf2x2(U0.y, bv[2], bv[3]);
    bf2x2(U0.z, bv[4], bv[5]);  bf2x2(U0.w, bv[6], bv[7]);
    bf2x2(U1.x, bv[8], bv[9]);  bf2x2(U1.y, bv[10], bv[11]);
    bf2x2(U1.z, bv[12], bv[13]); bf2x2(U1.w, bv[14], bv[15]);
    #pragma unroll
    for(int u=0;u<16;u++){
      acc[0][u] += a[0]*bv[u];
      acc[1][u] += a[1]*bv[u];
      acc[2][u] += a[2]*bv[u];
      acc[3][u] += a[3]*bv[u];
    }
  }
  const u16* Yb = Y + (size_t)n*M3*HWN;
  u16* ob = OM + (size_t)n*HWN*EDIM;
  #pragma unroll
  for(int s=0;s<4;s++){
    int i = ib + i0 + s;
    const u16* vp = Yb + (size_t)i*M3 + 512 + e0;
    uint4 U0 = *(const uint4*)vp, U1 = *(const uint4*)(vp+8);
    float vv[16];
    bf2x2(U0.x, vv[0], vv[1]);  bf2x2(U0.y, vv[2], vv[3]);
    bf2x2(U0.z, vv[4], vv[5]);  bf2x2(U0.w, vv[6], vv[7]);
    bf2x2(U1.x, vv[8], vv[9]);  bf2x2(U1.y, vv[10], vv[11]);
    bf2x2(U1.z, vv[12], vv[13]); bf2x2(U1.w, vv[14], vv[15]);
    #pragma unroll
    for(int t=0;t<16;t+=4){
      ushort4 o;
      o.x = f2bf(acc[s][t+0]+vv[t+0]);
      o.y = f2bf(acc[s][t+1]+vv[t+1]);
      o.z = f2bf(acc[s][t+2]+vv[t+2]);
      o.w = f2bf(acc[s][t+3]+vv[t+3]);
      *(ushort4*)&ob[(size_t)i*EDIM + e0 + t] = o;
    }
  }
}

// ---------------- transpose of raw-reshaped OM ----------------
__global__ __launch_bounds__(256) void k_trans2(const u16* __restrict__ OM, u16* __restrict__ OMT){
  __shared__ u16 Ts[64*65];
  const int bi = blockIdx.x;
  const int n = bi>>8, rem = bi&255, et = rem>>6, pt = rem&63;
  const int e0 = et*64, p0 = pt*64, tid = threadIdx.x;
  const u16* omb = OM + (size_t)n*HWN*EDIM;
  {
    int ee = tid>>2, pj = (tid&3)*16;
    const u16* ip = omb + (size_t)(e0+ee)*HWN + p0 + pj;
    ushort4 v0 = *(const ushort4*)(ip);
    ushort4 v1 = *(const ushort4*)(ip+4);
    ushort4 v2 = *(const ushort4*)(ip+8);
    ushort4 v3 = *(const ushort4*)(ip+12);
    u16* tp = &Ts[ee*65 + pj];
    tp[0]=v0.x; tp[1]=v0.y; tp[2]=v0.z; tp[3]=v0.w;
    tp[4]=v1.x; tp[5]=v1.y; tp[6]=v1.z; tp[7]=v1.w;
    tp[8]=v2.x; tp[9]=v2.y; tp[10]=v2.z; tp[11]=v2.w;
    tp[12]=v3.x; tp[13]=v3.y; tp[14]=v3.z; tp[15]=v3.w;
  }
  __syncthreads();
  {
    int pp = tid>>2, ej = (tid&3)*16;
    u16* op = OMT + ((size_t)n*HWN + p0 + pp)*EDIM + e0 + ej;
    ushort4 o[4];
    #pragma unroll
    for(int j=0;j<16;j++) ((u16*)o)[j] = Ts[(ej+j)*65 + pp];
    *(ushort4*)(op+0)  = o[0];
    *(ushort4*)(op+4)  = o[1];
    *(ushort4*)(op+8)  = o[2];
    *(ushort4*)(op+12) = o[3];
  }
}

// ---------------- proj GEMM 128x128xK256, global_load_lds + XOR swizzle ----------------
__global__ __launch_bounds__(256) void k_proj(const u16* __restrict__ Wb, const u16* __restrict__ OMT,
                                              const float* __restrict__ bias, float* __restrict__ out){
  __shared__ __align__(16) u16 As[128*64];
  __shared__ __align__(16) u16 Bs[128*64];
  const int bi = blockIdx.x;
  const int n = bi&7, rem = bi>>3;
  const int ch0 = (rem&1)*128, p0 = (rem>>1)*128;
  const int tid = threadIdx.x, lane = tid&63;
  const int c = tid&15, qq = (tid>>4)&3, w4 = tid>>6;
  const int wr0 = (w4&1)*64, wc0 = (w4>>1)*64;
  const u16* xb = OMT + ((size_t)n*HWN + p0)*EDIM;
  const u16* wb = Wb + (size_t)ch0*EDIM;
  f32x4 acc[4][4];
  #pragma unroll
  for(int mt=0;mt<4;mt++)
    #pragma unroll
    for(int nt=0;nt<4;nt++){ acc[mt][nt][0]=0.f; acc[mt][nt][1]=0.f; acc[mt][nt][2]=0.f; acc[mt][nt][3]=0.f; }
  const int srow  = w4*8 + (lane>>3);
  const int dslot = lane&7;
  const int sgo   = (dslot ^ (lane>>3))*8;
  const int rdswz = (c&7);
  for(int ph=0; ph<4; ph++){
    #pragma unroll
    for(int j=0;j<4;j++){
      int r = j*32 + srow;
      gl16(wb + (size_t)r*EDIM + ph*64 + sgo, &As[r*64 + dslot*8]);
    }
    #pragma unroll
    for(int j=0;j<4;j++){
      int r = j*32 + srow;
      gl16(xb + (size_t)r*EDIM + ph*64 + sgo, &Bs[r*64 + dslot*8]);
    }
    __syncthreads();
    #pragma unroll
    for(int kt=0;kt<2;kt++){
      short8 af[4], bff[4];
      const int rslot = ((kt*4+qq)^rdswz)*8;
      #pragma unroll
      for(int mt=0;mt<4;mt++) af[mt]  = *(const short8*)&As[(wr0+mt*16+c)*64 + rslot];
      #pragma unroll
      for(int nt=0;nt<4;nt++) bff[nt] = *(const short8*)&Bs[(wc0+nt*16+c)*64 + rslot];
      #pragma unroll
      for(int mt=0;mt<4;mt++)
        #pragma unroll
        for(int nt=0;nt<4;nt++)
          acc[mt][nt] = __builtin_amdgcn_mfma_f32_16x16x32_bf16(af[mt], bff[nt], acc[mt][nt], 0, 0, 0);
    }
    __syncthreads();
  }
  float* ob = out + (size_t)n*EDIM*HWN;
  #pragma unroll
  for(int mt=0;mt<4;mt++){
    int chb = ch0 + wr0 + mt*16 + 4*qq;
    float b0 = bias[chb], b1 = bias[chb+1], b2 = bias[chb+2], b3 = bias[chb+3];
    #pragma unroll
    for(int nt=0;nt<4;nt++){
      int p = p0 + wc0 + nt*16 + c;
      float* yp = ob + (size_t)chb*HWN + p;
      yp[0]             = acc[mt][nt][0]+b0;
      yp[HWN]           = acc[mt][nt][1]+b1;
      yp[2*(size_t)HWN] = acc[mt][nt][2]+b2;
      yp[3*(size_t)HWN] = acc[mt][nt][3]+b3;
    }
  }
}

extern "C" void kernel_launch(void* const* d_in, const int* in_sizes, int n_in,
                              void* d_out, int out_size, void* d_ws, size_t ws_size,
                              hipStream_t stream){
  (void)out_size; (void)ws_size;
  const float* x     = (const float*)d_in[0];
  const float* w_qkv = (const float*)d_in[1];
  const float* b_qkv = (const float*)d_in[2];
  const float* w_out = (const float*)d_in[3];
  const float* b_out = (const float*)d_in[4];
  for(int i=0;i<n_in;i++){
    switch(in_sizes[i]){
      case 8388608: x     = (const float*)d_in[i]; break;
      case 196608:  w_qkv = (const float*)d_in[i]; break;
      case 768:     b_qkv = (const float*)d_in[i]; break;
      case 65536:   w_out = (const float*)d_in[i]; break;
      case 256:     b_out = (const float*)d_in[i]; break;
      default: break;
    }
  }
  float* out = (float*)d_out;
  char* ws = (char*)d_ws;

  u16*   Y     = (u16*)(ws + 0);              // 50,331,648 B  bf16 [8][768*4096]
  float* qland = (float*)(ws + 50331648);
  float* kland = (float*)(ws + 50855936);
  float* Z1    = (float*)(ws + 51380224);
  float* Z3    = (float*)(ws + 59768832);
  float* KinvT = (float*)(ws + 68157440);
  u16*   Xt    = (u16*)(ws + 68288512);       // 16 MB region: Xt -> part -> OMT
  float* part  = (float*)(ws + 68288512);
  u16*   OMT   = (u16*)(ws + 68288512);
  float* B3    = (float*)(ws + 85065728);
  float* C2    = (float*)(ws + 85590016);
  u16*   OM    = (u16*)(ws + 86114304);       // 16 MB bf16
  // Wqb overlaps Z3 (Z3 written by k_landgemm AFTER k_qkv consumes Wqb — stream-ordered safe)
  u16*   Wqb   = (u16*)(ws + 59768832);       // 393,216 B bf16 [768][256]
  u16*   Wob   = (u16*)(ws + 102891520);      // 131,072 B bf16 [256][256] (persists to k_proj)

  k_prep    <<<dim3(2056),   256, 0, stream>>>(x, Xt, w_qkv, w_out, Wqb, Wob);
  k_qkv     <<<dim3(1536),   256, 0, stream>>>(Wqb, Xt, b_qkv, Y);
  k_land    <<<dim3(64,8),   256, 0, stream>>>(Y, qland, kland);
  k_landgemm<<<dim3(65,16),  256, 0, stream>>>(Y, qland, kland, Z1, Z3, KinvT);
  k_mega    <<<dim3(1024),   256, 0, stream>>>(Z3, Y, part, Z1);
  k_fred    <<<dim3(512),    256, 0, stream>>>(part, B3);
  k_c2      <<<dim3(4,8),    256, 0, stream>>>(KinvT, B3, C2);
  k_out     <<<dim3(64,8),   256, 0, stream>>>(Z1, C2, Y, OM);
  k_trans2  <<<dim3(2048),   256, 0, stream>>>(OM, OMT);
  k_proj    <<<dim3(512),    256, 0, stream>>>(Wob, OMT, b_out, out);
}

// Round 6
// 220.830 us; speedup vs baseline: 1.5454x; 1.0735x over previous
//
#include <hip/hip_runtime.h>
#include <hip/hip_bf16.h>

typedef unsigned short u16;
typedef __attribute__((ext_vector_type(4))) float f32x4;
typedef __attribute__((ext_vector_type(8))) short short8;

#define NB   8
#define CIN  256
#define EDIM 256
#define M3   768
#define HWN  4096
#define LND  64
#define NS2  72    // NS LDS row stride (bf16 elems): 144B, 16B aligned

__device__ __forceinline__ float bf2f(u16 u){ return __uint_as_float(((unsigned)u)<<16); }
__device__ __forceinline__ u16 f2bf(float f){ __hip_bfloat16 h = __float2bfloat16(f); return *reinterpret_cast<u16*>(&h); }
__device__ __forceinline__ void bf2x2(unsigned u, float &lo, float &hi){
  lo = __uint_as_float(u<<16);
  hi = __uint_as_float(u & 0xffff0000u);
}

typedef __attribute__((address_space(1))) unsigned as1_uint;
typedef __attribute__((address_space(3))) unsigned as3_uint;
// async global->LDS, 16B per lane; dest must be wave-uniform base + lane*16
__device__ __forceinline__ void gl16(const void* g, void* l){
  __builtin_amdgcn_global_load_lds((const as1_uint*)g, (as3_uint*)l, 16, 0, 0);
}

// ---------------- prep: Xt[n][p][c] (bf16) = transpose of X[n][c][p] (fp32) ----------------
// blocks >= 2048: convert w_qkv / w_out to bf16 (once, instead of per GEMM block)
__global__ __launch_bounds__(256) void k_prep(const float* __restrict__ x, u16* __restrict__ Xt,
                                              const float* __restrict__ wq, const float* __restrict__ wo,
                                              u16* __restrict__ Wqb, u16* __restrict__ Wob){
  const int bi = blockIdx.x;
  const int tid = threadIdx.x;
  if(bi >= 2048){
    int ti = (bi-2048)*256 + tid;          // 0..2047
    const float* src; u16* dst;
    if(ti < 1536){ src = wq + (size_t)ti*128;        dst = Wqb + (size_t)ti*128; }
    else         { src = wo + (size_t)(ti-1536)*128; dst = Wob + (size_t)(ti-1536)*128; }
    #pragma unroll
    for(int t=0;t<128;t+=8){
      float4 v0 = *(const float4*)(src+t);
      float4 v1 = *(const float4*)(src+t+4);
      ushort4 o0, o1;
      o0.x=f2bf(v0.x); o0.y=f2bf(v0.y); o0.z=f2bf(v0.z); o0.w=f2bf(v0.w);
      o1.x=f2bf(v1.x); o1.y=f2bf(v1.y); o1.z=f2bf(v1.z); o1.w=f2bf(v1.w);
      *(ushort4*)(dst+t)   = o0;
      *(ushort4*)(dst+t+4) = o1;
    }
    return;
  }
  __shared__ float Ts[64*65];
  const int n = bi>>8, rem = bi&255, ct = rem>>6, pt = rem&63;
  const int c0 = ct*64, p0 = pt*64;
  {
    int cc = tid>>2, pj = (tid&3)*16;
    const float* xp = x + (size_t)n*CIN*HWN + (size_t)(c0+cc)*HWN + p0 + pj;
    #pragma unroll
    for(int j=0;j<16;j++) Ts[cc*65 + pj + j] = xp[j];
  }
  __syncthreads();
  {
    int pp = tid>>2, ej = (tid&3)*16;
    u16* op = Xt + ((size_t)n*HWN + p0 + pp)*CIN + c0 + ej;
    ushort4 o[4];
    #pragma unroll
    for(int j=0;j<16;j++) ((u16*)o)[j] = f2bf(Ts[(ej+j)*65 + pp]);
    *(ushort4*)(op+0)  = o[0];
    *(ushort4*)(op+4)  = o[1];
    *(ushort4*)(op+8)  = o[2];
    *(ushort4*)(op+12) = o[3];
  }
}

// ---------------- QKV GEMM 128x128xK256 bf16 MFMA, global_load_lds + XOR swizzle ------------
__global__ __launch_bounds__(256) void k_qkv(const u16* __restrict__ Wb, const u16* __restrict__ Xt,
                                             const float* __restrict__ bias, u16* __restrict__ Y){
  __shared__ __align__(16) u16 As[128*64];
  __shared__ __align__(16) u16 Bs[128*64];
  const int bi = blockIdx.x;
  const int n = bi&7, rem = bi>>3;
  const int ch0 = (rem%6)*128, p0 = (rem/6)*128;
  const int tid = threadIdx.x, lane = tid&63;
  const int c = tid&15, qq = (tid>>4)&3, w4 = tid>>6;
  const int wr0 = (w4&1)*64, wc0 = (w4>>1)*64;
  const u16* xb = Xt + ((size_t)n*HWN + p0)*CIN;
  const u16* wb = Wb + (size_t)ch0*CIN;
  f32x4 acc[4][4];
  #pragma unroll
  for(int mt=0;mt<4;mt++)
    #pragma unroll
    for(int nt=0;nt<4;nt++){ acc[mt][nt][0]=0.f; acc[mt][nt][1]=0.f; acc[mt][nt][2]=0.f; acc[mt][nt][3]=0.f; }
  const int srow  = w4*8 + (lane>>3);
  const int dslot = lane&7;
  const int sgo   = (dslot ^ (lane>>3))*8;       // swizzled source u16 offset within row-chunk
  const int rdswz = (c&7);                        // read-side row&7
  for(int ph=0; ph<4; ph++){
    #pragma unroll
    for(int j=0;j<4;j++){
      int r = j*32 + srow;
      gl16(wb + (size_t)r*CIN + ph*64 + sgo, &As[r*64 + dslot*8]);
    }
    #pragma unroll
    for(int j=0;j<4;j++){
      int r = j*32 + srow;
      gl16(xb + (size_t)r*CIN + ph*64 + sgo, &Bs[r*64 + dslot*8]);
    }
    __syncthreads();
    #pragma unroll
    for(int kt=0;kt<2;kt++){
      short8 af[4], bff[4];
      const int rslot = ((kt*4+qq)^rdswz)*8;
      #pragma unroll
      for(int mt=0;mt<4;mt++) af[mt]  = *(const short8*)&As[(wr0+mt*16+c)*64 + rslot];
      #pragma unroll
      for(int nt=0;nt<4;nt++) bff[nt] = *(const short8*)&Bs[(wc0+nt*16+c)*64 + rslot];
      #pragma unroll
      for(int mt=0;mt<4;mt++)
        #pragma unroll
        for(int nt=0;nt<4;nt++)
          acc[mt][nt] = __builtin_amdgcn_mfma_f32_16x16x32_bf16(af[mt], bff[nt], acc[mt][nt], 0, 0, 0);
    }
    __syncthreads();
  }
  u16* Yb = Y + (size_t)n*M3*HWN;
  #pragma unroll
  for(int mt=0;mt<4;mt++){
    int chb = ch0 + wr0 + mt*16 + 4*qq;
    float b0 = bias[chb], b1 = bias[chb+1], b2 = bias[chb+2], b3 = bias[chb+3];
    #pragma unroll
    for(int nt=0;nt<4;nt++){
      int p = p0 + wc0 + nt*16 + c;
      u16* yp = Yb + (size_t)chb*HWN + p;
      yp[0]             = f2bf(acc[mt][nt][0]+b0);
      yp[HWN]           = f2bf(acc[mt][nt][1]+b1);
      yp[2*(size_t)HWN] = f2bf(acc[mt][nt][2]+b2);
      yp[3*(size_t)HWN] = f2bf(acc[mt][nt][3]+b3);
    }
  }
}

// ---------------- landmarks ----------------
__global__ void k_land(const u16* __restrict__ Y, float* __restrict__ qland, float* __restrict__ kland){
  const int l = blockIdx.x, n = blockIdx.y, e = threadIdx.x;
  const u16* base = Y + (size_t)n*M3*HWN;
  float qs=0.f, ks=0.f;
  #pragma unroll 8
  for(int m=0;m<64;m++){
    size_t off = (size_t)(l*64+m)*M3;
    qs += bf2f(base[off+e]);
    ks += bf2f(base[off+256+e]);
  }
  qland[((size_t)n*LND+l)*EDIM+e] = qs*(1.f/4096.f);
  kland[((size_t)n*LND+l)*EDIM+e] = ks*(1.f/4096.f);
}

// ---------------- NS 64x64 matmul via bf16 MFMA (per-operand LDS row stride) ----------------
__device__ __forceinline__ void ns_mm2(const u16* L, int sL, const u16* Rt, int sR,
                                       int wv, int q, int c, f32x4 r4[4]){
  short8 a0 = *(const short8*)(L + (size_t)(16*wv + c)*sL + 8*q);
  short8 a1 = *(const short8*)(L + (size_t)(16*wv + c)*sL + 32 + 8*q);
  #pragma unroll
  for(int tc=0;tc<4;tc++){
    f32x4 acc = {0.f,0.f,0.f,0.f};
    short8 b0 = *(const short8*)(Rt + (size_t)(16*tc + c)*sR + 8*q);
    short8 b1 = *(const short8*)(Rt + (size_t)(16*tc + c)*sR + 32 + 8*q);
    acc = __builtin_amdgcn_mfma_f32_16x16x32_bf16(a0, b0, acc, 0, 0, 0);
    acc = __builtin_amdgcn_mfma_f32_16x16x32_bf16(a1, b1, acc, 0, 0, 0);
    r4[tc] = acc;
  }
}

// ---------------- NS body (k2 + Newton-Schulz pseudo-inverse) ----------------
#define TTS 64
__device__ void ns_body(int n, char* smem, const float* __restrict__ qland,
                        const float* __restrict__ kland, float* __restrict__ KinvT){
  u16* Kb  = (u16*)(smem + 0);
  u16* Vb  = (u16*)(smem + 9216);
  u16* Vt  = (u16*)(smem + 18432);
  u16* KVb = (u16*)(smem + 27648);
  u16* KVt = (u16*)(smem + 36864);
  u16* Tt  = (u16*)(smem + 46080);         // stride 64, 8192 B -> end 54272
  float* sS   = (float*)(smem + 27648);    // 64x66 f32 = 16896, aliases KVb/KVt
  float* sred = (float*)(smem + 44544);    // 520 B, ends 45064 < 46080
  const int tid = threadIdx.x;
  const int wv = tid>>6, q = (tid>>4)&3, c = tid&15;
  const float* qb = qland + (size_t)n*LND*EDIM;
  const float* kb = kland + (size_t)n*LND*EDIM;
  f32x4 acc[4];
  #pragma unroll
  for(int t=0;t<4;t++){ acc[t][0]=0.f; acc[t][1]=0.f; acc[t][2]=0.f; acc[t][3]=0.f; }
  for(int e0=0;e0<EDIM;e0+=64){
    __syncthreads();
    {
      int row = tid>>2, c0 = (tid&3)*16;
      const float* qp = qb + (size_t)row*EDIM + e0 + c0;
      const float* kp = kb + (size_t)row*EDIM + e0 + c0;
      u16* qd = &KVb[row*NS2 + c0];
      u16* kd = &KVt[row*NS2 + c0];
      #pragma unroll
      for(int j=0;j<16;j+=4){
        float4 qv = *(const float4*)(qp+j);
        float4 kv = *(const float4*)(kp+j);
        ushort4 qo, ko;
        qo.x=f2bf(qv.x); qo.y=f2bf(qv.y); qo.z=f2bf(qv.z); qo.w=f2bf(qv.w);
        ko.x=f2bf(kv.x); ko.y=f2bf(kv.y); ko.z=f2bf(kv.z); ko.w=f2bf(kv.w);
        *(ushort4*)(qd+j) = qo;
        *(ushort4*)(kd+j) = ko;
      }
    }
    __syncthreads();
    {
      short8 a0 = *(const short8*)&KVb[(16*wv+c)*NS2 + 8*q];
      short8 a1 = *(const short8*)&KVb[(16*wv+c)*NS2 + 32 + 8*q];
      #pragma unroll
      for(int tc=0;tc<4;tc++){
        short8 b0 = *(const short8*)&KVt[(16*tc+c)*NS2 + 8*q];
        short8 b1 = *(const short8*)&KVt[(16*tc+c)*NS2 + 32 + 8*q];
        acc[tc] = __builtin_amdgcn_mfma_f32_16x16x32_bf16(a0, b0, acc[tc], 0, 0, 0);
        acc[tc] = __builtin_amdgcn_mfma_f32_16x16x32_bf16(a1, b1, acc[tc], 0, 0, 0);
      }
    }
  }
  __syncthreads();   // KVb/KVt reads done everywhere before sS (alias) is written
  #pragma unroll
  for(int tc=0;tc<4;tc++){
    int col = 16*tc + c, row0 = 16*wv + 4*q;
    sS[(row0+0)*66+col] = acc[tc][0];
    sS[(row0+1)*66+col] = acc[tc][1];
    sS[(row0+2)*66+col] = acc[tc][2];
    sS[(row0+3)*66+col] = acc[tc][3];
  }
  __syncthreads();
  if(tid < 64){
    int j = tid;
    float m = -1e30f;
    for(int i=0;i<64;i++) m = fmaxf(m, sS[i*66+j]);
    float ssum = 0.f;
    for(int i=0;i<64;i++) ssum += __expf(sS[i*66+j]-m);
    float inv = 1.f/ssum, cs = 0.f;
    for(int i=0;i<64;i++){
      float kv = __expf(sS[i*66+j]-m)*inv;
      cs += fabsf(kv);
      Kb[i*NS2+j] = f2bf(kv);
    }
    sred[j] = cs;
  }
  __syncthreads();
  if(tid < 64){
    int i = tid; float rs = 0.f;
    for(int j=0;j<64;j++) rs += fabsf(bf2f(Kb[i*NS2+j]));
    sred[64+i] = rs;
  }
  __syncthreads();
  if(tid == 0){
    float v0=-1e30f, vi=-1e30f;
    for(int t=0;t<64;t++){ v0 = fmaxf(v0, sred[t]); vi = fmaxf(vi, sred[64+t]); }
    sred[128] = 1.f/(v0*vi);
  }
  __syncthreads();
  {
    float sc = sred[128];
    int i = tid>>2, j16 = (tid&3)*16;
    #pragma unroll
    for(int jj=0;jj<16;jj++){
      int j = j16+jj;
      u16 bvv = f2bf(bf2f(Kb[j*NS2+i])*sc);
      Vb[i*NS2+j] = bvv;
      Vt[j*NS2+i] = bvv;
    }
  }
  __syncthreads();
  f32x4 r4[4];
  for(int it=0; it<6; it++){
    ns_mm2(Kb, NS2, Vt, NS2, wv, q, c, r4);
    #pragma unroll
    for(int tc=0;tc<4;tc++){
      int col = 16*tc + c, row0 = 16*wv + 4*q;
      ushort4 pk;
      pk.x = f2bf(r4[tc][0]); pk.y = f2bf(r4[tc][1]); pk.z = f2bf(r4[tc][2]); pk.w = f2bf(r4[tc][3]);
      KVb[(row0+0)*NS2+col] = pk.x; KVb[(row0+1)*NS2+col] = pk.y;
      KVb[(row0+2)*NS2+col] = pk.z; KVb[(row0+3)*NS2+col] = pk.w;
      *(ushort4*)&KVt[(size_t)col*NS2 + row0] = pk;
    }
    __syncthreads();
    ns_mm2(KVb, NS2, KVt, NS2, wv, q, c, r4);
    #pragma unroll
    for(int tc=0;tc<4;tc++){
      int col = 16*tc+c, row0 = 16*wv+4*q;
      ushort4 pk;
      #pragma unroll
      for(int r=0;r<4;r++){
        float kvv = bf2f(KVb[(row0+r)*NS2+col]);
        ((u16*)&pk)[r] = f2bf(7.f*kvv - r4[tc][r]);
      }
      *(ushort4*)&Tt[(size_t)col*TTS + row0] = pk;
    }
    __syncthreads();
    ns_mm2(KVb, NS2, Tt, TTS, wv, q, c, r4);
    __syncthreads();
    #pragma unroll
    for(int tc=0;tc<4;tc++){
      int col = 16*tc+c, row0 = 16*wv+4*q;
      ushort4 pk;
      #pragma unroll
      for(int r=0;r<4;r++){
        float kvv = bf2f(KVb[(row0+r)*NS2+col]);
        ((u16*)&pk)[r] = f2bf(15.f*kvv - r4[tc][r]);
      }
      *(ushort4*)&Tt[(size_t)col*TTS + row0] = pk;
    }
    __syncthreads();
    ns_mm2(Vb, NS2, Tt, TTS, wv, q, c, r4);
    __syncthreads();
    #pragma unroll
    for(int tc=0;tc<4;tc++){
      int col = 16*tc+c, row0 = 16*wv+4*q;
      float nv[4]; ushort4 pk;
      #pragma unroll
      for(int r=0;r<4;r++){
        float vv = bf2f(Vb[(row0+r)*NS2+col]);
        nv[r] = 0.25f*(13.f*vv - r4[tc][r]);
        u16 bb = f2bf(nv[r]);
        Vb[(row0+r)*NS2+col] = bb;
        ((u16*)&pk)[r] = bb;
      }
      *(ushort4*)&Vt[(size_t)col*NS2 + row0] = pk;
      if(it==5){
        *(float4*)&KinvT[(size_t)n*4096 + (size_t)col*64 + row0] = make_float4(nv[0],nv[1],nv[2],nv[3]);
      }
    }
    __syncthreads();
  }
}

// ---------------- Z1/Z3 landmark GEMM + fused NS (blockIdx.x==64) --------------------------
#define LGS 264   // A LDS row stride (u16): 528B, 16B aligned, bank-conflict-free
__global__ __launch_bounds__(256) void k_landgemm(const u16* __restrict__ Y, const float* __restrict__ qland,
                                                  const float* __restrict__ kland, float* __restrict__ Z1,
                                                  float* __restrict__ Z3, float* __restrict__ KinvT){
  __shared__ __align__(16) char usm[54272];
  const int z = blockIdx.y;
  if(blockIdx.x == 64){
    if((z&1)==0) ns_body(z>>1, usm, qland, kland, KinvT);
    return;
  }
  u16* As = (u16*)usm;                 // [64][LGS]
  u16* BsU = (u16*)(usm + 33792);      // [2][64*64]
  const int n = z>>1, which = z&1;
  const int b0 = blockIdx.x*64;
  const float* land = (which ? qland : kland) + (size_t)n*LND*EDIM;
  const int boff = which ? 256 : 0;
  float* out = (which ? Z3 : Z1) + (size_t)n*LND*HWN;
  const u16* Yb = Y + (size_t)n*M3*HWN + boff;
  const int tid = threadIdx.x, lane = tid&63;
  const int c = tid&15, qq = (tid>>4)&3, wv = tid>>6;
  {
    int r = tid>>2, c0 = (tid&3)*64;
    const float* lp = land + (size_t)r*EDIM + c0;
    u16* dp = &As[r*LGS + c0];
    #pragma unroll
    for(int j=0;j<64;j+=4){
      float4 v = *(const float4*)(lp+j);
      ushort4 o; o.x=f2bf(v.x); o.y=f2bf(v.y); o.z=f2bf(v.z); o.w=f2bf(v.w);
      *(ushort4*)(dp+j) = o;
    }
  }
  const int srow  = wv*8 + (lane>>3);            // 0..31
  const int dslot = lane&7;
  const int sgo   = (dslot ^ (lane>>3))*8;       // row&7 == lane>>3 here
  const int rdswz = (c&7);
  f32x4 acc[4];
  #pragma unroll
  for(int nt=0;nt<4;nt++){ acc[nt][0]=0.f; acc[nt][1]=0.f; acc[nt][2]=0.f; acc[nt][3]=0.f; }
  #pragma unroll
  for(int j=0;j<2;j++){
    int r = j*32 + srow;
    gl16(Yb + (size_t)(b0+r)*M3 + sgo, BsU + r*64 + dslot*8);
  }
  __syncthreads();
  for(int ph=0; ph<4; ph++){
    const int cur = ph&1;
    if(ph<3){
      #pragma unroll
      for(int j=0;j<2;j++){
        int r = j*32 + srow;
        gl16(Yb + (size_t)(b0+r)*M3 + (ph+1)*64 + sgo, BsU + (cur^1)*4096 + r*64 + dslot*8);
      }
    }
    #pragma unroll
    for(int kt=0;kt<2;kt++){
      short8 af = *(const short8*)&As[(16*wv + c)*LGS + ph*64 + kt*32 + qq*8];
      const int rslot = ((kt*4+qq)^rdswz)*8;
      #pragma unroll
      for(int nt=0;nt<4;nt++){
        short8 bff = *(const short8*)&BsU[cur*4096 + (nt*16+c)*64 + rslot];
        acc[nt] = __builtin_amdgcn_mfma_f32_16x16x32_bf16(af, bff, acc[nt], 0, 0, 0);
      }
    }
    __syncthreads();
  }
  const int m0 = 16*wv + 4*qq;
  #pragma unroll
  for(int nt=0;nt<4;nt++){
    int col = b0 + nt*16 + c;
    out[(size_t)(m0+0)*HWN + col] = acc[nt][0];
    out[(size_t)(m0+1)*HWN + col] = acc[nt][1];
    out[(size_t)(m0+2)*HWN + col] = acc[nt][2];
    out[(size_t)(m0+3)*HWN + col] = acc[nt][3];
  }
}

// ---------------- soft3: column-softmax of Z3 tile, write P bf16 [i][4096 j] row-major ------
__device__ void soft3_body(int idx, char* smem, const float* __restrict__ Z3, u16* __restrict__ P){
  const int kc = idx&31, n = idx>>5;
  const int tid = threadIdx.x, jb = kc*128;
  float* Sf   = (float*)smem;              // [64][132] logits -> exp
  float* sinv = (float*)(smem + 33792);    // [128] 1/sum per column
  const float* z3b = Z3 + (size_t)n*LND*HWN;
  {
    int ibase = (tid>>5)*8, j4 = (tid&31)*4;
    #pragma unroll
    for(int r=0;r<8;r++){
      int i = ibase + r;
      *(float4*)&Sf[i*132 + j4] = *(const float4*)&z3b[(size_t)i*HWN + jb + j4];
    }
  }
  __syncthreads();
  if(tid < 128){
    int j = tid;
    float m = -1e30f;
    for(int i=0;i<64;i++) m = fmaxf(m, Sf[i*132 + j]);
    float s = 0.f;
    for(int i=0;i<64;i++){ float e = __expf(Sf[i*132 + j] - m); Sf[i*132 + j] = e; s += e; }
    sinv[j] = 1.f/s;
  }
  __syncthreads();
  { // row pass: coalesced bf16 write of P[i][jb..jb+128]
    int i = tid>>2, j0 = (tid&3)*32;
    u16* pp = P + ((size_t)n*LND + i)*HWN + jb + j0;
    #pragma unroll
    for(int t=0;t<32;t+=4){
      ushort4 o;
      o.x = f2bf(Sf[i*132 + j0+t+0]*sinv[j0+t+0]);
      o.y = f2bf(Sf[i*132 + j0+t+1]*sinv[j0+t+1]);
      o.z = f2bf(Sf[i*132 + j0+t+2]*sinv[j0+t+2]);
      o.w = f2bf(Sf[i*132 + j0+t+3]*sinv[j0+t+3]);
      *(ushort4*)(pp+t) = o;
    }
  }
}

// ---------------- soft1 body: softmax of Z1 over contiguous 4096 ----------------
__device__ void soft1_body(int b, char* smem, float* __restrict__ Z1){
  const int n = b>>6, j = b&63, tid = threadIdx.x;
  float* redm = (float*)smem;
  float* reds = redm + 4;
  float* base = Z1 + ((size_t)n*LND + j)*HWN;
  float v[16];
  float m = -1e30f;
  #pragma unroll
  for(int r=0;r<16;r++){ v[r] = base[r*256 + tid]; m = fmaxf(m, v[r]); }
  #pragma unroll
  for(int o=32;o;o>>=1) m = fmaxf(m, __shfl_xor(m, o));
  const int wid = tid>>6;
  if((tid&63)==0) redm[wid] = m;
  __syncthreads();
  m = fmaxf(fmaxf(redm[0],redm[1]), fmaxf(redm[2],redm[3]));
  float s = 0.f;
  #pragma unroll
  for(int r=0;r<16;r++){ v[r] = __expf(v[r]-m); s += v[r]; }
  #pragma unroll
  for(int o=32;o;o>>=1) s += __shfl_xor(s, o);
  if((tid&63)==0) reds[wid] = s;
  __syncthreads();
  s = reds[0]+reds[1]+reds[2]+reds[3];
  float inv = 1.f/s;
  #pragma unroll
  for(int r=0;r<16;r++) base[r*256 + tid] = v[r]*inv;
}

// ---------------- mega: blocks 0-255 soft3 (-> P), 256-767 soft1 ----------------
__global__ __launch_bounds__(256) void k_mega(const float* __restrict__ Z3, u16* __restrict__ P,
                                              float* __restrict__ Z1){
  __shared__ __align__(16) char smem[34304];
  const int bi = blockIdx.x;
  if(bi < 256) soft3_body(bi, smem, Z3, P);
  else         soft1_body(bi-256, smem, Z1);
}

// ---------------- PV GEMM: part[n][kc][64 i][e] = P[i][jb..jb+128] @ V[j][e], MFMA ----------
// A = P tile via gl16 + XOR swizzle (landgemm pattern). B = V^T via manual transpose stage
// into slot-XOR layout: slot_stored = (j>>3) ^ (e&7) ^ ((e>>3)&7)  (both-sides involution).
__global__ __launch_bounds__(256) void k_pv(const u16* __restrict__ P, const u16* __restrict__ Y,
                                            float* __restrict__ part){
  __shared__ __align__(16) u16 As[64*64];     // [64 i][64 j] per phase, gl16-swizzled
  __shared__ __align__(16) u16 Vt[128*64];    // [128 e][64 j] per phase, slot-XOR layout
  const int bi = blockIdx.x;                  // 512 = (kc 32) + 32*(n 8) + 256*(eh 2)
  const int kc = bi&31, n = (bi>>5)&7, eh = bi>>8;
  const int jb = kc*128, eb = eh*128;
  const int tid = threadIdx.x, lane = tid&63;
  const int c = tid&15, qq = (tid>>4)&3, wv = tid>>6;
  const u16* Pb = P + (size_t)n*LND*HWN;
  const u16* Yb = Y + (size_t)n*M3*HWN;       // raw view: V[j][e] = flat[j*768 + 512 + e]
  const int srow  = wv*8 + (lane>>3);
  const int dslot = lane&7;
  const int sgo   = (dslot ^ (lane>>3))*8;
  const int rdswz = (c&7);
  f32x4 acc[4][2];
  #pragma unroll
  for(int mt=0;mt<4;mt++)
    #pragma unroll
    for(int nt=0;nt<2;nt++){ acc[mt][nt][0]=0.f; acc[mt][nt][1]=0.f; acc[mt][nt][2]=0.f; acc[mt][nt][3]=0.f; }
  for(int ph=0; ph<2; ph++){
    // A: 64 rows x 64 j (gl16, 2 per thread)
    #pragma unroll
    for(int j=0;j<2;j++){
      int r = j*32 + srow;
      gl16(Pb + (size_t)r*HWN + jb + ph*64 + sgo, &As[r*64 + dslot*8]);
    }
    // B: 64 j x 128 e, transposed into Vt[e][j]
    #pragma unroll
    for(int rep=0; rep<4; rep++){
      int jl = (tid>>4) + 16*rep;                       // 0..63
      int ec = (tid&15)*8;                              // 0..120
      uint4 U = *(const uint4*)&Yb[(size_t)(jb+ph*64+jl)*M3 + 512 + eb + ec];
      const u16* uv = (const u16*)&U;
      #pragma unroll
      for(int k=0;k<8;k++){
        int e = ec+k;
        int slot = ((jl>>3) ^ (e&7) ^ ((e>>3)&7)) & 7;
        Vt[e*64 + slot*8 + (jl&7)] = uv[k];
      }
    }
    __syncthreads();
    #pragma unroll
    for(int kt=0;kt<2;kt++){
      const int rslotA = ((kt*4+qq)^rdswz)*8;
      short8 af[4];
      #pragma unroll
      for(int mt=0;mt<4;mt++) af[mt] = *(const short8*)&As[(mt*16+c)*64 + rslotA];
      #pragma unroll
      for(int nt=0;nt<2;nt++){
        int e = wv*32 + nt*16 + c;
        int slotB = ((kt*4+qq) ^ (e&7) ^ ((e>>3)&7)) & 7;
        short8 bf_ = *(const short8*)&Vt[e*64 + slotB*8];
        #pragma unroll
        for(int mt=0;mt<4;mt++)
          acc[mt][nt] = __builtin_amdgcn_mfma_f32_16x16x32_bf16(af[mt], bf_, acc[mt][nt], 0, 0, 0);
      }
    }
    __syncthreads();
  }
  float* pb = part + ((size_t)n*32 + kc)*LND*EDIM + eb;
  #pragma unroll
  for(int mt=0;mt<4;mt++){
    int row0 = mt*16 + 4*qq;
    #pragma unroll
    for(int nt=0;nt<2;nt++){
      int e = wv*32 + nt*16 + c;
      pb[(size_t)(row0+0)*EDIM + e] = acc[mt][nt][0];
      pb[(size_t)(row0+1)*EDIM + e] = acc[mt][nt][1];
      pb[(size_t)(row0+2)*EDIM + e] = acc[mt][nt][2];
      pb[(size_t)(row0+3)*EDIM + e] = acc[mt][nt][3];
    }
  }
}

__global__ void k_fred(const float* __restrict__ part, float* __restrict__ B3){
  const int idx = blockIdx.x*256 + threadIdx.x;
  const int n = idx >> 14, rem = idx & 16383;
  const float* p = part + (size_t)n*32*16384 + rem;
  float s = 0.f;
  #pragma unroll
  for(int kc=0;kc<32;kc++) s += p[(size_t)kc*16384];
  B3[idx] = s;
}

// ---------------- C2[j][e] = sum_l Kinv[j][l]*B3[l][e] ----------------
__global__ __launch_bounds__(256) void k_c2(const float* __restrict__ KinvT, const float* __restrict__ B3,
                                            float* __restrict__ C2){
  const int eb = blockIdx.x*64, n = blockIdx.y, tid = threadIdx.x;
  __shared__ float KT[64][68];
  __shared__ float Bs2[64][68];
  {
    int l = tid>>2, o16 = (tid&3)*16;
    const float* kp = KinvT + (size_t)n*4096 + l*64 + o16;
    const float* bp = B3 + ((size_t)n*LND + l)*EDIM + eb + o16;
    #pragma unroll
    for(int t=0;t<16;t+=4){
      *(float4*)&KT[l][o16+t]  = *(const float4*)(kp+t);
      *(float4*)&Bs2[l][o16+t] = *(const float4*)(bp+t);
    }
  }
  __syncthreads();
  const int j0 = (tid>>4)*4, u0 = (tid&15)*4;
  float acc[4][4] = {};
  #pragma unroll 8
  for(int l=0;l<64;l++){
    f32x4 a = *(f32x4*)&KT[l][j0];
    f32x4 b = *(f32x4*)&Bs2[l][u0];
    #pragma unroll
    for(int s=0;s<4;s++)
      #pragma unroll
      for(int u=0;u<4;u++) acc[s][u] += a[s]*b[u];
  }
  #pragma unroll
  for(int s=0;s<4;s++){
    float4 fv = make_float4(acc[s][0],acc[s][1],acc[s][2],acc[s][3]);
    *(float4*)&C2[((size_t)n*LND + j0+s)*EDIM + eb + u0] = fv;
  }
}

// ---------------- out[i][e] = sum_j k1t[j][i]*C2[j][e] + v[i][e]; OM bf16 ----------------
__global__ __launch_bounds__(256) void k_out(const float* __restrict__ Z1, const float* __restrict__ C2,
                                             const u16* __restrict__ Y, u16* __restrict__ OM){
  const int ib = blockIdx.x*64, n = blockIdx.y, tid = threadIdx.x;
  __shared__ float K1s[64][68];
  __shared__ u16 C2s[64*264];
  {
    int j = tid>>2, i16 = (tid&3)*16;
    const float* zp = Z1 + ((size_t)n*LND + j)*HWN + ib + i16;
    #pragma unroll
    for(int t=0;t<16;t+=4) *(float4*)&K1s[j][i16+t] = *(const float4*)(zp+t);
    int e64 = (tid&3)*64;
    const float* cp = C2 + ((size_t)n*LND + j)*EDIM + e64;
    #pragma unroll
    for(int t=0;t<64;t+=4){
      float4 v = *(const float4*)(cp+t);
      C2s[j*264 + e64+t+0] = f2bf(v.x);
      C2s[j*264 + e64+t+1] = f2bf(v.y);
      C2s[j*264 + e64+t+2] = f2bf(v.z);
      C2s[j*264 + e64+t+3] = f2bf(v.w);
    }
  }
  __syncthreads();
  const int i0 = (tid>>4)*4, e0 = (tid&15)*16;
  float acc[4][16] = {};
  for(int j=0;j<64;j++){
    f32x4 a = *(f32x4*)&K1s[j][i0];
    const u16* cb = &C2s[j*264 + e0];
    uint4 U0 = *(const uint4*)cb;
    uint4 U1 = *(const uint4*)(cb+8);
    float bv[16];
    bf2x2(U0.x, bv[0], bv[1]);  bf2x2(U0.y, bv[2], bv[3]);
    bf2x2(U0.z, bv[4], bv[5]);  bf2x2(U0.w, bv[6], bv[7]);
    bf2x2(U1.x, bv[8], bv[9]);  bf2x2(U1.y, bv[10], bv[11]);
    bf2x2(U1.z, bv[12], bv[13]); bf2x2(U1.w, bv[14], bv[15]);
    #pragma unroll
    for(int u=0;u<16;u++){
      acc[0][u] += a[0]*bv[u];
      acc[1][u] += a[1]*bv[u];
      acc[2][u] += a[2]*bv[u];
      acc[3][u] += a[3]*bv[u];
    }
  }
  const u16* Yb = Y + (size_t)n*M3*HWN;
  u16* ob = OM + (size_t)n*HWN*EDIM;
  #pragma unroll
  for(int s=0;s<4;s++){
    int i = ib + i0 + s;
    const u16* vp = Yb + (size_t)i*M3 + 512 + e0;
    uint4 U0 = *(const uint4*)vp, U1 = *(const uint4*)(vp+8);
    float vv[16];
    bf2x2(U0.x, vv[0], vv[1]);  bf2x2(U0.y, vv[2], vv[3]);
    bf2x2(U0.z, vv[4], vv[5]);  bf2x2(U0.w, vv[6], vv[7]);
    bf2x2(U1.x, vv[8], vv[9]);  bf2x2(U1.y, vv[10], vv[11]);
    bf2x2(U1.z, vv[12], vv[13]); bf2x2(U1.w, vv[14], vv[15]);
    #pragma unroll
    for(int t=0;t<16;t+=4){
      ushort4 o;
      o.x = f2bf(acc[s][t+0]+vv[t+0]);
      o.y = f2bf(acc[s][t+1]+vv[t+1]);
      o.z = f2bf(acc[s][t+2]+vv[t+2]);
      o.w = f2bf(acc[s][t+3]+vv[t+3]);
      *(ushort4*)&ob[(size_t)i*EDIM + e0 + t] = o;
    }
  }
}

// ---------------- transpose of raw-reshaped OM ----------------
__global__ __launch_bounds__(256) void k_trans2(const u16* __restrict__ OM, u16* __restrict__ OMT){
  __shared__ u16 Ts[64*65];
  const int bi = blockIdx.x;
  const int n = bi>>8, rem = bi&255, et = rem>>6, pt = rem&63;
  const int e0 = et*64, p0 = pt*64, tid = threadIdx.x;
  const u16* omb = OM + (size_t)n*HWN*EDIM;
  {
    int ee = tid>>2, pj = (tid&3)*16;
    const u16* ip = omb + (size_t)(e0+ee)*HWN + p0 + pj;
    ushort4 v0 = *(const ushort4*)(ip);
    ushort4 v1 = *(const ushort4*)(ip+4);
    ushort4 v2 = *(const ushort4*)(ip+8);
    ushort4 v3 = *(const ushort4*)(ip+12);
    u16* tp = &Ts[ee*65 + pj];
    tp[0]=v0.x; tp[1]=v0.y; tp[2]=v0.z; tp[3]=v0.w;
    tp[4]=v1.x; tp[5]=v1.y; tp[6]=v1.z; tp[7]=v1.w;
    tp[8]=v2.x; tp[9]=v2.y; tp[10]=v2.z; tp[11]=v2.w;
    tp[12]=v3.x; tp[13]=v3.y; tp[14]=v3.z; tp[15]=v3.w;
  }
  __syncthreads();
  {
    int pp = tid>>2, ej = (tid&3)*16;
    u16* op = OMT + ((size_t)n*HWN + p0 + pp)*EDIM + e0 + ej;
    ushort4 o[4];
    #pragma unroll
    for(int j=0;j<16;j++) ((u16*)o)[j] = Ts[(ej+j)*65 + pp];
    *(ushort4*)(op+0)  = o[0];
    *(ushort4*)(op+4)  = o[1];
    *(ushort4*)(op+8)  = o[2];
    *(ushort4*)(op+12) = o[3];
  }
}

// ---------------- proj GEMM 128x128xK256, global_load_lds + XOR swizzle ----------------
__global__ __launch_bounds__(256) void k_proj(const u16* __restrict__ Wb, const u16* __restrict__ OMT,
                                              const float* __restrict__ bias, float* __restrict__ out){
  __shared__ __align__(16) u16 As[128*64];
  __shared__ __align__(16) u16 Bs[128*64];
  const int bi = blockIdx.x;
  const int n = bi&7, rem = bi>>3;
  const int ch0 = (rem&1)*128, p0 = (rem>>1)*128;
  const int tid = threadIdx.x, lane = tid&63;
  const int c = tid&15, qq = (tid>>4)&3, w4 = tid>>6;
  const int wr0 = (w4&1)*64, wc0 = (w4>>1)*64;
  const u16* xb = OMT + ((size_t)n*HWN + p0)*EDIM;
  const u16* wb = Wb + (size_t)ch0*EDIM;
  f32x4 acc[4][4];
  #pragma unroll
  for(int mt=0;mt<4;mt++)
    #pragma unroll
    for(int nt=0;nt<4;nt++){ acc[mt][nt][0]=0.f; acc[mt][nt][1]=0.f; acc[mt][nt][2]=0.f; acc[mt][nt][3]=0.f; }
  const int srow  = w4*8 + (lane>>3);
  const int dslot = lane&7;
  const int sgo   = (dslot ^ (lane>>3))*8;
  const int rdswz = (c&7);
  for(int ph=0; ph<4; ph++){
    #pragma unroll
    for(int j=0;j<4;j++){
      int r = j*32 + srow;
      gl16(wb + (size_t)r*EDIM + ph*64 + sgo, &As[r*64 + dslot*8]);
    }
    #pragma unroll
    for(int j=0;j<4;j++){
      int r = j*32 + srow;
      gl16(xb + (size_t)r*EDIM + ph*64 + sgo, &Bs[r*64 + dslot*8]);
    }
    __syncthreads();
    #pragma unroll
    for(int kt=0;kt<2;kt++){
      short8 af[4], bff[4];
      const int rslot = ((kt*4+qq)^rdswz)*8;
      #pragma unroll
      for(int mt=0;mt<4;mt++) af[mt]  = *(const short8*)&As[(wr0+mt*16+c)*64 + rslot];
      #pragma unroll
      for(int nt=0;nt<4;nt++) bff[nt] = *(const short8*)&Bs[(wc0+nt*16+c)*64 + rslot];
      #pragma unroll
      for(int mt=0;mt<4;mt++)
        #pragma unroll
        for(int nt=0;nt<4;nt++)
          acc[mt][nt] = __builtin_amdgcn_mfma_f32_16x16x32_bf16(af[mt], bff[nt], acc[mt][nt], 0, 0, 0);
    }
    __syncthreads();
  }
  float* ob = out + (size_t)n*EDIM*HWN;
  #pragma unroll
  for(int mt=0;mt<4;mt++){
    int chb = ch0 + wr0 + mt*16 + 4*qq;
    float b0 = bias[chb], b1 = bias[chb+1], b2 = bias[chb+2], b3 = bias[chb+3];
    #pragma unroll
    for(int nt=0;nt<4;nt++){
      int p = p0 + wc0 + nt*16 + c;
      float* yp = ob + (size_t)chb*HWN + p;
      yp[0]             = acc[mt][nt][0]+b0;
      yp[HWN]           = acc[mt][nt][1]+b1;
      yp[2*(size_t)HWN] = acc[mt][nt][2]+b2;
      yp[3*(size_t)HWN] = acc[mt][nt][3]+b3;
    }
  }
}

extern "C" void kernel_launch(void* const* d_in, const int* in_sizes, int n_in,
                              void* d_out, int out_size, void* d_ws, size_t ws_size,
                              hipStream_t stream){
  (void)out_size; (void)ws_size;
  const float* x     = (const float*)d_in[0];
  const float* w_qkv = (const float*)d_in[1];
  const float* b_qkv = (const float*)d_in[2];
  const float* w_out = (const float*)d_in[3];
  const float* b_out = (const float*)d_in[4];
  for(int i=0;i<n_in;i++){
    switch(in_sizes[i]){
      case 8388608: x     = (const float*)d_in[i]; break;
      case 196608:  w_qkv = (const float*)d_in[i]; break;
      case 768:     b_qkv = (const float*)d_in[i]; break;
      case 65536:   w_out = (const float*)d_in[i]; break;
      case 256:     b_out = (const float*)d_in[i]; break;
      default: break;
    }
  }
  float* out = (float*)d_out;
  char* ws = (char*)d_ws;

  u16*   Y     = (u16*)(ws + 0);              // 50,331,648 B  bf16 [8][768*4096]
  float* qland = (float*)(ws + 50331648);
  float* kland = (float*)(ws + 50855936);
  float* Z1    = (float*)(ws + 51380224);
  float* Z3    = (float*)(ws + 59768832);
  float* KinvT = (float*)(ws + 68157440);
  u16*   Xt    = (u16*)(ws + 68288512);       // 16 MB region: Xt -> part -> OMT
  float* part  = (float*)(ws + 68288512);
  u16*   OMT   = (u16*)(ws + 68288512);
  float* B3    = (float*)(ws + 85065728);
  float* C2    = (float*)(ws + 85590016);
  u16*   OM    = (u16*)(ws + 86114304);       // 16 MB bf16; P (4.2 MB) lives here until k_out
  u16*   Pbuf  = (u16*)(ws + 86114304);       // bf16 [8][64][4096], dead before OM is written
  // Wqb overlaps Z3 (Z3 written by k_landgemm AFTER k_qkv consumes Wqb — stream-ordered safe)
  u16*   Wqb   = (u16*)(ws + 59768832);       // 393,216 B bf16 [768][256]
  u16*   Wob   = (u16*)(ws + 102891520);      // 131,072 B bf16 [256][256] (persists to k_proj)

  k_prep    <<<dim3(2056),   256, 0, stream>>>(x, Xt, w_qkv, w_out, Wqb, Wob);
  k_qkv     <<<dim3(1536),   256, 0, stream>>>(Wqb, Xt, b_qkv, Y);
  k_land    <<<dim3(64,8),   256, 0, stream>>>(Y, qland, kland);
  k_landgemm<<<dim3(65,16),  256, 0, stream>>>(Y, qland, kland, Z1, Z3, KinvT);
  k_mega    <<<dim3(768),    256, 0, stream>>>(Z3, Pbuf, Z1);
  k_pv      <<<dim3(512),    256, 0, stream>>>(Pbuf, Y, part);
  k_fred    <<<dim3(512),    256, 0, stream>>>(part, B3);
  k_c2      <<<dim3(4,8),    256, 0, stream>>>(KinvT, B3, C2);
  k_out     <<<dim3(64,8),   256, 0, stream>>>(Z1, C2, Y, OM);
  k_trans2  <<<dim3(2048),   256, 0, stream>>>(OM, OMT);
  k_proj    <<<dim3(512),    256, 0, stream>>>(Wob, OMT, b_out, out);
}

// Round 7
// 211.456 us; speedup vs baseline: 1.6139x; 1.0443x over previous
//
#include <hip/hip_runtime.h>
#include <hip/hip_bf16.h>

typedef unsigned short u16;
typedef __attribute__((ext_vector_type(4))) float f32x4;
typedef __attribute__((ext_vector_type(8))) short short8;

#define NB   8
#define CIN  256
#define EDIM 256
#define M3   768
#define HWN  4096
#define LND  64
#define NS2  72    // NS LDS row stride (bf16 elems): 144B, 16B aligned

__device__ __forceinline__ float bf2f(u16 u){ return __uint_as_float(((unsigned)u)<<16); }
__device__ __forceinline__ u16 f2bf(float f){ __hip_bfloat16 h = __float2bfloat16(f); return *reinterpret_cast<u16*>(&h); }
__device__ __forceinline__ void bf2x2(unsigned u, float &lo, float &hi){
  lo = __uint_as_float(u<<16);
  hi = __uint_as_float(u & 0xffff0000u);
}

typedef __attribute__((address_space(1))) unsigned as1_uint;
typedef __attribute__((address_space(3))) unsigned as3_uint;
// async global->LDS, 16B per lane; dest must be wave-uniform base + lane*16
__device__ __forceinline__ void gl16(const void* g, void* l){
  __builtin_amdgcn_global_load_lds((const as1_uint*)g, (as3_uint*)l, 16, 0, 0);
}

// ---------------- prep: Xt[n][p][c] (bf16) = transpose of X[n][c][p] (fp32) ----------------
// blocks >= 2048: convert w_qkv / w_out to bf16 (once, instead of per GEMM block)
__global__ __launch_bounds__(256) void k_prep(const float* __restrict__ x, u16* __restrict__ Xt,
                                              const float* __restrict__ wq, const float* __restrict__ wo,
                                              u16* __restrict__ Wqb, u16* __restrict__ Wob){
  const int bi = blockIdx.x;
  const int tid = threadIdx.x;
  if(bi >= 2048){
    int ti = (bi-2048)*256 + tid;          // 0..2047
    const float* src; u16* dst;
    if(ti < 1536){ src = wq + (size_t)ti*128;        dst = Wqb + (size_t)ti*128; }
    else         { src = wo + (size_t)(ti-1536)*128; dst = Wob + (size_t)(ti-1536)*128; }
    #pragma unroll
    for(int t=0;t<128;t+=8){
      float4 v0 = *(const float4*)(src+t);
      float4 v1 = *(const float4*)(src+t+4);
      ushort4 o0, o1;
      o0.x=f2bf(v0.x); o0.y=f2bf(v0.y); o0.z=f2bf(v0.z); o0.w=f2bf(v0.w);
      o1.x=f2bf(v1.x); o1.y=f2bf(v1.y); o1.z=f2bf(v1.z); o1.w=f2bf(v1.w);
      *(ushort4*)(dst+t)   = o0;
      *(ushort4*)(dst+t+4) = o1;
    }
    return;
  }
  __shared__ float Ts[64*65];
  const int n = bi>>8, rem = bi&255, ct = rem>>6, pt = rem&63;
  const int c0 = ct*64, p0 = pt*64;
  {
    int cc = tid>>2, pj = (tid&3)*16;
    const float* xp = x + (size_t)n*CIN*HWN + (size_t)(c0+cc)*HWN + p0 + pj;
    #pragma unroll
    for(int j=0;j<16;j++) Ts[cc*65 + pj + j] = xp[j];
  }
  __syncthreads();
  {
    int pp = tid>>2, ej = (tid&3)*16;
    u16* op = Xt + ((size_t)n*HWN + p0 + pp)*CIN + c0 + ej;
    ushort4 o[4];
    #pragma unroll
    for(int j=0;j<16;j++) ((u16*)o)[j] = f2bf(Ts[(ej+j)*65 + pp]);
    *(ushort4*)(op+0)  = o[0];
    *(ushort4*)(op+4)  = o[1];
    *(ushort4*)(op+8)  = o[2];
    *(ushort4*)(op+12) = o[3];
  }
}

// ---------------- QKV GEMM 128x128xK256 bf16 MFMA, global_load_lds + XOR swizzle ------------
__global__ __launch_bounds__(256) void k_qkv(const u16* __restrict__ Wb, const u16* __restrict__ Xt,
                                             const float* __restrict__ bias, u16* __restrict__ Y){
  __shared__ __align__(16) u16 As[128*64];
  __shared__ __align__(16) u16 Bs[128*64];
  const int bi = blockIdx.x;
  const int n = bi&7, rem = bi>>3;
  const int ch0 = (rem%6)*128, p0 = (rem/6)*128;
  const int tid = threadIdx.x, lane = tid&63;
  const int c = tid&15, qq = (tid>>4)&3, w4 = tid>>6;
  const int wr0 = (w4&1)*64, wc0 = (w4>>1)*64;
  const u16* xb = Xt + ((size_t)n*HWN + p0)*CIN;
  const u16* wb = Wb + (size_t)ch0*CIN;
  f32x4 acc[4][4];
  #pragma unroll
  for(int mt=0;mt<4;mt++)
    #pragma unroll
    for(int nt=0;nt<4;nt++){ acc[mt][nt][0]=0.f; acc[mt][nt][1]=0.f; acc[mt][nt][2]=0.f; acc[mt][nt][3]=0.f; }
  const int srow  = w4*8 + (lane>>3);
  const int dslot = lane&7;
  const int sgo   = (dslot ^ (lane>>3))*8;       // swizzled source u16 offset within row-chunk
  const int rdswz = (c&7);                        // read-side row&7
  for(int ph=0; ph<4; ph++){
    #pragma unroll
    for(int j=0;j<4;j++){
      int r = j*32 + srow;
      gl16(wb + (size_t)r*CIN + ph*64 + sgo, &As[r*64 + dslot*8]);
    }
    #pragma unroll
    for(int j=0;j<4;j++){
      int r = j*32 + srow;
      gl16(xb + (size_t)r*CIN + ph*64 + sgo, &Bs[r*64 + dslot*8]);
    }
    __syncthreads();
    #pragma unroll
    for(int kt=0;kt<2;kt++){
      short8 af[4], bff[4];
      const int rslot = ((kt*4+qq)^rdswz)*8;
      #pragma unroll
      for(int mt=0;mt<4;mt++) af[mt]  = *(const short8*)&As[(wr0+mt*16+c)*64 + rslot];
      #pragma unroll
      for(int nt=0;nt<4;nt++) bff[nt] = *(const short8*)&Bs[(wc0+nt*16+c)*64 + rslot];
      #pragma unroll
      for(int mt=0;mt<4;mt++)
        #pragma unroll
        for(int nt=0;nt<4;nt++)
          acc[mt][nt] = __builtin_amdgcn_mfma_f32_16x16x32_bf16(af[mt], bff[nt], acc[mt][nt], 0, 0, 0);
    }
    __syncthreads();
  }
  u16* Yb = Y + (size_t)n*M3*HWN;
  #pragma unroll
  for(int mt=0;mt<4;mt++){
    int chb = ch0 + wr0 + mt*16 + 4*qq;
    float b0 = bias[chb], b1 = bias[chb+1], b2 = bias[chb+2], b3 = bias[chb+3];
    #pragma unroll
    for(int nt=0;nt<4;nt++){
      int p = p0 + wc0 + nt*16 + c;
      u16* yp = Yb + (size_t)chb*HWN + p;
      yp[0]             = f2bf(acc[mt][nt][0]+b0);
      yp[HWN]           = f2bf(acc[mt][nt][1]+b1);
      yp[2*(size_t)HWN] = f2bf(acc[mt][nt][2]+b2);
      yp[3*(size_t)HWN] = f2bf(acc[mt][nt][3]+b3);
    }
  }
}

// ---------------- landmarks ----------------
__global__ void k_land(const u16* __restrict__ Y, float* __restrict__ qland, float* __restrict__ kland){
  const int l = blockIdx.x, n = blockIdx.y, e = threadIdx.x;
  const u16* base = Y + (size_t)n*M3*HWN;
  float qs=0.f, ks=0.f;
  #pragma unroll 8
  for(int m=0;m<64;m++){
    size_t off = (size_t)(l*64+m)*M3;
    qs += bf2f(base[off+e]);
    ks += bf2f(base[off+256+e]);
  }
  qland[((size_t)n*LND+l)*EDIM+e] = qs*(1.f/4096.f);
  kland[((size_t)n*LND+l)*EDIM+e] = ks*(1.f/4096.f);
}

// ---------------- NS 64x64 matmul via bf16 MFMA (per-operand LDS row stride) ----------------
__device__ __forceinline__ void ns_mm2(const u16* L, int sL, const u16* Rt, int sR,
                                       int wv, int q, int c, f32x4 r4[4]){
  short8 a0 = *(const short8*)(L + (size_t)(16*wv + c)*sL + 8*q);
  short8 a1 = *(const short8*)(L + (size_t)(16*wv + c)*sL + 32 + 8*q);
  #pragma unroll
  for(int tc=0;tc<4;tc++){
    f32x4 acc = {0.f,0.f,0.f,0.f};
    short8 b0 = *(const short8*)(Rt + (size_t)(16*tc + c)*sR + 8*q);
    short8 b1 = *(const short8*)(Rt + (size_t)(16*tc + c)*sR + 32 + 8*q);
    acc = __builtin_amdgcn_mfma_f32_16x16x32_bf16(a0, b0, acc, 0, 0, 0);
    acc = __builtin_amdgcn_mfma_f32_16x16x32_bf16(a1, b1, acc, 0, 0, 0);
    r4[tc] = acc;
  }
}

// ---------------- NS body (k2 + Newton-Schulz pseudo-inverse) ----------------
#define TTS 64
__device__ void ns_body(int n, char* smem, const float* __restrict__ qland,
                        const float* __restrict__ kland, float* __restrict__ KinvT){
  u16* Kb  = (u16*)(smem + 0);
  u16* Vb  = (u16*)(smem + 9216);
  u16* Vt  = (u16*)(smem + 18432);
  u16* KVb = (u16*)(smem + 27648);
  u16* KVt = (u16*)(smem + 36864);
  u16* Tt  = (u16*)(smem + 46080);         // stride 64, 8192 B -> end 54272
  float* sS   = (float*)(smem + 27648);    // 64x66 f32 = 16896, aliases KVb/KVt
  float* sred = (float*)(smem + 44544);    // 520 B, ends 45064 < 46080
  const int tid = threadIdx.x;
  const int wv = tid>>6, q = (tid>>4)&3, c = tid&15;
  const float* qb = qland + (size_t)n*LND*EDIM;
  const float* kb = kland + (size_t)n*LND*EDIM;
  f32x4 acc[4];
  #pragma unroll
  for(int t=0;t<4;t++){ acc[t][0]=0.f; acc[t][1]=0.f; acc[t][2]=0.f; acc[t][3]=0.f; }
  for(int e0=0;e0<EDIM;e0+=64){
    __syncthreads();
    {
      int row = tid>>2, c0 = (tid&3)*16;
      const float* qp = qb + (size_t)row*EDIM + e0 + c0;
      const float* kp = kb + (size_t)row*EDIM + e0 + c0;
      u16* qd = &KVb[row*NS2 + c0];
      u16* kd = &KVt[row*NS2 + c0];
      #pragma unroll
      for(int j=0;j<16;j+=4){
        float4 qv = *(const float4*)(qp+j);
        float4 kv = *(const float4*)(kp+j);
        ushort4 qo, ko;
        qo.x=f2bf(qv.x); qo.y=f2bf(qv.y); qo.z=f2bf(qv.z); qo.w=f2bf(qv.w);
        ko.x=f2bf(kv.x); ko.y=f2bf(kv.y); ko.z=f2bf(kv.z); ko.w=f2bf(kv.w);
        *(ushort4*)(qd+j) = qo;
        *(ushort4*)(kd+j) = ko;
      }
    }
    __syncthreads();
    {
      short8 a0 = *(const short8*)&KVb[(16*wv+c)*NS2 + 8*q];
      short8 a1 = *(const short8*)&KVb[(16*wv+c)*NS2 + 32 + 8*q];
      #pragma unroll
      for(int tc=0;tc<4;tc++){
        short8 b0 = *(const short8*)&KVt[(16*tc+c)*NS2 + 8*q];
        short8 b1 = *(const short8*)&KVt[(16*tc+c)*NS2 + 32 + 8*q];
        acc[tc] = __builtin_amdgcn_mfma_f32_16x16x32_bf16(a0, b0, acc[tc], 0, 0, 0);
        acc[tc] = __builtin_amdgcn_mfma_f32_16x16x32_bf16(a1, b1, acc[tc], 0, 0, 0);
      }
    }
  }
  __syncthreads();   // KVb/KVt reads done everywhere before sS (alias) is written
  #pragma unroll
  for(int tc=0;tc<4;tc++){
    int col = 16*tc + c, row0 = 16*wv + 4*q;
    sS[(row0+0)*66+col] = acc[tc][0];
    sS[(row0+1)*66+col] = acc[tc][1];
    sS[(row0+2)*66+col] = acc[tc][2];
    sS[(row0+3)*66+col] = acc[tc][3];
  }
  __syncthreads();
  if(tid < 64){
    int j = tid;
    float m = -1e30f;
    for(int i=0;i<64;i++) m = fmaxf(m, sS[i*66+j]);
    float ssum = 0.f;
    for(int i=0;i<64;i++) ssum += __expf(sS[i*66+j]-m);
    float inv = 1.f/ssum, cs = 0.f;
    for(int i=0;i<64;i++){
      float kv = __expf(sS[i*66+j]-m)*inv;
      cs += fabsf(kv);
      Kb[i*NS2+j] = f2bf(kv);
    }
    sred[j] = cs;
  }
  __syncthreads();
  if(tid < 64){
    int i = tid; float rs = 0.f;
    for(int j=0;j<64;j++) rs += fabsf(bf2f(Kb[i*NS2+j]));
    sred[64+i] = rs;
  }
  __syncthreads();
  if(tid == 0){
    float v0=-1e30f, vi=-1e30f;
    for(int t=0;t<64;t++){ v0 = fmaxf(v0, sred[t]); vi = fmaxf(vi, sred[64+t]); }
    sred[128] = 1.f/(v0*vi);
  }
  __syncthreads();
  {
    float sc = sred[128];
    int i = tid>>2, j16 = (tid&3)*16;
    #pragma unroll
    for(int jj=0;jj<16;jj++){
      int j = j16+jj;
      u16 bvv = f2bf(bf2f(Kb[j*NS2+i])*sc);
      Vb[i*NS2+j] = bvv;
      Vt[j*NS2+i] = bvv;
    }
  }
  __syncthreads();
  f32x4 r4[4];
  for(int it=0; it<6; it++){
    ns_mm2(Kb, NS2, Vt, NS2, wv, q, c, r4);
    #pragma unroll
    for(int tc=0;tc<4;tc++){
      int col = 16*tc + c, row0 = 16*wv + 4*q;
      ushort4 pk;
      pk.x = f2bf(r4[tc][0]); pk.y = f2bf(r4[tc][1]); pk.z = f2bf(r4[tc][2]); pk.w = f2bf(r4[tc][3]);
      KVb[(row0+0)*NS2+col] = pk.x; KVb[(row0+1)*NS2+col] = pk.y;
      KVb[(row0+2)*NS2+col] = pk.z; KVb[(row0+3)*NS2+col] = pk.w;
      *(ushort4*)&KVt[(size_t)col*NS2 + row0] = pk;
    }
    __syncthreads();
    ns_mm2(KVb, NS2, KVt, NS2, wv, q, c, r4);
    #pragma unroll
    for(int tc=0;tc<4;tc++){
      int col = 16*tc+c, row0 = 16*wv+4*q;
      ushort4 pk;
      #pragma unroll
      for(int r=0;r<4;r++){
        float kvv = bf2f(KVb[(row0+r)*NS2+col]);
        ((u16*)&pk)[r] = f2bf(7.f*kvv - r4[tc][r]);
      }
      *(ushort4*)&Tt[(size_t)col*TTS + row0] = pk;
    }
    __syncthreads();
    ns_mm2(KVb, NS2, Tt, TTS, wv, q, c, r4);
    __syncthreads();
    #pragma unroll
    for(int tc=0;tc<4;tc++){
      int col = 16*tc+c, row0 = 16*wv+4*q;
      ushort4 pk;
      #pragma unroll
      for(int r=0;r<4;r++){
        float kvv = bf2f(KVb[(row0+r)*NS2+col]);
        ((u16*)&pk)[r] = f2bf(15.f*kvv - r4[tc][r]);
      }
      *(ushort4*)&Tt[(size_t)col*TTS + row0] = pk;
    }
    __syncthreads();
    ns_mm2(Vb, NS2, Tt, TTS, wv, q, c, r4);
    __syncthreads();
    #pragma unroll
    for(int tc=0;tc<4;tc++){
      int col = 16*tc+c, row0 = 16*wv+4*q;
      float nv[4]; ushort4 pk;
      #pragma unroll
      for(int r=0;r<4;r++){
        float vv = bf2f(Vb[(row0+r)*NS2+col]);
        nv[r] = 0.25f*(13.f*vv - r4[tc][r]);
        u16 bb = f2bf(nv[r]);
        Vb[(row0+r)*NS2+col] = bb;
        ((u16*)&pk)[r] = bb;
      }
      *(ushort4*)&Vt[(size_t)col*NS2 + row0] = pk;
      if(it==5){
        *(float4*)&KinvT[(size_t)n*4096 + (size_t)col*64 + row0] = make_float4(nv[0],nv[1],nv[2],nv[3]);
      }
    }
    __syncthreads();
  }
}

// ---------------- Z1/Z3 landmark GEMM + fused NS (blockIdx.x==64) --------------------------
#define LGS 264   // A LDS row stride (u16): 528B, 16B aligned, bank-conflict-free
__global__ __launch_bounds__(256) void k_landgemm(const u16* __restrict__ Y, const float* __restrict__ qland,
                                                  const float* __restrict__ kland, float* __restrict__ Z1,
                                                  float* __restrict__ Z3, float* __restrict__ KinvT){
  __shared__ __align__(16) char usm[54272];
  const int z = blockIdx.y;
  if(blockIdx.x == 64){
    if((z&1)==0) ns_body(z>>1, usm, qland, kland, KinvT);
    return;
  }
  u16* As = (u16*)usm;                 // [64][LGS]
  u16* BsU = (u16*)(usm + 33792);      // [2][64*64]
  const int n = z>>1, which = z&1;
  const int b0 = blockIdx.x*64;
  const float* land = (which ? qland : kland) + (size_t)n*LND*EDIM;
  const int boff = which ? 256 : 0;
  float* out = (which ? Z3 : Z1) + (size_t)n*LND*HWN;
  const u16* Yb = Y + (size_t)n*M3*HWN + boff;
  const int tid = threadIdx.x, lane = tid&63;
  const int c = tid&15, qq = (tid>>4)&3, wv = tid>>6;
  {
    int r = tid>>2, c0 = (tid&3)*64;
    const float* lp = land + (size_t)r*EDIM + c0;
    u16* dp = &As[r*LGS + c0];
    #pragma unroll
    for(int j=0;j<64;j+=4){
      float4 v = *(const float4*)(lp+j);
      ushort4 o; o.x=f2bf(v.x); o.y=f2bf(v.y); o.z=f2bf(v.z); o.w=f2bf(v.w);
      *(ushort4*)(dp+j) = o;
    }
  }
  const int srow  = wv*8 + (lane>>3);            // 0..31
  const int dslot = lane&7;
  const int sgo   = (dslot ^ (lane>>3))*8;       // row&7 == lane>>3 here
  const int rdswz = (c&7);
  f32x4 acc[4];
  #pragma unroll
  for(int nt=0;nt<4;nt++){ acc[nt][0]=0.f; acc[nt][1]=0.f; acc[nt][2]=0.f; acc[nt][3]=0.f; }
  #pragma unroll
  for(int j=0;j<2;j++){
    int r = j*32 + srow;
    gl16(Yb + (size_t)(b0+r)*M3 + sgo, BsU + r*64 + dslot*8);
  }
  __syncthreads();
  for(int ph=0; ph<4; ph++){
    const int cur = ph&1;
    if(ph<3){
      #pragma unroll
      for(int j=0;j<2;j++){
        int r = j*32 + srow;
        gl16(Yb + (size_t)(b0+r)*M3 + (ph+1)*64 + sgo, BsU + (cur^1)*4096 + r*64 + dslot*8);
      }
    }
    #pragma unroll
    for(int kt=0;kt<2;kt++){
      short8 af = *(const short8*)&As[(16*wv + c)*LGS + ph*64 + kt*32 + qq*8];
      const int rslot = ((kt*4+qq)^rdswz)*8;
      #pragma unroll
      for(int nt=0;nt<4;nt++){
        short8 bff = *(const short8*)&BsU[cur*4096 + (nt*16+c)*64 + rslot];
        acc[nt] = __builtin_amdgcn_mfma_f32_16x16x32_bf16(af, bff, acc[nt], 0, 0, 0);
      }
    }
    __syncthreads();
  }
  const int m0 = 16*wv + 4*qq;
  #pragma unroll
  for(int nt=0;nt<4;nt++){
    int col = b0 + nt*16 + c;
    out[(size_t)(m0+0)*HWN + col] = acc[nt][0];
    out[(size_t)(m0+1)*HWN + col] = acc[nt][1];
    out[(size_t)(m0+2)*HWN + col] = acc[nt][2];
    out[(size_t)(m0+3)*HWN + col] = acc[nt][3];
  }
}

// ---------------- soft3: column-softmax of Z3 tile, write P bf16 [i][4096 j] row-major ------
__device__ void soft3_body(int idx, char* smem, const float* __restrict__ Z3, u16* __restrict__ P){
  const int kc = idx&31, n = idx>>5;
  const int tid = threadIdx.x, jb = kc*128;
  float* Sf   = (float*)smem;              // [64][132] logits -> exp
  float* sinv = (float*)(smem + 33792);    // [128] 1/sum per column
  const float* z3b = Z3 + (size_t)n*LND*HWN;
  {
    int ibase = (tid>>5)*8, j4 = (tid&31)*4;
    #pragma unroll
    for(int r=0;r<8;r++){
      int i = ibase + r;
      *(float4*)&Sf[i*132 + j4] = *(const float4*)&z3b[(size_t)i*HWN + jb + j4];
    }
  }
  __syncthreads();
  if(tid < 128){
    int j = tid;
    float m = -1e30f;
    for(int i=0;i<64;i++) m = fmaxf(m, Sf[i*132 + j]);
    float s = 0.f;
    for(int i=0;i<64;i++){ float e = __expf(Sf[i*132 + j] - m); Sf[i*132 + j] = e; s += e; }
    sinv[j] = 1.f/s;
  }
  __syncthreads();
  { // row pass: coalesced bf16 write of P[i][jb..jb+128]
    int i = tid>>2, j0 = (tid&3)*32;
    u16* pp = P + ((size_t)n*LND + i)*HWN + jb + j0;
    #pragma unroll
    for(int t=0;t<32;t+=4){
      ushort4 o;
      o.x = f2bf(Sf[i*132 + j0+t+0]*sinv[j0+t+0]);
      o.y = f2bf(Sf[i*132 + j0+t+1]*sinv[j0+t+1]);
      o.z = f2bf(Sf[i*132 + j0+t+2]*sinv[j0+t+2]);
      o.w = f2bf(Sf[i*132 + j0+t+3]*sinv[j0+t+3]);
      *(ushort4*)(pp+t) = o;
    }
  }
}

// ---------------- soft1 body: softmax of Z1 over contiguous 4096 ----------------
__device__ void soft1_body(int b, char* smem, float* __restrict__ Z1){
  const int n = b>>6, j = b&63, tid = threadIdx.x;
  float* redm = (float*)smem;
  float* reds = redm + 4;
  float* base = Z1 + ((size_t)n*LND + j)*HWN;
  float v[16];
  float m = -1e30f;
  #pragma unroll
  for(int r=0;r<16;r++){ v[r] = base[r*256 + tid]; m = fmaxf(m, v[r]); }
  #pragma unroll
  for(int o=32;o;o>>=1) m = fmaxf(m, __shfl_xor(m, o));
  const int wid = tid>>6;
  if((tid&63)==0) redm[wid] = m;
  __syncthreads();
  m = fmaxf(fmaxf(redm[0],redm[1]), fmaxf(redm[2],redm[3]));
  float s = 0.f;
  #pragma unroll
  for(int r=0;r<16;r++){ v[r] = __expf(v[r]-m); s += v[r]; }
  #pragma unroll
  for(int o=32;o;o>>=1) s += __shfl_xor(s, o);
  if((tid&63)==0) reds[wid] = s;
  __syncthreads();
  s = reds[0]+reds[1]+reds[2]+reds[3];
  float inv = 1.f/s;
  #pragma unroll
  for(int r=0;r<16;r++) base[r*256 + tid] = v[r]*inv;
}

// ---------------- mega: blocks 0-255 soft3 (-> P), 256-767 soft1 ----------------
__global__ __launch_bounds__(256) void k_mega(const float* __restrict__ Z3, u16* __restrict__ P,
                                              float* __restrict__ Z1){
  __shared__ __align__(16) char smem[34304];
  const int bi = blockIdx.x;
  if(bi < 256) soft3_body(bi, smem, Z3, P);
  else         soft1_body(bi-256, smem, Z1);
}

// ---------------- PV GEMM: part[n][kc][64 i][e] = P[i][jb..jb+128] @ V[j][e], MFMA ----------
__global__ __launch_bounds__(256) void k_pv(const u16* __restrict__ P, const u16* __restrict__ Y,
                                            float* __restrict__ part){
  __shared__ __align__(16) u16 As[64*64];     // [64 i][64 j] per phase, gl16-swizzled
  __shared__ __align__(16) u16 Vt[128*64];    // [128 e][64 j] per phase, slot-XOR layout
  const int bi = blockIdx.x;                  // 512 = (kc 32) + 32*(n 8) + 256*(eh 2)
  const int kc = bi&31, n = (bi>>5)&7, eh = bi>>8;
  const int jb = kc*128, eb = eh*128;
  const int tid = threadIdx.x, lane = tid&63;
  const int c = tid&15, qq = (tid>>4)&3, wv = tid>>6;
  const u16* Pb = P + (size_t)n*LND*HWN;
  const u16* Yb = Y + (size_t)n*M3*HWN;       // raw view: V[j][e] = flat[j*768 + 512 + e]
  const int srow  = wv*8 + (lane>>3);
  const int dslot = lane&7;
  const int sgo   = (dslot ^ (lane>>3))*8;
  const int rdswz = (c&7);
  f32x4 acc[4][2];
  #pragma unroll
  for(int mt=0;mt<4;mt++)
    #pragma unroll
    for(int nt=0;nt<2;nt++){ acc[mt][nt][0]=0.f; acc[mt][nt][1]=0.f; acc[mt][nt][2]=0.f; acc[mt][nt][3]=0.f; }
  for(int ph=0; ph<2; ph++){
    #pragma unroll
    for(int j=0;j<2;j++){
      int r = j*32 + srow;
      gl16(Pb + (size_t)r*HWN + jb + ph*64 + sgo, &As[r*64 + dslot*8]);
    }
    #pragma unroll
    for(int rep=0; rep<4; rep++){
      int jl = (tid>>4) + 16*rep;                       // 0..63
      int ec = (tid&15)*8;                              // 0..120
      uint4 U = *(const uint4*)&Yb[(size_t)(jb+ph*64+jl)*M3 + 512 + eb + ec];
      const u16* uv = (const u16*)&U;
      #pragma unroll
      for(int k=0;k<8;k++){
        int e = ec+k;
        int slot = ((jl>>3) ^ (e&7) ^ ((e>>3)&7)) & 7;
        Vt[e*64 + slot*8 + (jl&7)] = uv[k];
      }
    }
    __syncthreads();
    #pragma unroll
    for(int kt=0;kt<2;kt++){
      const int rslotA = ((kt*4+qq)^rdswz)*8;
      short8 af[4];
      #pragma unroll
      for(int mt=0;mt<4;mt++) af[mt] = *(const short8*)&As[(mt*16+c)*64 + rslotA];
      #pragma unroll
      for(int nt=0;nt<2;nt++){
        int e = wv*32 + nt*16 + c;
        int slotB = ((kt*4+qq) ^ (e&7) ^ ((e>>3)&7)) & 7;
        short8 bf_ = *(const short8*)&Vt[e*64 + slotB*8];
        #pragma unroll
        for(int mt=0;mt<4;mt++)
          acc[mt][nt] = __builtin_amdgcn_mfma_f32_16x16x32_bf16(af[mt], bf_, acc[mt][nt], 0, 0, 0);
      }
    }
    __syncthreads();
  }
  float* pb = part + ((size_t)n*32 + kc)*LND*EDIM + eb;
  #pragma unroll
  for(int mt=0;mt<4;mt++){
    int row0 = mt*16 + 4*qq;
    #pragma unroll
    for(int nt=0;nt<2;nt++){
      int e = wv*32 + nt*16 + c;
      pb[(size_t)(row0+0)*EDIM + e] = acc[mt][nt][0];
      pb[(size_t)(row0+1)*EDIM + e] = acc[mt][nt][1];
      pb[(size_t)(row0+2)*EDIM + e] = acc[mt][nt][2];
      pb[(size_t)(row0+3)*EDIM + e] = acc[mt][nt][3];
    }
  }
}

// ---------------- C2T[n][e][j] (bf16) = (Kinv @ sum_kc part)[j][e], fused fred+c2 ----------
__global__ __launch_bounds__(256) void k_c2(const float* __restrict__ KinvT, const float* __restrict__ part,
                                            u16* __restrict__ C2T){
  const int eb = blockIdx.x*64, n = blockIdx.y, tid = threadIdx.x;
  __shared__ float KT[64][68];
  __shared__ float Bs2[64][68];
  __shared__ u16 Ct[64*72];
  {
    int l = tid>>2, o16 = (tid&3)*16;
    const float* kp = KinvT + (size_t)n*4096 + l*64 + o16;
    #pragma unroll
    for(int t=0;t<16;t+=4) *(float4*)&KT[l][o16+t] = *(const float4*)(kp+t);
    // fused k_fred: B3[l][eb+o16..+16] = sum_kc part[n][kc][l][...]
    const float* pp = part + (size_t)n*32*16384 + (size_t)l*256 + eb + o16;
    float4 s0 = {0,0,0,0}, s1 = {0,0,0,0}, s2 = {0,0,0,0}, s3 = {0,0,0,0};
    for(int kc=0;kc<32;kc++){
      const float* b = pp + (size_t)kc*16384;
      float4 v0 = *(const float4*)(b);
      float4 v1 = *(const float4*)(b+4);
      float4 v2 = *(const float4*)(b+8);
      float4 v3 = *(const float4*)(b+12);
      s0.x+=v0.x; s0.y+=v0.y; s0.z+=v0.z; s0.w+=v0.w;
      s1.x+=v1.x; s1.y+=v1.y; s1.z+=v1.z; s1.w+=v1.w;
      s2.x+=v2.x; s2.y+=v2.y; s2.z+=v2.z; s2.w+=v2.w;
      s3.x+=v3.x; s3.y+=v3.y; s3.z+=v3.z; s3.w+=v3.w;
    }
    *(float4*)&Bs2[l][o16+0]  = s0;
    *(float4*)&Bs2[l][o16+4]  = s1;
    *(float4*)&Bs2[l][o16+8]  = s2;
    *(float4*)&Bs2[l][o16+12] = s3;
  }
  __syncthreads();
  const int j0 = (tid>>4)*4, u0 = (tid&15)*4;
  float acc[4][4] = {};
  #pragma unroll 8
  for(int l=0;l<64;l++){
    f32x4 a = *(f32x4*)&KT[l][j0];
    f32x4 b = *(f32x4*)&Bs2[l][u0];
    #pragma unroll
    for(int s=0;s<4;s++)
      #pragma unroll
      for(int u=0;u<4;u++) acc[s][u] += a[s]*b[u];
  }
  // transpose to bf16 [e][j] via LDS, then coalesced global write
  #pragma unroll
  for(int s=0;s<4;s++)
    #pragma unroll
    for(int u=0;u<4;u++)
      Ct[(u0+u)*72 + j0+s] = f2bf(acc[s][u]);
  __syncthreads();
  {
    int e = tid>>2, j16 = (tid&3)*16;
    u16* op = C2T + ((size_t)n*256 + eb + e)*64 + j16;
    #pragma unroll
    for(int t=0;t<16;t+=4)
      *(ushort4*)(op+t) = *(const ushort4*)&Ct[e*72 + j16 + t];
  }
}

// ---------------- out[i][e] = sum_j Z1[j][i]*C2[j][e] + v[i][e]; MFMA, OM bf16 --------------
// A = C2T[e][j] (gl16+XOR), B = Z1^T[i][j] (LDS transpose-scatter, bf16). D[m=e][n=i].
__global__ __launch_bounds__(256) void k_out(const float* __restrict__ Z1, const u16* __restrict__ C2T,
                                             const u16* __restrict__ Y, u16* __restrict__ OM){
  __shared__ __align__(16) u16 Cs[256*64];    // [256 e][64 j], gl16-swizzled
  __shared__ __align__(16) u16 Zt[64*72];     // [64 i][72 j]
  const int ib = blockIdx.x*64, n = blockIdx.y;
  const int tid = threadIdx.x, lane = tid&63;
  const int c = tid&15, qq = (tid>>4)&3, wv = tid>>6;
  const int srow  = wv*8 + (lane>>3);
  const int dslot = lane&7;
  const int sgo   = (dslot ^ (lane>>3))*8;
  const int rdswz = (c&7);
  const u16* cb = C2T + (size_t)n*256*64;
  #pragma unroll
  for(int j=0;j<8;j++){
    int r = j*32 + srow;
    gl16(cb + (size_t)r*64 + sgo, &Cs[r*64 + dslot*8]);
  }
  {
    int j = tid>>2, i16 = (tid&3)*16;
    const float* zp = Z1 + ((size_t)n*LND + j)*HWN + ib + i16;
    #pragma unroll
    for(int t=0;t<16;t+=4){
      float4 v = *(const float4*)(zp+t);
      Zt[(i16+t+0)*72 + j] = f2bf(v.x);
      Zt[(i16+t+1)*72 + j] = f2bf(v.y);
      Zt[(i16+t+2)*72 + j] = f2bf(v.z);
      Zt[(i16+t+3)*72 + j] = f2bf(v.w);
    }
  }
  __syncthreads();
  f32x4 acc[4][4];
  #pragma unroll
  for(int mt=0;mt<4;mt++)
    #pragma unroll
    for(int nt=0;nt<4;nt++){ acc[mt][nt][0]=0.f; acc[mt][nt][1]=0.f; acc[mt][nt][2]=0.f; acc[mt][nt][3]=0.f; }
  #pragma unroll
  for(int kt=0;kt<2;kt++){
    const int rslot = ((kt*4+qq)^rdswz)*8;
    short8 af[4], bf_[4];
    #pragma unroll
    for(int mt=0;mt<4;mt++) af[mt] = *(const short8*)&Cs[(wv*64+mt*16+c)*64 + rslot];
    #pragma unroll
    for(int nt=0;nt<4;nt++) bf_[nt] = *(const short8*)&Zt[(nt*16+c)*72 + kt*32 + qq*8];
    #pragma unroll
    for(int mt=0;mt<4;mt++)
      #pragma unroll
      for(int nt=0;nt<4;nt++)
        acc[mt][nt] = __builtin_amdgcn_mfma_f32_16x16x32_bf16(af[mt], bf_[nt], acc[mt][nt], 0, 0, 0);
  }
  // epilogue: e = wv*64 + mt*16 + 4*qq (+r), i = ib + nt*16 + c ; ushort4 V-add + store
  const u16* Yb = Y + (size_t)n*M3*HWN;
  u16* ob = OM + (size_t)n*HWN*EDIM;
  #pragma unroll
  for(int mt=0;mt<4;mt++){
    int e = wv*64 + mt*16 + 4*qq;
    #pragma unroll
    for(int nt=0;nt<4;nt++){
      int i = ib + nt*16 + c;
      ushort4 V4 = *(const ushort4*)(Yb + (size_t)i*M3 + 512 + e);
      ushort4 o;
      o.x = f2bf(acc[mt][nt][0] + bf2f(V4.x));
      o.y = f2bf(acc[mt][nt][1] + bf2f(V4.y));
      o.z = f2bf(acc[mt][nt][2] + bf2f(V4.z));
      o.w = f2bf(acc[mt][nt][3] + bf2f(V4.w));
      *(ushort4*)(ob + (size_t)i*EDIM + e) = o;
    }
  }
}

// ---------------- proj GEMM 128x128xK256; B read directly from OM raw [e'][p'] view ---------
// B-tile staged via manual transpose + slot-XOR involution (k_pv pattern); OMT eliminated.
__global__ __launch_bounds__(256) void k_proj(const u16* __restrict__ Wb, const u16* __restrict__ OM,
                                              const float* __restrict__ bias, float* __restrict__ out){
  __shared__ __align__(16) u16 As[128*64];
  __shared__ __align__(16) u16 Bt[128*64];    // [128 p][64 e'] slot-XOR layout
  const int bi = blockIdx.x;
  const int n = bi&7, rem = bi>>3;
  const int ch0 = (rem&1)*128, p0 = (rem>>1)*128;
  const int tid = threadIdx.x, lane = tid&63;
  const int c = tid&15, qq = (tid>>4)&3, w4 = tid>>6;
  const int wr0 = (w4&1)*64, wc0 = (w4>>1)*64;
  const u16* omb = OM + (size_t)n*HWN*EDIM;   // flat, viewed [256 e'][4096 p']
  const u16* wb = Wb + (size_t)ch0*EDIM;
  f32x4 acc[4][4];
  #pragma unroll
  for(int mt=0;mt<4;mt++)
    #pragma unroll
    for(int nt=0;nt<4;nt++){ acc[mt][nt][0]=0.f; acc[mt][nt][1]=0.f; acc[mt][nt][2]=0.f; acc[mt][nt][3]=0.f; }
  const int srow  = w4*8 + (lane>>3);
  const int dslot = lane&7;
  const int sgo   = (dslot ^ (lane>>3))*8;
  const int rdswz = (c&7);
  for(int ph=0; ph<4; ph++){
    #pragma unroll
    for(int j=0;j<4;j++){
      int r = j*32 + srow;
      gl16(wb + (size_t)r*EDIM + ph*64 + sgo, &As[r*64 + dslot*8]);
    }
    #pragma unroll
    for(int rep=0; rep<4; rep++){
      int ee = (tid>>4) + 16*rep;                       // 0..63 (e' within phase)
      int pc = (tid&15)*8;                              // 0..120
      uint4 U = *(const uint4*)&omb[(size_t)(ph*64+ee)*HWN + p0 + pc];
      const u16* uv = (const u16*)&U;
      #pragma unroll
      for(int k=0;k<8;k++){
        int p = pc+k;
        int slot = ((ee>>3) ^ (p&7) ^ ((p>>3)&7)) & 7;
        Bt[p*64 + slot*8 + (ee&7)] = uv[k];
      }
    }
    __syncthreads();
    #pragma unroll
    for(int kt=0;kt<2;kt++){
      const int rslot = ((kt*4+qq)^rdswz)*8;
      short8 af[4], bff[4];
      #pragma unroll
      for(int mt=0;mt<4;mt++) af[mt] = *(const short8*)&As[(wr0+mt*16+c)*64 + rslot];
      #pragma unroll
      for(int nt=0;nt<4;nt++){
        int p = wc0 + nt*16 + c;
        int slotB = ((kt*4+qq) ^ (p&7) ^ ((p>>3)&7)) & 7;
        bff[nt] = *(const short8*)&Bt[p*64 + slotB*8];
      }
      #pragma unroll
      for(int mt=0;mt<4;mt++)
        #pragma unroll
        for(int nt=0;nt<4;nt++)
          acc[mt][nt] = __builtin_amdgcn_mfma_f32_16x16x32_bf16(af[mt], bff[nt], acc[mt][nt], 0, 0, 0);
    }
    __syncthreads();
  }
  float* ob = out + (size_t)n*EDIM*HWN;
  #pragma unroll
  for(int mt=0;mt<4;mt++){
    int chb = ch0 + wr0 + mt*16 + 4*qq;
    float b0 = bias[chb], b1 = bias[chb+1], b2 = bias[chb+2], b3 = bias[chb+3];
    #pragma unroll
    for(int nt=0;nt<4;nt++){
      int p = p0 + wc0 + nt*16 + c;
      float* yp = ob + (size_t)chb*HWN + p;
      yp[0]             = acc[mt][nt][0]+b0;
      yp[HWN]           = acc[mt][nt][1]+b1;
      yp[2*(size_t)HWN] = acc[mt][nt][2]+b2;
      yp[3*(size_t)HWN] = acc[mt][nt][3]+b3;
    }
  }
}

extern "C" void kernel_launch(void* const* d_in, const int* in_sizes, int n_in,
                              void* d_out, int out_size, void* d_ws, size_t ws_size,
                              hipStream_t stream){
  (void)out_size; (void)ws_size;
  const float* x     = (const float*)d_in[0];
  const float* w_qkv = (const float*)d_in[1];
  const float* b_qkv = (const float*)d_in[2];
  const float* w_out = (const float*)d_in[3];
  const float* b_out = (const float*)d_in[4];
  for(int i=0;i<n_in;i++){
    switch(in_sizes[i]){
      case 8388608: x     = (const float*)d_in[i]; break;
      case 196608:  w_qkv = (const float*)d_in[i]; break;
      case 768:     b_qkv = (const float*)d_in[i]; break;
      case 65536:   w_out = (const float*)d_in[i]; break;
      case 256:     b_out = (const float*)d_in[i]; break;
      default: break;
    }
  }
  float* out = (float*)d_out;
  char* ws = (char*)d_ws;

  u16*   Y     = (u16*)(ws + 0);              // 50,331,648 B  bf16 [8][768*4096]
  float* qland = (float*)(ws + 50331648);
  float* kland = (float*)(ws + 50855936);
  float* Z1    = (float*)(ws + 51380224);
  float* Z3    = (float*)(ws + 59768832);
  float* KinvT = (float*)(ws + 68157440);
  float* part  = (float*)(ws + 68288512);     // 16 MB region (was Xt -> part)
  u16*   Xt    = (u16*)(ws + 68288512);
  u16*   C2T   = (u16*)(ws + 85065728);       // bf16 [8][256 e][64 j] = 256 KB
  u16*   OM    = (u16*)(ws + 86114304);       // 16 MB bf16; P (4.2 MB) lives here until k_out
  u16*   Pbuf  = (u16*)(ws + 86114304);       // bf16 [8][64][4096], dead before OM is written
  // Wqb overlaps Z3 (Z3 written by k_landgemm AFTER k_qkv consumes Wqb — stream-ordered safe)
  u16*   Wqb   = (u16*)(ws + 59768832);       // 393,216 B bf16 [768][256]
  u16*   Wob   = (u16*)(ws + 102891520);      // 131,072 B bf16 [256][256] (persists to k_proj)

  k_prep    <<<dim3(2056),   256, 0, stream>>>(x, Xt, w_qkv, w_out, Wqb, Wob);
  k_qkv     <<<dim3(1536),   256, 0, stream>>>(Wqb, Xt, b_qkv, Y);
  k_land    <<<dim3(64,8),   256, 0, stream>>>(Y, qland, kland);
  k_landgemm<<<dim3(65,16),  256, 0, stream>>>(Y, qland, kland, Z1, Z3, KinvT);
  k_mega    <<<dim3(768),    256, 0, stream>>>(Z3, Pbuf, Z1);
  k_pv      <<<dim3(512),    256, 0, stream>>>(Pbuf, Y, part);
  k_c2      <<<dim3(4,8),    256, 0, stream>>>(KinvT, part, C2T);
  k_out     <<<dim3(64,8),   256, 0, stream>>>(Z1, C2T, Y, OM);
  k_proj    <<<dim3(512),    256, 0, stream>>>(Wob, OM, b_out, out);
}

// Round 8
// 202.463 us; speedup vs baseline: 1.6856x; 1.0444x over previous
//
#include <hip/hip_runtime.h>
#include <hip/hip_bf16.h>

typedef unsigned short u16;
typedef __attribute__((ext_vector_type(4))) float f32x4;
typedef __attribute__((ext_vector_type(8))) short short8;

#define NB   8
#define CIN  256
#define EDIM 256
#define M3   768
#define HWN  4096
#define LND  64
#define NS2  72    // NS LDS row stride (bf16 elems): 144B, 16B aligned

__device__ __forceinline__ float bf2f(u16 u){ return __uint_as_float(((unsigned)u)<<16); }
__device__ __forceinline__ u16 f2bf(float f){ __hip_bfloat16 h = __float2bfloat16(f); return *reinterpret_cast<u16*>(&h); }
__device__ __forceinline__ void bf2x2(unsigned u, float &lo, float &hi){
  lo = __uint_as_float(u<<16);
  hi = __uint_as_float(u & 0xffff0000u);
}

typedef __attribute__((address_space(1))) unsigned as1_uint;
typedef __attribute__((address_space(3))) unsigned as3_uint;
// async global->LDS, 16B per lane; dest must be wave-uniform base + lane*16
__device__ __forceinline__ void gl16(const void* g, void* l){
  __builtin_amdgcn_global_load_lds((const as1_uint*)g, (as3_uint*)l, 16, 0, 0);
}

// ---------------- prep: Xt[n][p][c] (bf16) = transpose of X[n][c][p] (fp32) ----------------
// blocks >= 2048: convert w_qkv / w_out to bf16 (once, instead of per GEMM block)
__global__ __launch_bounds__(256) void k_prep(const float* __restrict__ x, u16* __restrict__ Xt,
                                              const float* __restrict__ wq, const float* __restrict__ wo,
                                              u16* __restrict__ Wqb, u16* __restrict__ Wob){
  const int bi = blockIdx.x;
  const int tid = threadIdx.x;
  if(bi >= 2048){
    int ti = (bi-2048)*256 + tid;          // 0..2047
    const float* src; u16* dst;
    if(ti < 1536){ src = wq + (size_t)ti*128;        dst = Wqb + (size_t)ti*128; }
    else         { src = wo + (size_t)(ti-1536)*128; dst = Wob + (size_t)(ti-1536)*128; }
    #pragma unroll
    for(int t=0;t<128;t+=8){
      float4 v0 = *(const float4*)(src+t);
      float4 v1 = *(const float4*)(src+t+4);
      ushort4 o0, o1;
      o0.x=f2bf(v0.x); o0.y=f2bf(v0.y); o0.z=f2bf(v0.z); o0.w=f2bf(v0.w);
      o1.x=f2bf(v1.x); o1.y=f2bf(v1.y); o1.z=f2bf(v1.z); o1.w=f2bf(v1.w);
      *(ushort4*)(dst+t)   = o0;
      *(ushort4*)(dst+t+4) = o1;
    }
    return;
  }
  __shared__ float Ts[64*65];
  const int n = bi>>8, rem = bi&255, ct = rem>>6, pt = rem&63;
  const int c0 = ct*64, p0 = pt*64;
  {
    int cc = tid>>2, pj = (tid&3)*16;
    const float* xp = x + (size_t)n*CIN*HWN + (size_t)(c0+cc)*HWN + p0 + pj;
    #pragma unroll
    for(int j=0;j<16;j++) Ts[cc*65 + pj + j] = xp[j];
  }
  __syncthreads();
  {
    int pp = tid>>2, ej = (tid&3)*16;
    u16* op = Xt + ((size_t)n*HWN + p0 + pp)*CIN + c0 + ej;
    ushort4 o[4];
    #pragma unroll
    for(int j=0;j<16;j++) ((u16*)o)[j] = f2bf(Ts[(ej+j)*65 + pp]);
    *(ushort4*)(op+0)  = o[0];
    *(ushort4*)(op+4)  = o[1];
    *(ushort4*)(op+8)  = o[2];
    *(ushort4*)(op+12) = o[3];
  }
}

// ---------------- QKV GEMM 128x128xK256 bf16 MFMA, global_load_lds + XOR swizzle ------------
__global__ __launch_bounds__(256) void k_qkv(const u16* __restrict__ Wb, const u16* __restrict__ Xt,
                                             const float* __restrict__ bias, u16* __restrict__ Y){
  __shared__ __align__(16) u16 As[128*64];
  __shared__ __align__(16) u16 Bs[128*64];
  const int bi = blockIdx.x;
  const int n = bi&7, rem = bi>>3;
  const int ch0 = (rem%6)*128, p0 = (rem/6)*128;
  const int tid = threadIdx.x, lane = tid&63;
  const int c = tid&15, qq = (tid>>4)&3, w4 = tid>>6;
  const int wr0 = (w4&1)*64, wc0 = (w4>>1)*64;
  const u16* xb = Xt + ((size_t)n*HWN + p0)*CIN;
  const u16* wb = Wb + (size_t)ch0*CIN;
  f32x4 acc[4][4];
  #pragma unroll
  for(int mt=0;mt<4;mt++)
    #pragma unroll
    for(int nt=0;nt<4;nt++){ acc[mt][nt][0]=0.f; acc[mt][nt][1]=0.f; acc[mt][nt][2]=0.f; acc[mt][nt][3]=0.f; }
  const int srow  = w4*8 + (lane>>3);
  const int dslot = lane&7;
  const int sgo   = (dslot ^ (lane>>3))*8;       // swizzled source u16 offset within row-chunk
  const int rdswz = (c&7);                        // read-side row&7
  for(int ph=0; ph<4; ph++){
    #pragma unroll
    for(int j=0;j<4;j++){
      int r = j*32 + srow;
      gl16(wb + (size_t)r*CIN + ph*64 + sgo, &As[r*64 + dslot*8]);
    }
    #pragma unroll
    for(int j=0;j<4;j++){
      int r = j*32 + srow;
      gl16(xb + (size_t)r*CIN + ph*64 + sgo, &Bs[r*64 + dslot*8]);
    }
    __syncthreads();
    #pragma unroll
    for(int kt=0;kt<2;kt++){
      short8 af[4], bff[4];
      const int rslot = ((kt*4+qq)^rdswz)*8;
      #pragma unroll
      for(int mt=0;mt<4;mt++) af[mt]  = *(const short8*)&As[(wr0+mt*16+c)*64 + rslot];
      #pragma unroll
      for(int nt=0;nt<4;nt++) bff[nt] = *(const short8*)&Bs[(wc0+nt*16+c)*64 + rslot];
      #pragma unroll
      for(int mt=0;mt<4;mt++)
        #pragma unroll
        for(int nt=0;nt<4;nt++)
          acc[mt][nt] = __builtin_amdgcn_mfma_f32_16x16x32_bf16(af[mt], bff[nt], acc[mt][nt], 0, 0, 0);
    }
    __syncthreads();
  }
  u16* Yb = Y + (size_t)n*M3*HWN;
  #pragma unroll
  for(int mt=0;mt<4;mt++){
    int chb = ch0 + wr0 + mt*16 + 4*qq;
    float b0 = bias[chb], b1 = bias[chb+1], b2 = bias[chb+2], b3 = bias[chb+3];
    #pragma unroll
    for(int nt=0;nt<4;nt++){
      int p = p0 + wc0 + nt*16 + c;
      u16* yp = Yb + (size_t)chb*HWN + p;
      yp[0]             = f2bf(acc[mt][nt][0]+b0);
      yp[HWN]           = f2bf(acc[mt][nt][1]+b1);
      yp[2*(size_t)HWN] = f2bf(acc[mt][nt][2]+b2);
      yp[3*(size_t)HWN] = f2bf(acc[mt][nt][3]+b3);
    }
  }
}

// ---------------- landmarks ----------------
__global__ void k_land(const u16* __restrict__ Y, float* __restrict__ qland, float* __restrict__ kland){
  const int l = blockIdx.x, n = blockIdx.y, e = threadIdx.x;
  const u16* base = Y + (size_t)n*M3*HWN;
  float qs=0.f, ks=0.f;
  #pragma unroll 8
  for(int m=0;m<64;m++){
    size_t off = (size_t)(l*64+m)*M3;
    qs += bf2f(base[off+e]);
    ks += bf2f(base[off+256+e]);
  }
  qland[((size_t)n*LND+l)*EDIM+e] = qs*(1.f/4096.f);
  kland[((size_t)n*LND+l)*EDIM+e] = ks*(1.f/4096.f);
}

// ---------------- NS 64x64 matmul via bf16 MFMA (per-operand LDS row stride) ----------------
__device__ __forceinline__ void ns_mm2(const u16* L, int sL, const u16* Rt, int sR,
                                       int wv, int q, int c, f32x4 r4[4]){
  short8 a0 = *(const short8*)(L + (size_t)(16*wv + c)*sL + 8*q);
  short8 a1 = *(const short8*)(L + (size_t)(16*wv + c)*sL + 32 + 8*q);
  #pragma unroll
  for(int tc=0;tc<4;tc++){
    f32x4 acc = {0.f,0.f,0.f,0.f};
    short8 b0 = *(const short8*)(Rt + (size_t)(16*tc + c)*sR + 8*q);
    short8 b1 = *(const short8*)(Rt + (size_t)(16*tc + c)*sR + 32 + 8*q);
    acc = __builtin_amdgcn_mfma_f32_16x16x32_bf16(a0, b0, acc, 0, 0, 0);
    acc = __builtin_amdgcn_mfma_f32_16x16x32_bf16(a1, b1, acc, 0, 0, 0);
    r4[tc] = acc;
  }
}

// ---------------- NS body (k2 + Newton-Schulz pseudo-inverse) ----------------
#define TTS 64
__device__ void ns_body(int n, char* smem, const float* __restrict__ qland,
                        const float* __restrict__ kland, float* __restrict__ KinvT){
  u16* Kb  = (u16*)(smem + 0);
  u16* Vb  = (u16*)(smem + 9216);
  u16* Vt  = (u16*)(smem + 18432);
  u16* KVb = (u16*)(smem + 27648);
  u16* KVt = (u16*)(smem + 36864);
  u16* Tt  = (u16*)(smem + 46080);         // stride 64, 8192 B -> end 54272
  float* sS   = (float*)(smem + 27648);    // 64x66 f32 = 16896, aliases KVb/KVt
  float* sred = (float*)(smem + 44544);    // 520 B, ends 45064 < 46080
  const int tid = threadIdx.x;
  const int wv = tid>>6, q = (tid>>4)&3, c = tid&15;
  const float* qb = qland + (size_t)n*LND*EDIM;
  const float* kb = kland + (size_t)n*LND*EDIM;
  f32x4 acc[4];
  #pragma unroll
  for(int t=0;t<4;t++){ acc[t][0]=0.f; acc[t][1]=0.f; acc[t][2]=0.f; acc[t][3]=0.f; }
  for(int e0=0;e0<EDIM;e0+=64){
    __syncthreads();
    {
      int row = tid>>2, c0 = (tid&3)*16;
      const float* qp = qb + (size_t)row*EDIM + e0 + c0;
      const float* kp = kb + (size_t)row*EDIM + e0 + c0;
      u16* qd = &KVb[row*NS2 + c0];
      u16* kd = &KVt[row*NS2 + c0];
      #pragma unroll
      for(int j=0;j<16;j+=4){
        float4 qv = *(const float4*)(qp+j);
        float4 kv = *(const float4*)(kp+j);
        ushort4 qo, ko;
        qo.x=f2bf(qv.x); qo.y=f2bf(qv.y); qo.z=f2bf(qv.z); qo.w=f2bf(qv.w);
        ko.x=f2bf(kv.x); ko.y=f2bf(kv.y); ko.z=f2bf(kv.z); ko.w=f2bf(kv.w);
        *(ushort4*)(qd+j) = qo;
        *(ushort4*)(kd+j) = ko;
      }
    }
    __syncthreads();
    {
      short8 a0 = *(const short8*)&KVb[(16*wv+c)*NS2 + 8*q];
      short8 a1 = *(const short8*)&KVb[(16*wv+c)*NS2 + 32 + 8*q];
      #pragma unroll
      for(int tc=0;tc<4;tc++){
        short8 b0 = *(const short8*)&KVt[(16*tc+c)*NS2 + 8*q];
        short8 b1 = *(const short8*)&KVt[(16*tc+c)*NS2 + 32 + 8*q];
        acc[tc] = __builtin_amdgcn_mfma_f32_16x16x32_bf16(a0, b0, acc[tc], 0, 0, 0);
        acc[tc] = __builtin_amdgcn_mfma_f32_16x16x32_bf16(a1, b1, acc[tc], 0, 0, 0);
      }
    }
  }
  __syncthreads();   // KVb/KVt reads done everywhere before sS (alias) is written
  #pragma unroll
  for(int tc=0;tc<4;tc++){
    int col = 16*tc + c, row0 = 16*wv + 4*q;
    sS[(row0+0)*66+col] = acc[tc][0];
    sS[(row0+1)*66+col] = acc[tc][1];
    sS[(row0+2)*66+col] = acc[tc][2];
    sS[(row0+3)*66+col] = acc[tc][3];
  }
  __syncthreads();
  if(tid < 64){
    int j = tid;
    float m = -1e30f;
    for(int i=0;i<64;i++) m = fmaxf(m, sS[i*66+j]);
    float ssum = 0.f;
    for(int i=0;i<64;i++) ssum += __expf(sS[i*66+j]-m);
    float inv = 1.f/ssum, cs = 0.f;
    for(int i=0;i<64;i++){
      float kv = __expf(sS[i*66+j]-m)*inv;
      cs += fabsf(kv);
      Kb[i*NS2+j] = f2bf(kv);
    }
    sred[j] = cs;
  }
  __syncthreads();
  if(tid < 64){
    int i = tid; float rs = 0.f;
    for(int j=0;j<64;j++) rs += fabsf(bf2f(Kb[i*NS2+j]));
    sred[64+i] = rs;
  }
  __syncthreads();
  if(tid == 0){
    float v0=-1e30f, vi=-1e30f;
    for(int t=0;t<64;t++){ v0 = fmaxf(v0, sred[t]); vi = fmaxf(vi, sred[64+t]); }
    sred[128] = 1.f/(v0*vi);
  }
  __syncthreads();
  {
    float sc = sred[128];
    int i = tid>>2, j16 = (tid&3)*16;
    #pragma unroll
    for(int jj=0;jj<16;jj++){
      int j = j16+jj;
      u16 bvv = f2bf(bf2f(Kb[j*NS2+i])*sc);
      Vb[i*NS2+j] = bvv;
      Vt[j*NS2+i] = bvv;
    }
  }
  __syncthreads();
  f32x4 r4[4];
  for(int it=0; it<6; it++){
    ns_mm2(Kb, NS2, Vt, NS2, wv, q, c, r4);
    #pragma unroll
    for(int tc=0;tc<4;tc++){
      int col = 16*tc + c, row0 = 16*wv + 4*q;
      ushort4 pk;
      pk.x = f2bf(r4[tc][0]); pk.y = f2bf(r4[tc][1]); pk.z = f2bf(r4[tc][2]); pk.w = f2bf(r4[tc][3]);
      KVb[(row0+0)*NS2+col] = pk.x; KVb[(row0+1)*NS2+col] = pk.y;
      KVb[(row0+2)*NS2+col] = pk.z; KVb[(row0+3)*NS2+col] = pk.w;
      *(ushort4*)&KVt[(size_t)col*NS2 + row0] = pk;
    }
    __syncthreads();
    ns_mm2(KVb, NS2, KVt, NS2, wv, q, c, r4);
    #pragma unroll
    for(int tc=0;tc<4;tc++){
      int col = 16*tc+c, row0 = 16*wv+4*q;
      ushort4 pk;
      #pragma unroll
      for(int r=0;r<4;r++){
        float kvv = bf2f(KVb[(row0+r)*NS2+col]);
        ((u16*)&pk)[r] = f2bf(7.f*kvv - r4[tc][r]);
      }
      *(ushort4*)&Tt[(size_t)col*TTS + row0] = pk;
    }
    __syncthreads();
    ns_mm2(KVb, NS2, Tt, TTS, wv, q, c, r4);
    __syncthreads();
    #pragma unroll
    for(int tc=0;tc<4;tc++){
      int col = 16*tc+c, row0 = 16*wv+4*q;
      ushort4 pk;
      #pragma unroll
      for(int r=0;r<4;r++){
        float kvv = bf2f(KVb[(row0+r)*NS2+col]);
        ((u16*)&pk)[r] = f2bf(15.f*kvv - r4[tc][r]);
      }
      *(ushort4*)&Tt[(size_t)col*TTS + row0] = pk;
    }
    __syncthreads();
    ns_mm2(Vb, NS2, Tt, TTS, wv, q, c, r4);
    __syncthreads();
    #pragma unroll
    for(int tc=0;tc<4;tc++){
      int col = 16*tc+c, row0 = 16*wv+4*q;
      float nv[4]; ushort4 pk;
      #pragma unroll
      for(int r=0;r<4;r++){
        float vv = bf2f(Vb[(row0+r)*NS2+col]);
        nv[r] = 0.25f*(13.f*vv - r4[tc][r]);
        u16 bb = f2bf(nv[r]);
        Vb[(row0+r)*NS2+col] = bb;
        ((u16*)&pk)[r] = bb;
      }
      *(ushort4*)&Vt[(size_t)col*NS2 + row0] = pk;
      if(it==5){
        *(float4*)&KinvT[(size_t)n*4096 + (size_t)col*64 + row0] = make_float4(nv[0],nv[1],nv[2],nv[3]);
      }
    }
    __syncthreads();
  }
}

// ---------------- Z1/Z3 landmark GEMM + fused NS (blockIdx.x==64) --------------------------
#define LGS 264   // A LDS row stride (u16): 528B, 16B aligned, bank-conflict-free
__global__ __launch_bounds__(256) void k_landgemm(const u16* __restrict__ Y, const float* __restrict__ qland,
                                                  const float* __restrict__ kland, float* __restrict__ Z1,
                                                  float* __restrict__ Z3, float* __restrict__ KinvT){
  __shared__ __align__(16) char usm[54272];
  const int z = blockIdx.y;
  if(blockIdx.x == 64){
    if((z&1)==0) ns_body(z>>1, usm, qland, kland, KinvT);
    return;
  }
  u16* As = (u16*)usm;                 // [64][LGS]
  u16* BsU = (u16*)(usm + 33792);      // [2][64*64]
  const int n = z>>1, which = z&1;
  const int b0 = blockIdx.x*64;
  const float* land = (which ? qland : kland) + (size_t)n*LND*EDIM;
  const int boff = which ? 256 : 0;
  float* out = (which ? Z3 : Z1) + (size_t)n*LND*HWN;
  const u16* Yb = Y + (size_t)n*M3*HWN + boff;
  const int tid = threadIdx.x, lane = tid&63;
  const int c = tid&15, qq = (tid>>4)&3, wv = tid>>6;
  {
    int r = tid>>2, c0 = (tid&3)*64;
    const float* lp = land + (size_t)r*EDIM + c0;
    u16* dp = &As[r*LGS + c0];
    #pragma unroll
    for(int j=0;j<64;j+=4){
      float4 v = *(const float4*)(lp+j);
      ushort4 o; o.x=f2bf(v.x); o.y=f2bf(v.y); o.z=f2bf(v.z); o.w=f2bf(v.w);
      *(ushort4*)(dp+j) = o;
    }
  }
  const int srow  = wv*8 + (lane>>3);            // 0..31
  const int dslot = lane&7;
  const int sgo   = (dslot ^ (lane>>3))*8;       // row&7 == lane>>3 here
  const int rdswz = (c&7);
  f32x4 acc[4];
  #pragma unroll
  for(int nt=0;nt<4;nt++){ acc[nt][0]=0.f; acc[nt][1]=0.f; acc[nt][2]=0.f; acc[nt][3]=0.f; }
  #pragma unroll
  for(int j=0;j<2;j++){
    int r = j*32 + srow;
    gl16(Yb + (size_t)(b0+r)*M3 + sgo, BsU + r*64 + dslot*8);
  }
  __syncthreads();
  for(int ph=0; ph<4; ph++){
    const int cur = ph&1;
    if(ph<3){
      #pragma unroll
      for(int j=0;j<2;j++){
        int r = j*32 + srow;
        gl16(Yb + (size_t)(b0+r)*M3 + (ph+1)*64 + sgo, BsU + (cur^1)*4096 + r*64 + dslot*8);
      }
    }
    #pragma unroll
    for(int kt=0;kt<2;kt++){
      short8 af = *(const short8*)&As[(16*wv + c)*LGS + ph*64 + kt*32 + qq*8];
      const int rslot = ((kt*4+qq)^rdswz)*8;
      #pragma unroll
      for(int nt=0;nt<4;nt++){
        short8 bff = *(const short8*)&BsU[cur*4096 + (nt*16+c)*64 + rslot];
        acc[nt] = __builtin_amdgcn_mfma_f32_16x16x32_bf16(af, bff, acc[nt], 0, 0, 0);
      }
    }
    __syncthreads();
  }
  const int m0 = 16*wv + 4*qq;
  #pragma unroll
  for(int nt=0;nt<4;nt++){
    int col = b0 + nt*16 + c;
    out[(size_t)(m0+0)*HWN + col] = acc[nt][0];
    out[(size_t)(m0+1)*HWN + col] = acc[nt][1];
    out[(size_t)(m0+2)*HWN + col] = acc[nt][2];
    out[(size_t)(m0+3)*HWN + col] = acc[nt][3];
  }
}

// ---------------- soft1 body: softmax of Z1 over contiguous 4096 ----------------
__device__ void soft1_body(int b, char* smem, float* __restrict__ Z1){
  const int n = b>>6, j = b&63, tid = threadIdx.x;
  float* redm = (float*)smem;
  float* reds = redm + 4;
  float* base = Z1 + ((size_t)n*LND + j)*HWN;
  float v[16];
  float m = -1e30f;
  #pragma unroll
  for(int r=0;r<16;r++){ v[r] = base[r*256 + tid]; m = fmaxf(m, v[r]); }
  #pragma unroll
  for(int o=32;o;o>>=1) m = fmaxf(m, __shfl_xor(m, o));
  const int wid = tid>>6;
  if((tid&63)==0) redm[wid] = m;
  __syncthreads();
  m = fmaxf(fmaxf(redm[0],redm[1]), fmaxf(redm[2],redm[3]));
  float s = 0.f;
  #pragma unroll
  for(int r=0;r<16;r++){ v[r] = __expf(v[r]-m); s += v[r]; }
  #pragma unroll
  for(int o=32;o;o>>=1) s += __shfl_xor(s, o);
  if((tid&63)==0) reds[wid] = s;
  __syncthreads();
  s = reds[0]+reds[1]+reds[2]+reds[3];
  float inv = 1.f/s;
  #pragma unroll
  for(int r=0;r<16;r++) base[r*256 + tid] = v[r]*inv;
}

// ---------------- fused soft3 + PV GEMM (+ soft1 blocks 512-1023) ---------------------------
// Block (kc,n,eh): stage Z3 tile -> column-softmax -> write P bf16 DIRECTLY into the
// XOR-swizzled A buffers (As[i*64 + ((j>>3)^(i&7))*8 + (j&7)], same image gl16 produced);
// then per-phase V^T staging (slot-XOR involution) + MFMA. P never touches HBM.
__global__ __launch_bounds__(256) void k_pv(const float* __restrict__ Z3, const u16* __restrict__ Y,
                                            float* __restrict__ part, float* __restrict__ Z1){
  __shared__ __align__(16) char smem[50688];
  const int bi = blockIdx.x;
  if(bi >= 512){ soft1_body(bi-512, smem, Z1); return; }
  float* Sf   = (float*)smem;              // [64][132] logits -> exp   (0..33792)
  float* sinv = (float*)(smem + 33792);    // [128] 1/sum               (33792..34304)
  u16*   Asb  = (u16*)(smem + 34304);      // [2][64][64] P bf16, XOR-swizzled (..50688)
  u16*   Vt   = (u16*)smem;                // [128 e][64 j] per phase — overlays Sf (dead)
  const int kc = bi&31, n = (bi>>5)&7, eh = bi>>8;
  const int jb = kc*128, eb = eh*128;
  const int tid = threadIdx.x, lane = tid&63;
  const int c = tid&15, qq = (tid>>4)&3, wv = tid>>6;
  const u16* Yb = Y + (size_t)n*M3*HWN;       // raw view: V[j][e] = flat[j*768 + 512 + e]
  const float* z3b = Z3 + (size_t)n*LND*HWN;
  // ---- soft3: stage logits ----
  {
    int ibase = (tid>>5)*8, j4 = (tid&31)*4;
    #pragma unroll
    for(int r=0;r<8;r++){
      int i = ibase + r;
      *(float4*)&Sf[i*132 + j4] = *(const float4*)&z3b[(size_t)i*HWN + jb + j4];
    }
  }
  __syncthreads();
  if(tid < 128){
    int j = tid;
    float m = -1e30f;
    for(int i=0;i<64;i++) m = fmaxf(m, Sf[i*132 + j]);
    float s = 0.f;
    for(int i=0;i<64;i++){ float e = __expf(Sf[i*132 + j] - m); Sf[i*132 + j] = e; s += e; }
    sinv[j] = 1.f/s;
  }
  __syncthreads();
  // ---- write P bf16 straight into swizzled A buffers (both phases) ----
  {
    int i = tid>>2, j0q = (tid&3)*32;
    const int iswz = (i&7);
    #pragma unroll
    for(int t=0;t<32;t+=4){
      int jg = j0q + t;                 // 0..127
      int phb = jg>>6, jl = jg&63;
      ushort4 o;
      o.x = f2bf(Sf[i*132 + jg+0]*sinv[jg+0]);
      o.y = f2bf(Sf[i*132 + jg+1]*sinv[jg+1]);
      o.z = f2bf(Sf[i*132 + jg+2]*sinv[jg+2]);
      o.w = f2bf(Sf[i*132 + jg+3]*sinv[jg+3]);
      *(ushort4*)&Asb[phb*4096 + i*64 + ((jl>>3)^iswz)*8 + (jl&7)] = o;
    }
  }
  __syncthreads();   // Sf dead from here; Vt may overlay it
  const int rdswz = (c&7);
  f32x4 acc[4][2];
  #pragma unroll
  for(int mt=0;mt<4;mt++)
    #pragma unroll
    for(int nt=0;nt<2;nt++){ acc[mt][nt][0]=0.f; acc[mt][nt][1]=0.f; acc[mt][nt][2]=0.f; acc[mt][nt][3]=0.f; }
  for(int ph=0; ph<2; ph++){
    #pragma unroll
    for(int rep=0; rep<4; rep++){
      int jl = (tid>>4) + 16*rep;                       // 0..63
      int ec = (tid&15)*8;                              // 0..120
      uint4 U = *(const uint4*)&Yb[(size_t)(jb+ph*64+jl)*M3 + 512 + eb + ec];
      const u16* uv = (const u16*)&U;
      #pragma unroll
      for(int k=0;k<8;k++){
        int e = ec+k;
        int slot = ((jl>>3) ^ (e&7) ^ ((e>>3)&7)) & 7;
        Vt[e*64 + slot*8 + (jl&7)] = uv[k];
      }
    }
    __syncthreads();
    #pragma unroll
    for(int kt=0;kt<2;kt++){
      const int rslotA = ((kt*4+qq)^rdswz)*8;
      short8 af[4];
      #pragma unroll
      for(int mt=0;mt<4;mt++) af[mt] = *(const short8*)&Asb[ph*4096 + (mt*16+c)*64 + rslotA];
      #pragma unroll
      for(int nt=0;nt<2;nt++){
        int e = wv*32 + nt*16 + c;
        int slotB = ((kt*4+qq) ^ (e&7) ^ ((e>>3)&7)) & 7;
        short8 bf_ = *(const short8*)&Vt[e*64 + slotB*8];
        #pragma unroll
        for(int mt=0;mt<4;mt++)
          acc[mt][nt] = __builtin_amdgcn_mfma_f32_16x16x32_bf16(af[mt], bf_, acc[mt][nt], 0, 0, 0);
      }
    }
    __syncthreads();
  }
  float* pb = part + ((size_t)n*32 + kc)*LND*EDIM + eb;
  #pragma unroll
  for(int mt=0;mt<4;mt++){
    int row0 = mt*16 + 4*qq;
    #pragma unroll
    for(int nt=0;nt<2;nt++){
      int e = wv*32 + nt*16 + c;
      pb[(size_t)(row0+0)*EDIM + e] = acc[mt][nt][0];
      pb[(size_t)(row0+1)*EDIM + e] = acc[mt][nt][1];
      pb[(size_t)(row0+2)*EDIM + e] = acc[mt][nt][2];
      pb[(size_t)(row0+3)*EDIM + e] = acc[mt][nt][3];
    }
  }
}

// ---------------- C2T[n][e][j] (bf16) = (Kinv @ sum_kc part)[j][e], fused fred+c2 ----------
__global__ __launch_bounds__(256) void k_c2(const float* __restrict__ KinvT, const float* __restrict__ part,
                                            u16* __restrict__ C2T){
  const int eb = blockIdx.x*64, n = blockIdx.y, tid = threadIdx.x;
  __shared__ float KT[64][68];
  __shared__ float Bs2[64][68];
  __shared__ u16 Ct[64*72];
  {
    int l = tid>>2, o16 = (tid&3)*16;
    const float* kp = KinvT + (size_t)n*4096 + l*64 + o16;
    #pragma unroll
    for(int t=0;t<16;t+=4) *(float4*)&KT[l][o16+t] = *(const float4*)(kp+t);
    // fused k_fred: B3[l][eb+o16..+16] = sum_kc part[n][kc][l][...]
    const float* pp = part + (size_t)n*32*16384 + (size_t)l*256 + eb + o16;
    float4 s0 = {0,0,0,0}, s1 = {0,0,0,0}, s2 = {0,0,0,0}, s3 = {0,0,0,0};
    for(int kc=0;kc<32;kc++){
      const float* b = pp + (size_t)kc*16384;
      float4 v0 = *(const float4*)(b);
      float4 v1 = *(const float4*)(b+4);
      float4 v2 = *(const float4*)(b+8);
      float4 v3 = *(const float4*)(b+12);
      s0.x+=v0.x; s0.y+=v0.y; s0.z+=v0.z; s0.w+=v0.w;
      s1.x+=v1.x; s1.y+=v1.y; s1.z+=v1.z; s1.w+=v1.w;
      s2.x+=v2.x; s2.y+=v2.y; s2.z+=v2.z; s2.w+=v2.w;
      s3.x+=v3.x; s3.y+=v3.y; s3.z+=v3.z; s3.w+=v3.w;
    }
    *(float4*)&Bs2[l][o16+0]  = s0;
    *(float4*)&Bs2[l][o16+4]  = s1;
    *(float4*)&Bs2[l][o16+8]  = s2;
    *(float4*)&Bs2[l][o16+12] = s3;
  }
  __syncthreads();
  const int j0 = (tid>>4)*4, u0 = (tid&15)*4;
  float acc[4][4] = {};
  #pragma unroll 8
  for(int l=0;l<64;l++){
    f32x4 a = *(f32x4*)&KT[l][j0];
    f32x4 b = *(f32x4*)&Bs2[l][u0];
    #pragma unroll
    for(int s=0;s<4;s++)
      #pragma unroll
      for(int u=0;u<4;u++) acc[s][u] += a[s]*b[u];
  }
  // transpose to bf16 [e][j] via LDS, then coalesced global write
  #pragma unroll
  for(int s=0;s<4;s++)
    #pragma unroll
    for(int u=0;u<4;u++)
      Ct[(u0+u)*72 + j0+s] = f2bf(acc[s][u]);
  __syncthreads();
  {
    int e = tid>>2, j16 = (tid&3)*16;
    u16* op = C2T + ((size_t)n*256 + eb + e)*64 + j16;
    #pragma unroll
    for(int t=0;t<16;t+=4)
      *(ushort4*)(op+t) = *(const ushort4*)&Ct[e*72 + j16 + t];
  }
}

// ---------------- out[i][e] = sum_j Z1[j][i]*C2[j][e] + v[i][e]; MFMA, OM bf16 --------------
__global__ __launch_bounds__(256) void k_out(const float* __restrict__ Z1, const u16* __restrict__ C2T,
                                             const u16* __restrict__ Y, u16* __restrict__ OM){
  __shared__ __align__(16) u16 Cs[256*64];    // [256 e][64 j], gl16-swizzled
  __shared__ __align__(16) u16 Zt[64*72];     // [64 i][72 j]
  const int ib = blockIdx.x*64, n = blockIdx.y;
  const int tid = threadIdx.x, lane = tid&63;
  const int c = tid&15, qq = (tid>>4)&3, wv = tid>>6;
  const int srow  = wv*8 + (lane>>3);
  const int dslot = lane&7;
  const int sgo   = (dslot ^ (lane>>3))*8;
  const int rdswz = (c&7);
  const u16* cb = C2T + (size_t)n*256*64;
  #pragma unroll
  for(int j=0;j<8;j++){
    int r = j*32 + srow;
    gl16(cb + (size_t)r*64 + sgo, &Cs[r*64 + dslot*8]);
  }
  {
    int j = tid>>2, i16 = (tid&3)*16;
    const float* zp = Z1 + ((size_t)n*LND + j)*HWN + ib + i16;
    #pragma unroll
    for(int t=0;t<16;t+=4){
      float4 v = *(const float4*)(zp+t);
      Zt[(i16+t+0)*72 + j] = f2bf(v.x);
      Zt[(i16+t+1)*72 + j] = f2bf(v.y);
      Zt[(i16+t+2)*72 + j] = f2bf(v.z);
      Zt[(i16+t+3)*72 + j] = f2bf(v.w);
    }
  }
  __syncthreads();
  f32x4 acc[4][4];
  #pragma unroll
  for(int mt=0;mt<4;mt++)
    #pragma unroll
    for(int nt=0;nt<4;nt++){ acc[mt][nt][0]=0.f; acc[mt][nt][1]=0.f; acc[mt][nt][2]=0.f; acc[mt][nt][3]=0.f; }
  #pragma unroll
  for(int kt=0;kt<2;kt++){
    const int rslot = ((kt*4+qq)^rdswz)*8;
    short8 af[4], bf_[4];
    #pragma unroll
    for(int mt=0;mt<4;mt++) af[mt] = *(const short8*)&Cs[(wv*64+mt*16+c)*64 + rslot];
    #pragma unroll
    for(int nt=0;nt<4;nt++) bf_[nt] = *(const short8*)&Zt[(nt*16+c)*72 + kt*32 + qq*8];
    #pragma unroll
    for(int mt=0;mt<4;mt++)
      #pragma unroll
      for(int nt=0;nt<4;nt++)
        acc[mt][nt] = __builtin_amdgcn_mfma_f32_16x16x32_bf16(af[mt], bf_[nt], acc[mt][nt], 0, 0, 0);
  }
  // epilogue: e = wv*64 + mt*16 + 4*qq (+r), i = ib + nt*16 + c ; ushort4 V-add + store
  const u16* Yb = Y + (size_t)n*M3*HWN;
  u16* ob = OM + (size_t)n*HWN*EDIM;
  #pragma unroll
  for(int mt=0;mt<4;mt++){
    int e = wv*64 + mt*16 + 4*qq;
    #pragma unroll
    for(int nt=0;nt<4;nt++){
      int i = ib + nt*16 + c;
      ushort4 V4 = *(const ushort4*)(Yb + (size_t)i*M3 + 512 + e);
      ushort4 o;
      o.x = f2bf(acc[mt][nt][0] + bf2f(V4.x));
      o.y = f2bf(acc[mt][nt][1] + bf2f(V4.y));
      o.z = f2bf(acc[mt][nt][2] + bf2f(V4.z));
      o.w = f2bf(acc[mt][nt][3] + bf2f(V4.w));
      *(ushort4*)(ob + (size_t)i*EDIM + e) = o;
    }
  }
}

// ---------------- proj GEMM 128x128xK256; B read directly from OM raw [e'][p'] view ---------
__global__ __launch_bounds__(256) void k_proj(const u16* __restrict__ Wb, const u16* __restrict__ OM,
                                              const float* __restrict__ bias, float* __restrict__ out){
  __shared__ __align__(16) u16 As[128*64];
  __shared__ __align__(16) u16 Bt[128*64];    // [128 p][64 e'] slot-XOR layout
  const int bi = blockIdx.x;
  const int n = bi&7, rem = bi>>3;
  const int ch0 = (rem&1)*128, p0 = (rem>>1)*128;
  const int tid = threadIdx.x, lane = tid&63;
  const int c = tid&15, qq = (tid>>4)&3, w4 = tid>>6;
  const int wr0 = (w4&1)*64, wc0 = (w4>>1)*64;
  const u16* omb = OM + (size_t)n*HWN*EDIM;   // flat, viewed [256 e'][4096 p']
  const u16* wb = Wb + (size_t)ch0*EDIM;
  f32x4 acc[4][4];
  #pragma unroll
  for(int mt=0;mt<4;mt++)
    #pragma unroll
    for(int nt=0;nt<4;nt++){ acc[mt][nt][0]=0.f; acc[mt][nt][1]=0.f; acc[mt][nt][2]=0.f; acc[mt][nt][3]=0.f; }
  const int srow  = w4*8 + (lane>>3);
  const int dslot = lane&7;
  const int sgo   = (dslot ^ (lane>>3))*8;
  const int rdswz = (c&7);
  for(int ph=0; ph<4; ph++){
    #pragma unroll
    for(int j=0;j<4;j++){
      int r = j*32 + srow;
      gl16(wb + (size_t)r*EDIM + ph*64 + sgo, &As[r*64 + dslot*8]);
    }
    #pragma unroll
    for(int rep=0; rep<4; rep++){
      int ee = (tid>>4) + 16*rep;                       // 0..63 (e' within phase)
      int pc = (tid&15)*8;                              // 0..120
      uint4 U = *(const uint4*)&omb[(size_t)(ph*64+ee)*HWN + p0 + pc];
      const u16* uv = (const u16*)&U;
      #pragma unroll
      for(int k=0;k<8;k++){
        int p = pc+k;
        int slot = ((ee>>3) ^ (p&7) ^ ((p>>3)&7)) & 7;
        Bt[p*64 + slot*8 + (ee&7)] = uv[k];
      }
    }
    __syncthreads();
    #pragma unroll
    for(int kt=0;kt<2;kt++){
      const int rslot = ((kt*4+qq)^rdswz)*8;
      short8 af[4], bff[4];
      #pragma unroll
      for(int mt=0;mt<4;mt++) af[mt] = *(const short8*)&As[(wr0+mt*16+c)*64 + rslot];
      #pragma unroll
      for(int nt=0;nt<4;nt++){
        int p = wc0 + nt*16 + c;
        int slotB = ((kt*4+qq) ^ (p&7) ^ ((p>>3)&7)) & 7;
        bff[nt] = *(const short8*)&Bt[p*64 + slotB*8];
      }
      #pragma unroll
      for(int mt=0;mt<4;mt++)
        #pragma unroll
        for(int nt=0;nt<4;nt++)
          acc[mt][nt] = __builtin_amdgcn_mfma_f32_16x16x32_bf16(af[mt], bff[nt], acc[mt][nt], 0, 0, 0);
    }
    __syncthreads();
  }
  float* ob = out + (size_t)n*EDIM*HWN;
  #pragma unroll
  for(int mt=0;mt<4;mt++){
    int chb = ch0 + wr0 + mt*16 + 4*qq;
    float b0 = bias[chb], b1 = bias[chb+1], b2 = bias[chb+2], b3 = bias[chb+3];
    #pragma unroll
    for(int nt=0;nt<4;nt++){
      int p = p0 + wc0 + nt*16 + c;
      float* yp = ob + (size_t)chb*HWN + p;
      yp[0]             = acc[mt][nt][0]+b0;
      yp[HWN]           = acc[mt][nt][1]+b1;
      yp[2*(size_t)HWN] = acc[mt][nt][2]+b2;
      yp[3*(size_t)HWN] = acc[mt][nt][3]+b3;
    }
  }
}

extern "C" void kernel_launch(void* const* d_in, const int* in_sizes, int n_in,
                              void* d_out, int out_size, void* d_ws, size_t ws_size,
                              hipStream_t stream){
  (void)out_size; (void)ws_size;
  const float* x     = (const float*)d_in[0];
  const float* w_qkv = (const float*)d_in[1];
  const float* b_qkv = (const float*)d_in[2];
  const float* w_out = (const float*)d_in[3];
  const float* b_out = (const float*)d_in[4];
  for(int i=0;i<n_in;i++){
    switch(in_sizes[i]){
      case 8388608: x     = (const float*)d_in[i]; break;
      case 196608:  w_qkv = (const float*)d_in[i]; break;
      case 768:     b_qkv = (const float*)d_in[i]; break;
      case 65536:   w_out = (const float*)d_in[i]; break;
      case 256:     b_out = (const float*)d_in[i]; break;
      default: break;
    }
  }
  float* out = (float*)d_out;
  char* ws = (char*)d_ws;

  u16*   Y     = (u16*)(ws + 0);              // 50,331,648 B  bf16 [8][768*4096]
  float* qland = (float*)(ws + 50331648);
  float* kland = (float*)(ws + 50855936);
  float* Z1    = (float*)(ws + 51380224);
  float* Z3    = (float*)(ws + 59768832);
  float* KinvT = (float*)(ws + 68157440);
  float* part  = (float*)(ws + 68288512);     // 16 MB region (was Xt -> part)
  u16*   Xt    = (u16*)(ws + 68288512);
  u16*   C2T   = (u16*)(ws + 85065728);       // bf16 [8][256 e][64 j] = 256 KB
  u16*   OM    = (u16*)(ws + 86114304);       // 16 MB bf16
  // Wqb overlaps Z3 (Z3 written by k_landgemm AFTER k_qkv consumes Wqb — stream-ordered safe)
  u16*   Wqb   = (u16*)(ws + 59768832);       // 393,216 B bf16 [768][256]
  u16*   Wob   = (u16*)(ws + 102891520);      // 131,072 B bf16 [256][256] (persists to k_proj)

  k_prep    <<<dim3(2056),   256, 0, stream>>>(x, Xt, w_qkv, w_out, Wqb, Wob);
  k_qkv     <<<dim3(1536),   256, 0, stream>>>(Wqb, Xt, b_qkv, Y);
  k_land    <<<dim3(64,8),   256, 0, stream>>>(Y, qland, kland);
  k_landgemm<<<dim3(65,16),  256, 0, stream>>>(Y, qland, kland, Z1, Z3, KinvT);
  k_pv      <<<dim3(1024),   256, 0, stream>>>(Z3, Y, part, Z1);
  k_c2      <<<dim3(4,8),    256, 0, stream>>>(KinvT, part, C2T);
  k_out     <<<dim3(64,8),   256, 0, stream>>>(Z1, C2T, Y, OM);
  k_proj    <<<dim3(512),    256, 0, stream>>>(Wob, OM, b_out, out);
}